// Round 11
// baseline (139.164 us; speedup 1.0000x reference)
//
#include <hip/hip_runtime.h>
#include <hip/hip_bf16.h>
#include <cstddef>

// NLBasicBlock fused, round 11: split-K raised to SJ=10 (runtime-selected,
// falls back to 5 if ws_size too small) -> k_nl/k_colstat grid 2000 blocks,
// ~5 resident blocks/CU (LDS cap) = 10 waves/CU so ds_read/VALU/MFMA overlap
// across waves instead of serializing at 1.25 waves/SIMD (R10's limiter).

constexpr int kB = 2, kC = 64, kH = 80, kW = 80, kN = kH * kW;
constexpr float kLOG2E = 1.4426950408889634f;
constexpr float kSHIFT = 28.853900817779268f;  // 20 * log2(e)

typedef __attribute__((ext_vector_type(8))) short short8;
typedef __attribute__((ext_vector_type(4))) float f32x4;

__device__ __forceinline__ uint pkbf(float a, float b) {
  union { __hip_bfloat162 h; uint u; } x;
  x.h.x = __float2bfloat16(a);
  x.h.y = __float2bfloat16(b);
  return x.u;
}

#define GL16(gsrc, ldst)                                                    \
  __builtin_amdgcn_global_load_lds(                                         \
      (__attribute__((address_space(1))) void*)(char*)(gsrc),               \
      (__attribute__((address_space(3))) void*)(ldst), 16, 0, 0)

// ---- conv weights -> bf16 MFMA B-fragment-linear
__global__ void k_prep(const float* __restrict__ w1, const float* __restrict__ w2,
                       ushort* __restrict__ wc1, ushort* __restrict__ wc2) {
  const int idx = blockIdx.x * 256 + threadIdx.x;  // 36864
  const int o = idx / (kC * 9);
  const int r = idx % (kC * 9);
  const int ci = r / 9, tap = r % 9;
  const int og = o >> 4, il = o & 15;
  const int kc = ci >> 5, hi = (ci >> 3) & 3, e = ci & 7;
  const int pos = ((tap * 2 + kc) * 4 + og) * 512 + (hi * 16 + il) * 8 + e;
  union { __hip_bfloat16 h; ushort u; } c1, c2;
  c1.h = __float2bfloat16(w1[idx]);
  c2.h = __float2bfloat16(w2[idx]);
  wc1[pos] = c1.u;
  wc2[pos] = c2.u;
}

// ---- M = Wth^T.Wph (bf16) + bf16 Wg, WW
__global__ void k_prepM(const float* __restrict__ wth, const float* __restrict__ wph,
                        const float* __restrict__ wg, const float* __restrict__ wWm,
                        __hip_bfloat16* __restrict__ Mb,
                        __hip_bfloat16* __restrict__ wgb,
                        __hip_bfloat16* __restrict__ wWb) {
  const int idx = blockIdx.x * 256 + threadIdx.x;  // 4096
  const int a = idx >> 6, bb = idx & 63;
  float s = 0.f;
  for (int o = 0; o < kC; ++o) s += wth[o * kC + a] * wph[o * kC + bb];
  Mb[idx] = __float2bfloat16(s);
  wgb[idx] = __float2bfloat16(wg[idx]);
  wWb[idx] = __float2bfloat16(wWm[idx]);
}

// ---- x f32 [B][C][N] -> bf16 pixel-major [B][N][C]
__global__ __launch_bounds__(256) void k_tobf(const float* __restrict__ x,
                                              ushort* __restrict__ xb) {
  const int b = blockIdx.y;
  const int j0 = blockIdx.x * 64;
  const int t = threadIdx.x;
  __shared__ ushort tile[64][68];
  {
    const int c = t >> 2, jseg = (t & 3) * 16;
    const float* s = &x[((size_t)b * kC + c) * kN + j0 + jseg];
#pragma unroll
    for (int k = 0; k < 16; ++k) {
      union { __hip_bfloat16 h; ushort u; } cv;
      cv.h = __float2bfloat16(s[k]);
      tile[c][jseg + k] = cv.u;
    }
  }
  __syncthreads();
  {
    const int j = t >> 2, cseg = (t & 3) * 16;
    union { short8 v; ushort u[8]; } o0, o1;
#pragma unroll
    for (int k = 0; k < 16; ++k) {
      const ushort u = tile[cseg + k][j];
      if (k < 8) o0.u[k] = u; else o1.u[k - 8] = u;
    }
    short8* d = (short8*)&xb[((size_t)b * kN + j0 + j) * kC + cseg];
    d[0] = o0.v;
    d[1] = o1.v;
  }
}

// ---- MFMA 3x3 reflect conv (R10)
template <int MODE>
__global__ __launch_bounds__(256) void k_convm(
    const ushort* __restrict__ xb, const ushort* __restrict__ wc,
    const float* __restrict__ alphap, float* __restrict__ raw,
    ushort* __restrict__ pt) {
  const int tile = blockIdx.x;  // 400 = 80 rows x 5 col-tiles
  const int b = blockIdx.y;
  const int r0 = tile / 5, c0 = (tile % 5) * 16;
  const int lane = threadIdx.x & 63, w = threadIdx.x >> 6;
  const int il = lane & 15, hi = lane >> 4;

  __shared__ ushort zt[16][72];

  short8 wt[9][2];
#pragma unroll
  for (int t = 0; t < 9; ++t)
#pragma unroll
    for (int kc = 0; kc < 2; ++kc)
      wt[t][kc] = *(const short8*)&wc[(size_t)((t * 2 + kc) * 4 + w) * 512 + lane * 8];

  int cl[3], rb[3];
#pragma unroll
  for (int d = 0; d < 3; ++d) {
    const int cc = c0 + il + d - 1;
    cl[d] = cc < 0 ? 1 : (cc > kW - 1 ? kW - 2 : cc);
    const int rr = r0 + d - 1;
    rb[d] = rr < 0 ? 1 : (rr > kH - 1 ? kH - 2 : rr);
  }
  const ushort* xB = xb + (size_t)b * kN * kC;

  f32x4 acc = {0.f, 0.f, 0.f, 0.f};
#pragma unroll
  for (int dh = 0; dh < 3; ++dh) {
    const int nb = rb[dh] * kW;
#pragma unroll
    for (int dw = 0; dw < 3; ++dw) {
      const ushort* src = &xB[(size_t)(nb + cl[dw]) * kC + hi * 8];
      const short8 a0 = *(const short8*)src;
      const short8 a1 = *(const short8*)(src + 32);
      acc = __builtin_amdgcn_mfma_f32_16x16x32_bf16(a0, wt[dh * 3 + dw][0], acc, 0, 0, 0);
      acc = __builtin_amdgcn_mfma_f32_16x16x32_bf16(a1, wt[dh * 3 + dw][1], acc, 0, 0, 0);
    }
  }

  const int n0 = r0 * kW + c0;
  const float alpha = alphap[0];
  if (MODE == 0) {
    *(f32x4*)&raw[((size_t)b * kC + w * 16 + il) * kN + n0 + hi * 4] = acc;
#pragma unroll
    for (int r = 0; r < 4; ++r) {
      const float v = acc[r];
      union { __hip_bfloat16 h; ushort u; } cv;
      cv.h = __float2bfloat16(v >= 0.f ? v : alpha * v);
      zt[hi * 4 + r][w * 16 + il] = cv.u;
    }
    __syncthreads();
    const int t = threadIdx.x;
    const int px = t >> 4, cb = (t & 15) * 4;
    uint2 o2;
    o2.x = (uint)zt[px][cb] | ((uint)zt[px][cb + 1] << 16);
    o2.y = (uint)zt[px][cb + 2] | ((uint)zt[px][cb + 3] << 16);
    *(uint2*)&pt[((size_t)b * kN + n0 + px) * kC + cb] = o2;
  } else {
    f32x4 pr;
#pragma unroll
    for (int r = 0; r < 4; ++r) {
      const float v = acc[r];
      pr[r] = v >= 0.f ? v : alpha * v;
    }
    *(f32x4*)&raw[((size_t)b * kC + w * 16 + il) * kN + n0 + hi * 4] = pr;
  }
}

// ---- phi' = M.p, g = Wg.p (bf16 pixel-major)
__global__ __launch_bounds__(256) void k_pw(
    const __hip_bfloat16* __restrict__ pTb, const __hip_bfloat16* __restrict__ Mb,
    const __hip_bfloat16* __restrict__ wgb, __hip_bfloat16* __restrict__ phb,
    __hip_bfloat16* __restrict__ gb) {
  const int b = blockIdx.y;
  const int lane = threadIdx.x & 63, w = threadIdx.x >> 6;
  const int il = lane & 15, hi = lane >> 4;
  const int n = blockIdx.x * 16 + il;

  const short8 b0 = *(const short8*)&pTb[((size_t)b * kN + n) * kC + hi * 8];
  const short8 b1 = *(const short8*)&pTb[((size_t)b * kN + n) * kC + 32 + hi * 8];

  const short8 am0 = *(const short8*)&Mb[(size_t)(w * 16 + il) * kC + hi * 8];
  const short8 am1 = *(const short8*)&Mb[(size_t)(w * 16 + il) * kC + 32 + hi * 8];
  f32x4 o4 = {0.f, 0.f, 0.f, 0.f};
  o4 = __builtin_amdgcn_mfma_f32_16x16x32_bf16(am0, b0, o4, 0, 0, 0);
  o4 = __builtin_amdgcn_mfma_f32_16x16x32_bf16(am1, b1, o4, 0, 0, 0);
  uint2 p2;
  p2.x = pkbf(o4[0], o4[1]);
  p2.y = pkbf(o4[2], o4[3]);
  *(uint2*)&phb[((size_t)b * kN + n) * kC + w * 16 + hi * 4] = p2;

  const short8 ag0 = *(const short8*)&wgb[(size_t)(w * 16 + il) * kC + hi * 8];
  const short8 ag1 = *(const short8*)&wgb[(size_t)(w * 16 + il) * kC + 32 + hi * 8];
  f32x4 g4 = {0.f, 0.f, 0.f, 0.f};
  g4 = __builtin_amdgcn_mfma_f32_16x16x32_bf16(ag0, b0, g4, 0, 0, 0);
  g4 = __builtin_amdgcn_mfma_f32_16x16x32_bf16(ag1, b1, g4, 0, 0, 0);
  uint2 g2;
  g2.x = pkbf(g4[0], g4[1]);
  g2.y = pkbf(g4[2], g4[3]);
  *(uint2*)&gb[((size_t)b * kN + n) * kC + w * 16 + hi * 4] = g2;
}

// ---- column sums, j-tile 32/wave, i streamed in 64-tiles, split SJ.
__global__ __launch_bounds__(128, 4) void k_colstat(
    const __hip_bfloat16* __restrict__ th, const __hip_bfloat16* __restrict__ ph,
    float* __restrict__ partial, int chunk, int sj) {
  const int b = blockIdx.z, ic = blockIdx.y;
  const int lane = threadIdx.x & 63, w = threadIdx.x >> 6;
  const int il = lane & 15, hi = lane >> 4;
  const int j0w = blockIdx.x * 64 + w * 32;
  const int NT = chunk / 64;

  __shared__ __align__(16) ushort tbufA[4096], tbufB[4096];

  const __hip_bfloat16* thB = th + (size_t)b * kN * kC;
  const size_t phr0 = ((size_t)b * kN + j0w + il) * kC;
  const size_t phr1 = ((size_t)b * kN + j0w + 16 + il) * kC;
  const short8 a00 = *(const short8*)&ph[phr0 + hi * 8];
  const short8 a01 = *(const short8*)&ph[phr0 + 32 + hi * 8];
  const short8 a10 = *(const short8*)&ph[phr1 + hi * 8];
  const short8 a11 = *(const short8*)&ph[phr1 + 32 + hi * 8];

  const int f0 = 4 * w;
  const char* st[4];
#pragma unroll
  for (int k = 0; k < 4; ++k) {
    const int f = f0 + k;
    st[k] = (const char*)&thB[(size_t)(ic * chunk + (f >> 1) * 16 + il) * kC +
                              (f & 1) * 32 + hi * 8];
  }

#define CSTAGE(DST)                                                         \
  {                                                                         \
    _Pragma("unroll") for (int k = 0; k < 4; ++k) {                         \
      GL16(st[k], &DST[(f0 + k) * 512]);                                    \
      st[k] += (size_t)64 * kC * 2;                                         \
    }                                                                       \
  }

#define CCOMP(SRC)                                                         \
  {                                                                        \
    const ushort* bp_ = SRC;                                               \
    _Pragma("unroll") for (int s = 0; s < 4; ++s) {                        \
      const short8 bf0 = *(const short8*)&bp_[(2 * s) * 512 + lane * 8];   \
      const short8 bf1 = *(const short8*)&bp_[(2 * s + 1) * 512 + lane * 8];\
      f32x4 sj0 = {0.f, 0.f, 0.f, 0.f};                                    \
      f32x4 sj1 = {0.f, 0.f, 0.f, 0.f};                                    \
      sj0 = __builtin_amdgcn_mfma_f32_16x16x32_bf16(a00, bf0, sj0, 0, 0, 0);\
      sj0 = __builtin_amdgcn_mfma_f32_16x16x32_bf16(a01, bf1, sj0, 0, 0, 0);\
      sj1 = __builtin_amdgcn_mfma_f32_16x16x32_bf16(a10, bf0, sj1, 0, 0, 0);\
      sj1 = __builtin_amdgcn_mfma_f32_16x16x32_bf16(a11, bf1, sj1, 0, 0, 0);\
      _Pragma("unroll") for (int r = 0; r < 4; ++r) {                      \
        cs0[r] += exp2f(fmaf(sj0[r], kLOG2E, -kSHIFT));                    \
        cs1[r] += exp2f(fmaf(sj1[r], kLOG2E, -kSHIFT));                    \
      }                                                                    \
    }                                                                      \
  }

  float cs0[4] = {0.f, 0.f, 0.f, 0.f};
  float cs1[4] = {0.f, 0.f, 0.f, 0.f};
  CSTAGE(tbufA);
  __syncthreads();
#pragma unroll 1
  for (int t = 0; t < NT / 2 - 1; ++t) {
    CSTAGE(tbufB);
    CCOMP(tbufA);
    __syncthreads();
    CSTAGE(tbufA);
    CCOMP(tbufB);
    __syncthreads();
  }
  CSTAGE(tbufB);
  CCOMP(tbufA);
  __syncthreads();
  CCOMP(tbufB);
#undef CSTAGE
#undef CCOMP

#pragma unroll
  for (int r = 0; r < 4; ++r) {
    cs0[r] += __shfl_xor(cs0[r], 1); cs1[r] += __shfl_xor(cs1[r], 1);
    cs0[r] += __shfl_xor(cs0[r], 2); cs1[r] += __shfl_xor(cs1[r], 2);
    cs0[r] += __shfl_xor(cs0[r], 4); cs1[r] += __shfl_xor(cs1[r], 4);
    cs0[r] += __shfl_xor(cs0[r], 8); cs1[r] += __shfl_xor(cs1[r], 8);
  }
  if (il == 0) {
    float* p = partial + (size_t)(b * sj + ic) * kN + j0w + hi * 4;
#pragma unroll
    for (int r = 0; r < 4; ++r) {
      p[r] = cs0[r];
      p[16 + r] = cs1[r];
    }
  }
}

// ---- gT[b][c][j] = bf16( g[b][j][c] * 1/colsum[b][j] )
__global__ __launch_bounds__(256) void k_gscale(
    const __hip_bfloat16* __restrict__ gb, const float* __restrict__ partial,
    __hip_bfloat16* __restrict__ gT, int sj) {
  const int b = blockIdx.y;
  const int j0 = blockIdx.x * 64;
  const int t = threadIdx.x;
  __shared__ ushort tile[64][66];
  __shared__ float rsv[64];
  if (t < 64) {
    const int j = j0 + t;
    float cs = 0.f;
#pragma unroll 1
    for (int s = 0; s < sj; ++s) cs += partial[(size_t)(b * sj + s) * kN + j];
    rsv[t] = 1.0f / cs;
  }
  {
    const int jl = t >> 2, cseg = (t & 3) * 16;
    const ushort* src = (const ushort*)&gb[((size_t)b * kN + j0 + jl) * kC + cseg];
    union { short8 v; ushort u[8]; } u0, u1;
    u0.v = *(const short8*)src;
    u1.v = *(const short8*)(src + 8);
#pragma unroll
    for (int k = 0; k < 8; ++k) {
      tile[jl][cseg + k] = u0.u[k];
      tile[jl][cseg + 8 + k] = u1.u[k];
    }
  }
  __syncthreads();
  const int c = t >> 2, jseg = (t & 3) * 16;
  union { short8 v; ushort u[8]; } o0, o1;
#pragma unroll
  for (int k = 0; k < 16; ++k) {
    const int j = jseg + k;
    const float gv = __uint_as_float((uint)tile[j][c] << 16);
    union { __hip_bfloat16 h; ushort us; } cv;
    cv.h = __float2bfloat16(gv * rsv[j]);
    if (k < 8) o0.u[k] = cv.us; else o1.u[k - 8] = cv.us;
  }
  short8* dst = (short8*)&gT[((size_t)b * kC + c) * kN + j0 + jseg];
  dst[0] = o0.v;
  dst[1] = o1.v;
}

// ---- pass B, j-split SJ, i-tile 32/wave.
__global__ __launch_bounds__(128, 2) void k_nl(
    const __hip_bfloat16* __restrict__ th, const __hip_bfloat16* __restrict__ ph,
    const __hip_bfloat16* __restrict__ gT, ushort* __restrict__ py, int chunk) {
  const int js = blockIdx.y, b = blockIdx.z;
  const int lane = threadIdx.x & 63, w = threadIdx.x >> 6;
  const int il = lane & 15, hi = lane >> 4;
  const int itile32 = blockIdx.x * 2 + w;
  const int i0w = itile32 * 32;
  const int jstart = js * chunk;
  const int NT = chunk / 64;
  const int jbase = ((il >> 2) << 3) + (il & 3);  // sigma(row=il)

  __shared__ __align__(16) ushort bufA[8192], bufB[8192];

  const __hip_bfloat16* phB = ph + (size_t)b * kN * kC;
  const __hip_bfloat16* gTB = gT + (size_t)b * kC * kN;

  const size_t tr0 = ((size_t)b * kN + i0w + il) * kC;
  const size_t tr1 = ((size_t)b * kN + i0w + 16 + il) * kC;
  const short8 tA0k0 = *(const short8*)&th[tr0 + hi * 8];
  const short8 tA0k1 = *(const short8*)&th[tr0 + 32 + hi * 8];
  const short8 tA1k0 = *(const short8*)&th[tr1 + hi * 8];
  const short8 tA1k1 = *(const short8*)&th[tr1 + 32 + hi * 8];

  const int f0 = 4 * w;
  const char* sp[4];
  const char* sg[4];
#pragma unroll
  for (int k = 0; k < 4; ++k) {
    const int f = f0 + k;
    const int pr = jstart + jbase + ((f >> 1) & 1) * 4 + ((f >> 2) & 1) * 32;
    const int pc = (f & 1) * 32 + hi * 8;
    sp[k] = (const char*)&phB[(size_t)pr * kC + pc];
    const int gc = (f & 3) * 16 + il;
    const int gj = jstart + ((f >> 2) & 1) * 32 + hi * 8;
    sg[k] = (const char*)&gTB[(size_t)gc * kN + gj];
  }

#define NLSTAGE(DST)                                                        \
  {                                                                         \
    _Pragma("unroll") for (int k = 0; k < 4; ++k) {                         \
      GL16(sp[k], &DST[(f0 + k) * 512]);                                    \
      GL16(sg[k], &DST[4096 + (f0 + k) * 512]);                             \
      sp[k] += (size_t)64 * kC * 2;                                         \
      sg[k] += (size_t)64 * 2;                                              \
    }                                                                       \
  }

#define QKI(TB0, TB1, s0, s1, s2, s3)                                        \
    f32x4 s0 = {0.f, 0.f, 0.f, 0.f};                                         \
    f32x4 s1 = {0.f, 0.f, 0.f, 0.f};                                         \
    f32x4 s2 = {0.f, 0.f, 0.f, 0.f};                                         \
    f32x4 s3 = {0.f, 0.f, 0.f, 0.f};                                         \
    s0 = __builtin_amdgcn_mfma_f32_16x16x32_bf16(pa0, TB0, s0, 0, 0, 0);     \
    s0 = __builtin_amdgcn_mfma_f32_16x16x32_bf16(pa1, TB1, s0, 0, 0, 0);     \
    s1 = __builtin_amdgcn_mfma_f32_16x16x32_bf16(pa2, TB0, s1, 0, 0, 0);     \
    s1 = __builtin_amdgcn_mfma_f32_16x16x32_bf16(pa3, TB1, s1, 0, 0, 0);     \
    s2 = __builtin_amdgcn_mfma_f32_16x16x32_bf16(pa4, TB0, s2, 0, 0, 0);     \
    s2 = __builtin_amdgcn_mfma_f32_16x16x32_bf16(pa5, TB1, s2, 0, 0, 0);     \
    s3 = __builtin_amdgcn_mfma_f32_16x16x32_bf16(pa6, TB0, s3, 0, 0, 0);     \
    s3 = __builtin_amdgcn_mfma_f32_16x16x32_bf16(pa7, TB1, s3, 0, 0, 0);

#define PACK2(sa, sb, pb)                                                    \
    short8 pb;                                                               \
    {                                                                        \
      uint* pw_ = (uint*)&pb;                                                \
      pw_[0] = pkbf(exp2f(fmaf(sa[0], kLOG2E, -kSHIFT)),                     \
                    exp2f(fmaf(sa[1], kLOG2E, -kSHIFT)));                    \
      pw_[1] = pkbf(exp2f(fmaf(sa[2], kLOG2E, -kSHIFT)),                     \
                    exp2f(fmaf(sa[3], kLOG2E, -kSHIFT)));                    \
      pw_[2] = pkbf(exp2f(fmaf(sb[0], kLOG2E, -kSHIFT)),                     \
                    exp2f(fmaf(sb[1], kLOG2E, -kSHIFT)));                    \
      pw_[3] = pkbf(exp2f(fmaf(sb[2], kLOG2E, -kSHIFT)),                     \
                    exp2f(fmaf(sb[3], kLOG2E, -kSHIFT)));                    \
    }

#define NLCOMP(SRC)                                                          \
  {                                                                          \
    const ushort* bp_ = SRC;                                                 \
    const short8 pa0 = *(const short8*)&bp_[0 * 512 + lane * 8];             \
    const short8 pa1 = *(const short8*)&bp_[1 * 512 + lane * 8];             \
    const short8 pa2 = *(const short8*)&bp_[2 * 512 + lane * 8];             \
    const short8 pa3 = *(const short8*)&bp_[3 * 512 + lane * 8];             \
    const short8 pa4 = *(const short8*)&bp_[4 * 512 + lane * 8];             \
    const short8 pa5 = *(const short8*)&bp_[5 * 512 + lane * 8];             \
    const short8 pa6 = *(const short8*)&bp_[6 * 512 + lane * 8];             \
    const short8 pa7 = *(const short8*)&bp_[7 * 512 + lane * 8];             \
    const short8 ga0 = *(const short8*)&bp_[4096 + 0 * 512 + lane * 8];      \
    const short8 ga1 = *(const short8*)&bp_[4096 + 1 * 512 + lane * 8];      \
    const short8 ga2 = *(const short8*)&bp_[4096 + 2 * 512 + lane * 8];      \
    const short8 ga3 = *(const short8*)&bp_[4096 + 3 * 512 + lane * 8];      \
    const short8 ga4 = *(const short8*)&bp_[4096 + 4 * 512 + lane * 8];      \
    const short8 ga5 = *(const short8*)&bp_[4096 + 5 * 512 + lane * 8];      \
    const short8 ga6 = *(const short8*)&bp_[4096 + 6 * 512 + lane * 8];      \
    const short8 ga7 = *(const short8*)&bp_[4096 + 7 * 512 + lane * 8];      \
    {                                                                        \
      QKI(tA0k0, tA0k1, s00, s01, s02, s03)                                  \
      PACK2(s00, s01, pb00)                                                  \
      PACK2(s02, s03, pb01)                                                  \
      ay00 = __builtin_amdgcn_mfma_f32_16x16x32_bf16(ga0, pb00, ay00, 0, 0, 0);\
      ay01 = __builtin_amdgcn_mfma_f32_16x16x32_bf16(ga1, pb00, ay01, 0, 0, 0);\
      ay02 = __builtin_amdgcn_mfma_f32_16x16x32_bf16(ga2, pb00, ay02, 0, 0, 0);\
      ay03 = __builtin_amdgcn_mfma_f32_16x16x32_bf16(ga3, pb00, ay03, 0, 0, 0);\
      ay00 = __builtin_amdgcn_mfma_f32_16x16x32_bf16(ga4, pb01, ay00, 0, 0, 0);\
      ay01 = __builtin_amdgcn_mfma_f32_16x16x32_bf16(ga5, pb01, ay01, 0, 0, 0);\
      ay02 = __builtin_amdgcn_mfma_f32_16x16x32_bf16(ga6, pb01, ay02, 0, 0, 0);\
      ay03 = __builtin_amdgcn_mfma_f32_16x16x32_bf16(ga7, pb01, ay03, 0, 0, 0);\
    }                                                                        \
    {                                                                        \
      QKI(tA1k0, tA1k1, s10, s11, s12, s13)                                  \
      PACK2(s10, s11, pb10)                                                  \
      PACK2(s12, s13, pb11)                                                  \
      ay10 = __builtin_amdgcn_mfma_f32_16x16x32_bf16(ga0, pb10, ay10, 0, 0, 0);\
      ay11 = __builtin_amdgcn_mfma_f32_16x16x32_bf16(ga1, pb10, ay11, 0, 0, 0);\
      ay12 = __builtin_amdgcn_mfma_f32_16x16x32_bf16(ga2, pb10, ay12, 0, 0, 0);\
      ay13 = __builtin_amdgcn_mfma_f32_16x16x32_bf16(ga3, pb10, ay13, 0, 0, 0);\
      ay10 = __builtin_amdgcn_mfma_f32_16x16x32_bf16(ga4, pb11, ay10, 0, 0, 0);\
      ay11 = __builtin_amdgcn_mfma_f32_16x16x32_bf16(ga5, pb11, ay11, 0, 0, 0);\
      ay12 = __builtin_amdgcn_mfma_f32_16x16x32_bf16(ga6, pb11, ay12, 0, 0, 0);\
      ay13 = __builtin_amdgcn_mfma_f32_16x16x32_bf16(ga7, pb11, ay13, 0, 0, 0);\
    }                                                                        \
  }

  f32x4 ay00 = {0.f, 0.f, 0.f, 0.f}, ay01 = {0.f, 0.f, 0.f, 0.f};
  f32x4 ay02 = {0.f, 0.f, 0.f, 0.f}, ay03 = {0.f, 0.f, 0.f, 0.f};
  f32x4 ay10 = {0.f, 0.f, 0.f, 0.f}, ay11 = {0.f, 0.f, 0.f, 0.f};
  f32x4 ay12 = {0.f, 0.f, 0.f, 0.f}, ay13 = {0.f, 0.f, 0.f, 0.f};

  NLSTAGE(bufA);
  __syncthreads();
#pragma unroll 1
  for (int t = 0; t < NT / 2 - 1; ++t) {
    NLSTAGE(bufB);
    NLCOMP(bufA);
    __syncthreads();
    NLSTAGE(bufA);
    NLCOMP(bufB);
    __syncthreads();
  }
  NLSTAGE(bufB);
  NLCOMP(bufA);
  __syncthreads();
  NLCOMP(bufB);
#undef NLSTAGE
#undef NLCOMP
#undef QKI
#undef PACK2

  uint* b32 = (uint*)(py + ((size_t)(js * kB + b) * (kN / 32) + itile32) * 2048);
  b32[0 * 64 + lane] = pkbf(ay00[0], ay00[1]);
  b32[1 * 64 + lane] = pkbf(ay00[2], ay00[3]);
  b32[2 * 64 + lane] = pkbf(ay01[0], ay01[1]);
  b32[3 * 64 + lane] = pkbf(ay01[2], ay01[3]);
  b32[4 * 64 + lane] = pkbf(ay02[0], ay02[1]);
  b32[5 * 64 + lane] = pkbf(ay02[2], ay02[3]);
  b32[6 * 64 + lane] = pkbf(ay03[0], ay03[1]);
  b32[7 * 64 + lane] = pkbf(ay03[2], ay03[3]);
  b32[8 * 64 + lane] = pkbf(ay10[0], ay10[1]);
  b32[9 * 64 + lane] = pkbf(ay10[2], ay10[3]);
  b32[10 * 64 + lane] = pkbf(ay11[0], ay11[1]);
  b32[11 * 64 + lane] = pkbf(ay11[2], ay11[3]);
  b32[12 * 64 + lane] = pkbf(ay12[0], ay12[1]);
  b32[13 * 64 + lane] = pkbf(ay12[2], ay12[3]);
  b32[14 * 64 + lane] = pkbf(ay13[0], ay13[1]);
  b32[15 * 64 + lane] = pkbf(ay13[2], ay13[3]);
}

// ---- reduce SJ partials + fused W_y + residuals -> z bf16 pixel-major.
__global__ __launch_bounds__(128) void k_wy(
    const ushort* __restrict__ py, const __hip_bfloat16* __restrict__ wWb,
    const float* __restrict__ x1, const float* __restrict__ alphap,
    ushort* __restrict__ zb, int sj) {
  const int b = blockIdx.y;
  const int lane = threadIdx.x & 63, w = threadIdx.x >> 6;
  const int il = lane & 15, hi = lane >> 4;
  const int itile32 = blockIdx.x * 2 + w;
  const int i0w = itile32 * 32;

  __shared__ __align__(16) ushort yt2[2][32 * 72];
  __shared__ __align__(16) ushort zt2[2][32 * 72];
  ushort* yt = yt2[w];
  ushort* zt = zt2[w];

  float lo[16], hs[16];
#pragma unroll
  for (int k = 0; k < 16; ++k) { lo[k] = 0.f; hs[k] = 0.f; }
#pragma unroll 1
  for (int s = 0; s < sj; ++s) {
    const uint* ps =
        (const uint*)(py + ((size_t)(s * kB + b) * (kN / 32) + itile32) * 2048);
#pragma unroll
    for (int k = 0; k < 16; ++k) {
      const uint u = ps[k * 64 + lane];
      lo[k] += __uint_as_float(u << 16);
      hs[k] += __uint_as_float(u & 0xffff0000u);
    }
  }
#pragma unroll
  for (int k = 0; k < 16; ++k) {
    const int row = (k >> 3) * 16 + il;
    const int col = ((k >> 1) & 3) * 16 + hi * 4 + (k & 1) * 2;
    *(uint*)&yt[row * 72 + col] = pkbf(lo[k], hs[k]);
  }

  const float alpha = alphap[0];
#pragma unroll
  for (int a = 0; a < 2; ++a) {
    const short8 by0 = *(const short8*)&yt[(a * 16 + il) * 72 + hi * 8];
    const short8 by1 = *(const short8*)&yt[(a * 16 + il) * 72 + 32 + hi * 8];
#pragma unroll
    for (int q = 0; q < 4; ++q) {
      const short8 af0 = *(const short8*)&wWb[(size_t)(q * 16 + il) * kC + hi * 8];
      const short8 af1 = *(const short8*)&wWb[(size_t)(q * 16 + il) * kC + 32 + hi * 8];
      f32x4 o4 = {0.f, 0.f, 0.f, 0.f};
      o4 = __builtin_amdgcn_mfma_f32_16x16x32_bf16(af0, by0, o4, 0, 0, 0);
      o4 = __builtin_amdgcn_mfma_f32_16x16x32_bf16(af1, by1, o4, 0, 0, 0);
      float zv[4];
#pragma unroll
      for (int r = 0; r < 4; ++r) {
        const int o = q * 16 + hi * 4 + r;
        const size_t idx = ((size_t)b * kC + o) * kN + i0w + a * 16 + il;
        const float xv = x1[idx];
        const float pr = xv >= 0.f ? xv : alpha * xv;
        zv[r] = o4[r] + pr + xv;
      }
      *(uint*)&zt[(a * 16 + il) * 72 + q * 16 + hi * 4] = pkbf(zv[0], zv[1]);
      *(uint*)&zt[(a * 16 + il) * 72 + q * 16 + hi * 4 + 2] = pkbf(zv[2], zv[3]);
    }
  }

  const int px = lane >> 1, cseg = (lane & 1) * 32;
  short8* d = (short8*)&zb[((size_t)b * kN + i0w + px) * kC + cseg];
#pragma unroll
  for (int k = 0; k < 4; ++k)
    d[k] = *(const short8*)&zt[px * 72 + cseg + k * 8];
}

extern "C" void kernel_launch(void* const* d_in, const int* in_sizes, int n_in,
                              void* d_out, int out_size, void* d_ws, size_t ws_size,
                              hipStream_t stream) {
  const float* x      = (const float*)d_in[0];
  const float* w1     = (const float*)d_in[1];
  const float* w2     = (const float*)d_in[2];
  const float* wg     = (const float*)d_in[3];
  const float* wth    = (const float*)d_in[4];
  const float* wph    = (const float*)d_in[5];
  const float* wWm    = (const float*)d_in[6];
  const float* alphap = (const float*)d_in[7];
  float* out = (float*)d_out;

  const size_t SZ = (size_t)kB * kC * kN;  // 819200

  // footprint(SJ) in floats: x1 + 4 bf16 arrays + partial + weights + py
  auto footprint = [&](int SJ) -> size_t {
    size_t f = SZ;                 // x1
    f += 4 * (SZ / 2);             // pTb, phb, gb, gT (bf16)
    f += (size_t)kB * SJ * kN;     // partial
    f += (2 * 9 * kC * kC) / 2;    // wc1, wc2 (ushort)
    f += (3 * kC * kC) / 2;        // Mb, wgb, wWb
    f += (size_t)SJ * kB * (kN / 32) * 2048 / 2;  // py (ushort)
    return f * 4;                  // bytes
  };
  const int SJ = (ws_size >= footprint(10)) ? 10 : 5;
  const int chunk = kN / SJ;

  float* x1 = (float*)d_ws;
  __hip_bfloat16* pTb = (__hip_bfloat16*)(x1 + SZ);
  __hip_bfloat16* phb = pTb + SZ;
  __hip_bfloat16* gb  = phb + SZ;
  __hip_bfloat16* gT  = gb + SZ;
  float* partial = (float*)(gT + SZ);
  ushort* wc1 = (ushort*)(partial + (size_t)kB * SJ * kN);
  ushort* wc2 = wc1 + 9 * kC * kC;
  __hip_bfloat16* Mb  = (__hip_bfloat16*)(wc2 + 9 * kC * kC);
  __hip_bfloat16* wgb = Mb + kC * kC;
  __hip_bfloat16* wWb = wgb + kC * kC;
  ushort* py = (ushort*)(wWb + kC * kC);
  ushort* xb = py;                // overlay: dead before k_nl writes py
  ushort* zb = (ushort*)gb;       // overlay: gb dead after gscale

  k_prep<<<144, 256, 0, stream>>>(w1, w2, wc1, wc2);
  k_prepM<<<16, 256, 0, stream>>>(wth, wph, wg, wWm, Mb, wgb, wWb);
  k_tobf<<<dim3(kN / 64, kB), 256, 0, stream>>>(x, xb);
  k_convm<0><<<dim3(400, kB), 256, 0, stream>>>(xb, wc1, alphap, x1, (ushort*)pTb);
  k_pw<<<dim3(kN / 16, kB), 256, 0, stream>>>(pTb, Mb, wgb, phb, gb);
  k_colstat<<<dim3(kN / 64, SJ, kB), 128, 0, stream>>>(pTb, phb, partial, chunk, SJ);
  k_gscale<<<dim3(kN / 64, kB), 256, 0, stream>>>(gb, partial, gT, SJ);
  k_nl<<<dim3(kN / 64, SJ, kB), 128, 0, stream>>>(pTb, phb, gT, py, chunk);
  k_wy<<<dim3(kN / 64, kB), 128, 0, stream>>>(py, wWb, x1, alphap, zb, SJ);
  k_convm<1><<<dim3(400, kB), 256, 0, stream>>>(zb, wc2, alphap, out, nullptr);
}

// Round 12
// 127.284 us; speedup vs baseline: 1.0933x; 1.0933x over previous
//
#include <hip/hip_runtime.h>
#include <hip/hip_bf16.h>
#include <cstddef>

// NLBasicBlock fused, round 12: k_nl / k_colstat reshaped to 4-wave blocks
// sharing one staged tile (stage bytes per MFMA halved vs R10), SJ=5.
// R11 lesson: block count doesn't raise residency (~2.4 blocks/CU cap);
// waves-per-block and stage reuse do.

constexpr int kB = 2, kC = 64, kH = 80, kW = 80, kN = kH * kW;
constexpr int kSJ = 5, kChunk = kN / kSJ, kNT = kChunk / 64;  // 1280, 20
constexpr float kLOG2E = 1.4426950408889634f;
constexpr float kSHIFT = 28.853900817779268f;  // 20 * log2(e)

typedef __attribute__((ext_vector_type(8))) short short8;
typedef __attribute__((ext_vector_type(4))) float f32x4;

__device__ __forceinline__ uint pkbf(float a, float b) {
  union { __hip_bfloat162 h; uint u; } x;
  x.h.x = __float2bfloat16(a);
  x.h.y = __float2bfloat16(b);
  return x.u;
}

#define GL16(gsrc, ldst)                                                    \
  __builtin_amdgcn_global_load_lds(                                         \
      (__attribute__((address_space(1))) void*)(char*)(gsrc),               \
      (__attribute__((address_space(3))) void*)(ldst), 16, 0, 0)

// ---- conv weights -> bf16 MFMA B-fragment-linear
__global__ void k_prep(const float* __restrict__ w1, const float* __restrict__ w2,
                       ushort* __restrict__ wc1, ushort* __restrict__ wc2) {
  const int idx = blockIdx.x * 256 + threadIdx.x;  // 36864
  const int o = idx / (kC * 9);
  const int r = idx % (kC * 9);
  const int ci = r / 9, tap = r % 9;
  const int og = o >> 4, il = o & 15;
  const int kc = ci >> 5, hi = (ci >> 3) & 3, e = ci & 7;
  const int pos = ((tap * 2 + kc) * 4 + og) * 512 + (hi * 16 + il) * 8 + e;
  union { __hip_bfloat16 h; ushort u; } c1, c2;
  c1.h = __float2bfloat16(w1[idx]);
  c2.h = __float2bfloat16(w2[idx]);
  wc1[pos] = c1.u;
  wc2[pos] = c2.u;
}

// ---- M = Wth^T.Wph (bf16) + bf16 Wg, WW
__global__ void k_prepM(const float* __restrict__ wth, const float* __restrict__ wph,
                        const float* __restrict__ wg, const float* __restrict__ wWm,
                        __hip_bfloat16* __restrict__ Mb,
                        __hip_bfloat16* __restrict__ wgb,
                        __hip_bfloat16* __restrict__ wWb) {
  const int idx = blockIdx.x * 256 + threadIdx.x;  // 4096
  const int a = idx >> 6, bb = idx & 63;
  float s = 0.f;
  for (int o = 0; o < kC; ++o) s += wth[o * kC + a] * wph[o * kC + bb];
  Mb[idx] = __float2bfloat16(s);
  wgb[idx] = __float2bfloat16(wg[idx]);
  wWb[idx] = __float2bfloat16(wWm[idx]);
}

// ---- x f32 [B][C][N] -> bf16 pixel-major [B][N][C]
__global__ __launch_bounds__(256) void k_tobf(const float* __restrict__ x,
                                              ushort* __restrict__ xb) {
  const int b = blockIdx.y;
  const int j0 = blockIdx.x * 64;
  const int t = threadIdx.x;
  __shared__ ushort tile[64][68];
  {
    const int c = t >> 2, jseg = (t & 3) * 16;
    const float* s = &x[((size_t)b * kC + c) * kN + j0 + jseg];
#pragma unroll
    for (int k = 0; k < 16; ++k) {
      union { __hip_bfloat16 h; ushort u; } cv;
      cv.h = __float2bfloat16(s[k]);
      tile[c][jseg + k] = cv.u;
    }
  }
  __syncthreads();
  {
    const int j = t >> 2, cseg = (t & 3) * 16;
    union { short8 v; ushort u[8]; } o0, o1;
#pragma unroll
    for (int k = 0; k < 16; ++k) {
      const ushort u = tile[cseg + k][j];
      if (k < 8) o0.u[k] = u; else o1.u[k - 8] = u;
    }
    short8* d = (short8*)&xb[((size_t)b * kN + j0 + j) * kC + cseg];
    d[0] = o0.v;
    d[1] = o1.v;
  }
}

// ---- MFMA 3x3 reflect conv (R10)
template <int MODE>
__global__ __launch_bounds__(256) void k_convm(
    const ushort* __restrict__ xb, const ushort* __restrict__ wc,
    const float* __restrict__ alphap, float* __restrict__ raw,
    ushort* __restrict__ pt) {
  const int tile = blockIdx.x;  // 400 = 80 rows x 5 col-tiles
  const int b = blockIdx.y;
  const int r0 = tile / 5, c0 = (tile % 5) * 16;
  const int lane = threadIdx.x & 63, w = threadIdx.x >> 6;
  const int il = lane & 15, hi = lane >> 4;

  __shared__ ushort zt[16][72];

  short8 wt[9][2];
#pragma unroll
  for (int t = 0; t < 9; ++t)
#pragma unroll
    for (int kc = 0; kc < 2; ++kc)
      wt[t][kc] = *(const short8*)&wc[(size_t)((t * 2 + kc) * 4 + w) * 512 + lane * 8];

  int cl[3], rb[3];
#pragma unroll
  for (int d = 0; d < 3; ++d) {
    const int cc = c0 + il + d - 1;
    cl[d] = cc < 0 ? 1 : (cc > kW - 1 ? kW - 2 : cc);
    const int rr = r0 + d - 1;
    rb[d] = rr < 0 ? 1 : (rr > kH - 1 ? kH - 2 : rr);
  }
  const ushort* xB = xb + (size_t)b * kN * kC;

  f32x4 acc = {0.f, 0.f, 0.f, 0.f};
#pragma unroll
  for (int dh = 0; dh < 3; ++dh) {
    const int nb = rb[dh] * kW;
#pragma unroll
    for (int dw = 0; dw < 3; ++dw) {
      const ushort* src = &xB[(size_t)(nb + cl[dw]) * kC + hi * 8];
      const short8 a0 = *(const short8*)src;
      const short8 a1 = *(const short8*)(src + 32);
      acc = __builtin_amdgcn_mfma_f32_16x16x32_bf16(a0, wt[dh * 3 + dw][0], acc, 0, 0, 0);
      acc = __builtin_amdgcn_mfma_f32_16x16x32_bf16(a1, wt[dh * 3 + dw][1], acc, 0, 0, 0);
    }
  }

  const int n0 = r0 * kW + c0;
  const float alpha = alphap[0];
  if (MODE == 0) {
    *(f32x4*)&raw[((size_t)b * kC + w * 16 + il) * kN + n0 + hi * 4] = acc;
#pragma unroll
    for (int r = 0; r < 4; ++r) {
      const float v = acc[r];
      union { __hip_bfloat16 h; ushort u; } cv;
      cv.h = __float2bfloat16(v >= 0.f ? v : alpha * v);
      zt[hi * 4 + r][w * 16 + il] = cv.u;
    }
    __syncthreads();
    const int t = threadIdx.x;
    const int px = t >> 4, cb = (t & 15) * 4;
    uint2 o2;
    o2.x = (uint)zt[px][cb] | ((uint)zt[px][cb + 1] << 16);
    o2.y = (uint)zt[px][cb + 2] | ((uint)zt[px][cb + 3] << 16);
    *(uint2*)&pt[((size_t)b * kN + n0 + px) * kC + cb] = o2;
  } else {
    f32x4 pr;
#pragma unroll
    for (int r = 0; r < 4; ++r) {
      const float v = acc[r];
      pr[r] = v >= 0.f ? v : alpha * v;
    }
    *(f32x4*)&raw[((size_t)b * kC + w * 16 + il) * kN + n0 + hi * 4] = pr;
  }
}

// ---- phi' = M.p, g = Wg.p (bf16 pixel-major)
__global__ __launch_bounds__(256) void k_pw(
    const __hip_bfloat16* __restrict__ pTb, const __hip_bfloat16* __restrict__ Mb,
    const __hip_bfloat16* __restrict__ wgb, __hip_bfloat16* __restrict__ phb,
    __hip_bfloat16* __restrict__ gb) {
  const int b = blockIdx.y;
  const int lane = threadIdx.x & 63, w = threadIdx.x >> 6;
  const int il = lane & 15, hi = lane >> 4;
  const int n = blockIdx.x * 16 + il;

  const short8 b0 = *(const short8*)&pTb[((size_t)b * kN + n) * kC + hi * 8];
  const short8 b1 = *(const short8*)&pTb[((size_t)b * kN + n) * kC + 32 + hi * 8];

  const short8 am0 = *(const short8*)&Mb[(size_t)(w * 16 + il) * kC + hi * 8];
  const short8 am1 = *(const short8*)&Mb[(size_t)(w * 16 + il) * kC + 32 + hi * 8];
  f32x4 o4 = {0.f, 0.f, 0.f, 0.f};
  o4 = __builtin_amdgcn_mfma_f32_16x16x32_bf16(am0, b0, o4, 0, 0, 0);
  o4 = __builtin_amdgcn_mfma_f32_16x16x32_bf16(am1, b1, o4, 0, 0, 0);
  uint2 p2;
  p2.x = pkbf(o4[0], o4[1]);
  p2.y = pkbf(o4[2], o4[3]);
  *(uint2*)&phb[((size_t)b * kN + n) * kC + w * 16 + hi * 4] = p2;

  const short8 ag0 = *(const short8*)&wgb[(size_t)(w * 16 + il) * kC + hi * 8];
  const short8 ag1 = *(const short8*)&wgb[(size_t)(w * 16 + il) * kC + 32 + hi * 8];
  f32x4 g4 = {0.f, 0.f, 0.f, 0.f};
  g4 = __builtin_amdgcn_mfma_f32_16x16x32_bf16(ag0, b0, g4, 0, 0, 0);
  g4 = __builtin_amdgcn_mfma_f32_16x16x32_bf16(ag1, b1, g4, 0, 0, 0);
  uint2 g2;
  g2.x = pkbf(g4[0], g4[1]);
  g2.y = pkbf(g4[2], g4[3]);
  *(uint2*)&gb[((size_t)b * kN + n) * kC + w * 16 + hi * 4] = g2;
}

// ---- column sums: 4 waves x 32 j share one staged theta tile (8KB),
// i streamed in 64-tiles, split kSJ.
__global__ __launch_bounds__(256, 2) void k_colstat(
    const __hip_bfloat16* __restrict__ th, const __hip_bfloat16* __restrict__ ph,
    float* __restrict__ partial) {
  const int b = blockIdx.z, ic = blockIdx.y;
  const int lane = threadIdx.x & 63, w = threadIdx.x >> 6;
  const int il = lane & 15, hi = lane >> 4;
  const int j0w = blockIdx.x * 128 + w * 32;

  __shared__ __align__(16) ushort tbufA[4096], tbufB[4096];

  const __hip_bfloat16* thB = th + (size_t)b * kN * kC;
  const size_t phr0 = ((size_t)b * kN + j0w + il) * kC;
  const size_t phr1 = ((size_t)b * kN + j0w + 16 + il) * kC;
  const short8 a00 = *(const short8*)&ph[phr0 + hi * 8];
  const short8 a01 = *(const short8*)&ph[phr0 + 32 + hi * 8];
  const short8 a10 = *(const short8*)&ph[phr1 + hi * 8];
  const short8 a11 = *(const short8*)&ph[phr1 + 32 + hi * 8];

  // theta frag f (0..7): row i = (f>>1)*16 + il, col = (f&1)*32 + hi*8.
  // Wave w stages f = 2w, 2w+1.
  const int f0 = 2 * w;
  const char* st[2];
#pragma unroll
  for (int k = 0; k < 2; ++k) {
    const int f = f0 + k;
    st[k] = (const char*)&thB[(size_t)(ic * kChunk + (f >> 1) * 16 + il) * kC +
                              (f & 1) * 32 + hi * 8];
  }

#define CSTAGE(DST)                                                         \
  {                                                                         \
    _Pragma("unroll") for (int k = 0; k < 2; ++k) {                         \
      GL16(st[k], &DST[(f0 + k) * 512]);                                    \
      st[k] += (size_t)64 * kC * 2;                                         \
    }                                                                       \
  }

#define CCOMP(SRC)                                                         \
  {                                                                        \
    const ushort* bp_ = SRC;                                               \
    _Pragma("unroll") for (int s = 0; s < 4; ++s) {                        \
      const short8 bf0 = *(const short8*)&bp_[(2 * s) * 512 + lane * 8];   \
      const short8 bf1 = *(const short8*)&bp_[(2 * s + 1) * 512 + lane * 8];\
      f32x4 sj0 = {0.f, 0.f, 0.f, 0.f};                                    \
      f32x4 sj1 = {0.f, 0.f, 0.f, 0.f};                                    \
      sj0 = __builtin_amdgcn_mfma_f32_16x16x32_bf16(a00, bf0, sj0, 0, 0, 0);\
      sj0 = __builtin_amdgcn_mfma_f32_16x16x32_bf16(a01, bf1, sj0, 0, 0, 0);\
      sj1 = __builtin_amdgcn_mfma_f32_16x16x32_bf16(a10, bf0, sj1, 0, 0, 0);\
      sj1 = __builtin_amdgcn_mfma_f32_16x16x32_bf16(a11, bf1, sj1, 0, 0, 0);\
      _Pragma("unroll") for (int r = 0; r < 4; ++r) {                      \
        cs0[r] += exp2f(fmaf(sj0[r], kLOG2E, -kSHIFT));                    \
        cs1[r] += exp2f(fmaf(sj1[r], kLOG2E, -kSHIFT));                    \
      }                                                                    \
    }                                                                      \
  }

  float cs0[4] = {0.f, 0.f, 0.f, 0.f};
  float cs1[4] = {0.f, 0.f, 0.f, 0.f};
  CSTAGE(tbufA);
  __syncthreads();
#pragma unroll 1
  for (int t = 0; t < kNT / 2 - 1; ++t) {
    CSTAGE(tbufB);
    CCOMP(tbufA);
    __syncthreads();
    CSTAGE(tbufA);
    CCOMP(tbufB);
    __syncthreads();
  }
  CSTAGE(tbufB);
  CCOMP(tbufA);
  __syncthreads();
  CCOMP(tbufB);
#undef CSTAGE
#undef CCOMP

#pragma unroll
  for (int r = 0; r < 4; ++r) {
    cs0[r] += __shfl_xor(cs0[r], 1); cs1[r] += __shfl_xor(cs1[r], 1);
    cs0[r] += __shfl_xor(cs0[r], 2); cs1[r] += __shfl_xor(cs1[r], 2);
    cs0[r] += __shfl_xor(cs0[r], 4); cs1[r] += __shfl_xor(cs1[r], 4);
    cs0[r] += __shfl_xor(cs0[r], 8); cs1[r] += __shfl_xor(cs1[r], 8);
  }
  if (il == 0) {
    float* p = partial + (size_t)(b * kSJ + ic) * kN + j0w + hi * 4;
#pragma unroll
    for (int r = 0; r < 4; ++r) {
      p[r] = cs0[r];
      p[16 + r] = cs1[r];
    }
  }
}

// ---- gT[b][c][j] = bf16( g[b][j][c] * 1/colsum[b][j] )
__global__ __launch_bounds__(256) void k_gscale(
    const __hip_bfloat16* __restrict__ gb, const float* __restrict__ partial,
    __hip_bfloat16* __restrict__ gT) {
  const int b = blockIdx.y;
  const int j0 = blockIdx.x * 64;
  const int t = threadIdx.x;
  __shared__ ushort tile[64][66];
  __shared__ float rsv[64];
  if (t < 64) {
    const int j = j0 + t;
    float cs = 0.f;
#pragma unroll
    for (int s = 0; s < kSJ; ++s) cs += partial[(size_t)(b * kSJ + s) * kN + j];
    rsv[t] = 1.0f / cs;
  }
  {
    const int jl = t >> 2, cseg = (t & 3) * 16;
    const ushort* src = (const ushort*)&gb[((size_t)b * kN + j0 + jl) * kC + cseg];
    union { short8 v; ushort u[8]; } u0, u1;
    u0.v = *(const short8*)src;
    u1.v = *(const short8*)(src + 8);
#pragma unroll
    for (int k = 0; k < 8; ++k) {
      tile[jl][cseg + k] = u0.u[k];
      tile[jl][cseg + 8 + k] = u1.u[k];
    }
  }
  __syncthreads();
  const int c = t >> 2, jseg = (t & 3) * 16;
  union { short8 v; ushort u[8]; } o0, o1;
#pragma unroll
  for (int k = 0; k < 16; ++k) {
    const int j = jseg + k;
    const float gv = __uint_as_float((uint)tile[j][c] << 16);
    union { __hip_bfloat16 h; ushort us; } cv;
    cv.h = __float2bfloat16(gv * rsv[j]);
    if (k < 8) o0.u[k] = cv.us; else o1.u[k - 8] = cv.us;
  }
  short8* dst = (short8*)&gT[((size_t)b * kC + c) * kN + j0 + jseg];
  dst[0] = o0.v;
  dst[1] = o1.v;
}

// ---- pass B: 4 waves x 32 i share one staged phi+gT tile (16KB), split kSJ.
__global__ __launch_bounds__(256, 2) void k_nl(
    const __hip_bfloat16* __restrict__ th, const __hip_bfloat16* __restrict__ ph,
    const __hip_bfloat16* __restrict__ gT, ushort* __restrict__ py) {
  const int js = blockIdx.y, b = blockIdx.z;
  const int lane = threadIdx.x & 63, w = threadIdx.x >> 6;
  const int il = lane & 15, hi = lane >> 4;
  const int itile32 = blockIdx.x * 4 + w;
  const int i0w = itile32 * 32;
  const int jstart = js * kChunk;
  const int jbase = ((il >> 2) << 3) + (il & 3);  // sigma(row=il)

  __shared__ __align__(16) ushort bufA[8192], bufB[8192];

  const __hip_bfloat16* phB = ph + (size_t)b * kN * kC;
  const __hip_bfloat16* gTB = gT + (size_t)b * kC * kN;

  const size_t tr0 = ((size_t)b * kN + i0w + il) * kC;
  const size_t tr1 = ((size_t)b * kN + i0w + 16 + il) * kC;
  const short8 tA0k0 = *(const short8*)&th[tr0 + hi * 8];
  const short8 tA0k1 = *(const short8*)&th[tr0 + 32 + hi * 8];
  const short8 tA1k0 = *(const short8*)&th[tr1 + hi * 8];
  const short8 tA1k1 = *(const short8*)&th[tr1 + 32 + hi * 8];

  // Wave w stages phi frags 2w,2w+1 and gT frags 2w,2w+1.
  const int f0 = 2 * w;
  const char* sp[2];
  const char* sg[2];
#pragma unroll
  for (int k = 0; k < 2; ++k) {
    const int f = f0 + k;
    const int pr = jstart + jbase + ((f >> 1) & 1) * 4 + ((f >> 2) & 1) * 32;
    const int pc = (f & 1) * 32 + hi * 8;
    sp[k] = (const char*)&phB[(size_t)pr * kC + pc];
    const int gc = (f & 3) * 16 + il;
    const int gj = jstart + ((f >> 2) & 1) * 32 + hi * 8;
    sg[k] = (const char*)&gTB[(size_t)gc * kN + gj];
  }

#define NLSTAGE(DST)                                                        \
  {                                                                         \
    _Pragma("unroll") for (int k = 0; k < 2; ++k) {                         \
      GL16(sp[k], &DST[(f0 + k) * 512]);                                    \
      GL16(sg[k], &DST[4096 + (f0 + k) * 512]);                             \
      sp[k] += (size_t)64 * kC * 2;                                         \
      sg[k] += (size_t)64 * 2;                                              \
    }                                                                       \
  }

#define QKI(TB0, TB1, s0, s1, s2, s3)                                        \
    f32x4 s0 = {0.f, 0.f, 0.f, 0.f};                                         \
    f32x4 s1 = {0.f, 0.f, 0.f, 0.f};                                         \
    f32x4 s2 = {0.f, 0.f, 0.f, 0.f};                                         \
    f32x4 s3 = {0.f, 0.f, 0.f, 0.f};                                         \
    s0 = __builtin_amdgcn_mfma_f32_16x16x32_bf16(pa0, TB0, s0, 0, 0, 0);     \
    s0 = __builtin_amdgcn_mfma_f32_16x16x32_bf16(pa1, TB1, s0, 0, 0, 0);     \
    s1 = __builtin_amdgcn_mfma_f32_16x16x32_bf16(pa2, TB0, s1, 0, 0, 0);     \
    s1 = __builtin_amdgcn_mfma_f32_16x16x32_bf16(pa3, TB1, s1, 0, 0, 0);     \
    s2 = __builtin_amdgcn_mfma_f32_16x16x32_bf16(pa4, TB0, s2, 0, 0, 0);     \
    s2 = __builtin_amdgcn_mfma_f32_16x16x32_bf16(pa5, TB1, s2, 0, 0, 0);     \
    s3 = __builtin_amdgcn_mfma_f32_16x16x32_bf16(pa6, TB0, s3, 0, 0, 0);     \
    s3 = __builtin_amdgcn_mfma_f32_16x16x32_bf16(pa7, TB1, s3, 0, 0, 0);

#define PACK2(sa, sb, pb)                                                    \
    short8 pb;                                                               \
    {                                                                        \
      uint* pw_ = (uint*)&pb;                                                \
      pw_[0] = pkbf(exp2f(fmaf(sa[0], kLOG2E, -kSHIFT)),                     \
                    exp2f(fmaf(sa[1], kLOG2E, -kSHIFT)));                    \
      pw_[1] = pkbf(exp2f(fmaf(sa[2], kLOG2E, -kSHIFT)),                     \
                    exp2f(fmaf(sa[3], kLOG2E, -kSHIFT)));                    \
      pw_[2] = pkbf(exp2f(fmaf(sb[0], kLOG2E, -kSHIFT)),                     \
                    exp2f(fmaf(sb[1], kLOG2E, -kSHIFT)));                    \
      pw_[3] = pkbf(exp2f(fmaf(sb[2], kLOG2E, -kSHIFT)),                     \
                    exp2f(fmaf(sb[3], kLOG2E, -kSHIFT)));                    \
    }

#define NLCOMP(SRC)                                                          \
  {                                                                          \
    const ushort* bp_ = SRC;                                                 \
    const short8 pa0 = *(const short8*)&bp_[0 * 512 + lane * 8];             \
    const short8 pa1 = *(const short8*)&bp_[1 * 512 + lane * 8];             \
    const short8 pa2 = *(const short8*)&bp_[2 * 512 + lane * 8];             \
    const short8 pa3 = *(const short8*)&bp_[3 * 512 + lane * 8];             \
    const short8 pa4 = *(const short8*)&bp_[4 * 512 + lane * 8];             \
    const short8 pa5 = *(const short8*)&bp_[5 * 512 + lane * 8];             \
    const short8 pa6 = *(const short8*)&bp_[6 * 512 + lane * 8];             \
    const short8 pa7 = *(const short8*)&bp_[7 * 512 + lane * 8];             \
    const short8 ga0 = *(const short8*)&bp_[4096 + 0 * 512 + lane * 8];      \
    const short8 ga1 = *(const short8*)&bp_[4096 + 1 * 512 + lane * 8];      \
    const short8 ga2 = *(const short8*)&bp_[4096 + 2 * 512 + lane * 8];      \
    const short8 ga3 = *(const short8*)&bp_[4096 + 3 * 512 + lane * 8];      \
    const short8 ga4 = *(const short8*)&bp_[4096 + 4 * 512 + lane * 8];      \
    const short8 ga5 = *(const short8*)&bp_[4096 + 5 * 512 + lane * 8];      \
    const short8 ga6 = *(const short8*)&bp_[4096 + 6 * 512 + lane * 8];      \
    const short8 ga7 = *(const short8*)&bp_[4096 + 7 * 512 + lane * 8];      \
    {                                                                        \
      QKI(tA0k0, tA0k1, s00, s01, s02, s03)                                  \
      PACK2(s00, s01, pb00)                                                  \
      PACK2(s02, s03, pb01)                                                  \
      ay00 = __builtin_amdgcn_mfma_f32_16x16x32_bf16(ga0, pb00, ay00, 0, 0, 0);\
      ay01 = __builtin_amdgcn_mfma_f32_16x16x32_bf16(ga1, pb00, ay01, 0, 0, 0);\
      ay02 = __builtin_amdgcn_mfma_f32_16x16x32_bf16(ga2, pb00, ay02, 0, 0, 0);\
      ay03 = __builtin_amdgcn_mfma_f32_16x16x32_bf16(ga3, pb00, ay03, 0, 0, 0);\
      ay00 = __builtin_amdgcn_mfma_f32_16x16x32_bf16(ga4, pb01, ay00, 0, 0, 0);\
      ay01 = __builtin_amdgcn_mfma_f32_16x16x32_bf16(ga5, pb01, ay01, 0, 0, 0);\
      ay02 = __builtin_amdgcn_mfma_f32_16x16x32_bf16(ga6, pb01, ay02, 0, 0, 0);\
      ay03 = __builtin_amdgcn_mfma_f32_16x16x32_bf16(ga7, pb01, ay03, 0, 0, 0);\
    }                                                                        \
    {                                                                        \
      QKI(tA1k0, tA1k1, s10, s11, s12, s13)                                  \
      PACK2(s10, s11, pb10)                                                  \
      PACK2(s12, s13, pb11)                                                  \
      ay10 = __builtin_amdgcn_mfma_f32_16x16x32_bf16(ga0, pb10, ay10, 0, 0, 0);\
      ay11 = __builtin_amdgcn_mfma_f32_16x16x32_bf16(ga1, pb10, ay11, 0, 0, 0);\
      ay12 = __builtin_amdgcn_mfma_f32_16x16x32_bf16(ga2, pb10, ay12, 0, 0, 0);\
      ay13 = __builtin_amdgcn_mfma_f32_16x16x32_bf16(ga3, pb10, ay13, 0, 0, 0);\
      ay10 = __builtin_amdgcn_mfma_f32_16x16x32_bf16(ga4, pb11, ay10, 0, 0, 0);\
      ay11 = __builtin_amdgcn_mfma_f32_16x16x32_bf16(ga5, pb11, ay11, 0, 0, 0);\
      ay12 = __builtin_amdgcn_mfma_f32_16x16x32_bf16(ga6, pb11, ay12, 0, 0, 0);\
      ay13 = __builtin_amdgcn_mfma_f32_16x16x32_bf16(ga7, pb11, ay13, 0, 0, 0);\
    }                                                                        \
  }

  f32x4 ay00 = {0.f, 0.f, 0.f, 0.f}, ay01 = {0.f, 0.f, 0.f, 0.f};
  f32x4 ay02 = {0.f, 0.f, 0.f, 0.f}, ay03 = {0.f, 0.f, 0.f, 0.f};
  f32x4 ay10 = {0.f, 0.f, 0.f, 0.f}, ay11 = {0.f, 0.f, 0.f, 0.f};
  f32x4 ay12 = {0.f, 0.f, 0.f, 0.f}, ay13 = {0.f, 0.f, 0.f, 0.f};

  NLSTAGE(bufA);
  __syncthreads();
#pragma unroll 1
  for (int t = 0; t < kNT / 2 - 1; ++t) {
    NLSTAGE(bufB);
    NLCOMP(bufA);
    __syncthreads();
    NLSTAGE(bufA);
    NLCOMP(bufB);
    __syncthreads();
  }
  NLSTAGE(bufB);
  NLCOMP(bufA);
  __syncthreads();
  NLCOMP(bufB);
#undef NLSTAGE
#undef NLCOMP
#undef QKI
#undef PACK2

  uint* b32 = (uint*)(py + ((size_t)(js * kB + b) * (kN / 32) + itile32) * 2048);
  b32[0 * 64 + lane] = pkbf(ay00[0], ay00[1]);
  b32[1 * 64 + lane] = pkbf(ay00[2], ay00[3]);
  b32[2 * 64 + lane] = pkbf(ay01[0], ay01[1]);
  b32[3 * 64 + lane] = pkbf(ay01[2], ay01[3]);
  b32[4 * 64 + lane] = pkbf(ay02[0], ay02[1]);
  b32[5 * 64 + lane] = pkbf(ay02[2], ay02[3]);
  b32[6 * 64 + lane] = pkbf(ay03[0], ay03[1]);
  b32[7 * 64 + lane] = pkbf(ay03[2], ay03[3]);
  b32[8 * 64 + lane] = pkbf(ay10[0], ay10[1]);
  b32[9 * 64 + lane] = pkbf(ay10[2], ay10[3]);
  b32[10 * 64 + lane] = pkbf(ay11[0], ay11[1]);
  b32[11 * 64 + lane] = pkbf(ay11[2], ay11[3]);
  b32[12 * 64 + lane] = pkbf(ay12[0], ay12[1]);
  b32[13 * 64 + lane] = pkbf(ay12[2], ay12[3]);
  b32[14 * 64 + lane] = pkbf(ay13[0], ay13[1]);
  b32[15 * 64 + lane] = pkbf(ay13[2], ay13[3]);
}

// ---- reduce kSJ partials + fused W_y + residuals -> z bf16 pixel-major.
__global__ __launch_bounds__(128) void k_wy(
    const ushort* __restrict__ py, const __hip_bfloat16* __restrict__ wWb,
    const float* __restrict__ x1, const float* __restrict__ alphap,
    ushort* __restrict__ zb) {
  const int b = blockIdx.y;
  const int lane = threadIdx.x & 63, w = threadIdx.x >> 6;
  const int il = lane & 15, hi = lane >> 4;
  const int itile32 = blockIdx.x * 2 + w;
  const int i0w = itile32 * 32;

  __shared__ __align__(16) ushort yt2[2][32 * 72];
  __shared__ __align__(16) ushort zt2[2][32 * 72];
  ushort* yt = yt2[w];
  ushort* zt = zt2[w];

  float lo[16], hs[16];
#pragma unroll
  for (int k = 0; k < 16; ++k) { lo[k] = 0.f; hs[k] = 0.f; }
#pragma unroll
  for (int s = 0; s < kSJ; ++s) {
    const uint* ps =
        (const uint*)(py + ((size_t)(s * kB + b) * (kN / 32) + itile32) * 2048);
#pragma unroll
    for (int k = 0; k < 16; ++k) {
      const uint u = ps[k * 64 + lane];
      lo[k] += __uint_as_float(u << 16);
      hs[k] += __uint_as_float(u & 0xffff0000u);
    }
  }
#pragma unroll
  for (int k = 0; k < 16; ++k) {
    const int row = (k >> 3) * 16 + il;
    const int col = ((k >> 1) & 3) * 16 + hi * 4 + (k & 1) * 2;
    *(uint*)&yt[row * 72 + col] = pkbf(lo[k], hs[k]);
  }

  const float alpha = alphap[0];
#pragma unroll
  for (int a = 0; a < 2; ++a) {
    const short8 by0 = *(const short8*)&yt[(a * 16 + il) * 72 + hi * 8];
    const short8 by1 = *(const short8*)&yt[(a * 16 + il) * 72 + 32 + hi * 8];
#pragma unroll
    for (int q = 0; q < 4; ++q) {
      const short8 af0 = *(const short8*)&wWb[(size_t)(q * 16 + il) * kC + hi * 8];
      const short8 af1 = *(const short8*)&wWb[(size_t)(q * 16 + il) * kC + 32 + hi * 8];
      f32x4 o4 = {0.f, 0.f, 0.f, 0.f};
      o4 = __builtin_amdgcn_mfma_f32_16x16x32_bf16(af0, by0, o4, 0, 0, 0);
      o4 = __builtin_amdgcn_mfma_f32_16x16x32_bf16(af1, by1, o4, 0, 0, 0);
      float zv[4];
#pragma unroll
      for (int r = 0; r < 4; ++r) {
        const int o = q * 16 + hi * 4 + r;
        const size_t idx = ((size_t)b * kC + o) * kN + i0w + a * 16 + il;
        const float xv = x1[idx];
        const float pr = xv >= 0.f ? xv : alpha * xv;
        zv[r] = o4[r] + pr + xv;
      }
      *(uint*)&zt[(a * 16 + il) * 72 + q * 16 + hi * 4] = pkbf(zv[0], zv[1]);
      *(uint*)&zt[(a * 16 + il) * 72 + q * 16 + hi * 4 + 2] = pkbf(zv[2], zv[3]);
    }
  }

  const int px = lane >> 1, cseg = (lane & 1) * 32;
  short8* d = (short8*)&zb[((size_t)b * kN + i0w + px) * kC + cseg];
#pragma unroll
  for (int k = 0; k < 4; ++k)
    d[k] = *(const short8*)&zt[px * 72 + cseg + k * 8];
}

extern "C" void kernel_launch(void* const* d_in, const int* in_sizes, int n_in,
                              void* d_out, int out_size, void* d_ws, size_t ws_size,
                              hipStream_t stream) {
  const float* x      = (const float*)d_in[0];
  const float* w1     = (const float*)d_in[1];
  const float* w2     = (const float*)d_in[2];
  const float* wg     = (const float*)d_in[3];
  const float* wth    = (const float*)d_in[4];
  const float* wph    = (const float*)d_in[5];
  const float* wWm    = (const float*)d_in[6];
  const float* alphap = (const float*)d_in[7];
  float* out = (float*)d_out;

  const size_t SZ = (size_t)kB * kC * kN;  // 819200

  float* x1 = (float*)d_ws;
  __hip_bfloat16* pTb = (__hip_bfloat16*)(x1 + SZ);
  __hip_bfloat16* phb = pTb + SZ;
  __hip_bfloat16* gb  = phb + SZ;
  __hip_bfloat16* gT  = gb + SZ;
  float* partial = (float*)(gT + SZ);
  ushort* wc1 = (ushort*)(partial + (size_t)kB * kSJ * kN);
  ushort* wc2 = wc1 + 9 * kC * kC;
  __hip_bfloat16* Mb  = (__hip_bfloat16*)(wc2 + 9 * kC * kC);
  __hip_bfloat16* wgb = Mb + kC * kC;
  __hip_bfloat16* wWb = wgb + kC * kC;
  ushort* py = (ushort*)(wWb + kC * kC);
  ushort* xb = py;                // overlay: dead before k_nl writes py
  ushort* zb = (ushort*)gb;       // overlay: gb dead after gscale

  k_prep<<<144, 256, 0, stream>>>(w1, w2, wc1, wc2);
  k_prepM<<<16, 256, 0, stream>>>(wth, wph, wg, wWm, Mb, wgb, wWb);
  k_tobf<<<dim3(kN / 64, kB), 256, 0, stream>>>(x, xb);
  k_convm<0><<<dim3(400, kB), 256, 0, stream>>>(xb, wc1, alphap, x1, (ushort*)pTb);
  k_pw<<<dim3(kN / 16, kB), 256, 0, stream>>>(pTb, Mb, wgb, phb, gb);
  k_colstat<<<dim3(kN / 128, kSJ, kB), 256, 0, stream>>>(pTb, phb, partial);
  k_gscale<<<dim3(kN / 64, kB), 256, 0, stream>>>(gb, partial, gT);
  k_nl<<<dim3(kN / 128, kSJ, kB), 256, 0, stream>>>(pTb, phb, gT, py);
  k_wy<<<dim3(kN / 64, kB), 128, 0, stream>>>(py, wWb, x1, alphap, zb);
  k_convm<1><<<dim3(400, kB), 256, 0, stream>>>(zb, wc2, alphap, out, nullptr);
}

// Round 13
// 123.725 us; speedup vs baseline: 1.1248x; 1.0288x over previous
//
#include <hip/hip_runtime.h>
#include <hip/hip_bf16.h>
#include <cstddef>

// NLBasicBlock fused, round 13: 4-wave shared-stage blocks (R12) x SJ=10
// (R11) -> k_nl/k_colstat grid 1000 blocks (3.9/CU, ~15.6 waves/CU).
// R11's SJ=10 regression was at 16-i-per-wave blocks (stage reuse too low);
// with 4x32-i sharing each staged tile the fixed costs amortize.

constexpr int kB = 2, kC = 64, kH = 80, kW = 80, kN = kH * kW;
constexpr int kSJ = 10, kChunk = kN / kSJ, kNT = kChunk / 64;  // 640, 10
constexpr float kLOG2E = 1.4426950408889634f;
constexpr float kSHIFT = 28.853900817779268f;  // 20 * log2(e)

typedef __attribute__((ext_vector_type(8))) short short8;
typedef __attribute__((ext_vector_type(4))) float f32x4;

__device__ __forceinline__ uint pkbf(float a, float b) {
  union { __hip_bfloat162 h; uint u; } x;
  x.h.x = __float2bfloat16(a);
  x.h.y = __float2bfloat16(b);
  return x.u;
}

#define GL16(gsrc, ldst)                                                    \
  __builtin_amdgcn_global_load_lds(                                         \
      (__attribute__((address_space(1))) void*)(char*)(gsrc),               \
      (__attribute__((address_space(3))) void*)(ldst), 16, 0, 0)

// ---- conv weights -> bf16 MFMA B-fragment-linear
__global__ void k_prep(const float* __restrict__ w1, const float* __restrict__ w2,
                       ushort* __restrict__ wc1, ushort* __restrict__ wc2) {
  const int idx = blockIdx.x * 256 + threadIdx.x;  // 36864
  const int o = idx / (kC * 9);
  const int r = idx % (kC * 9);
  const int ci = r / 9, tap = r % 9;
  const int og = o >> 4, il = o & 15;
  const int kc = ci >> 5, hi = (ci >> 3) & 3, e = ci & 7;
  const int pos = ((tap * 2 + kc) * 4 + og) * 512 + (hi * 16 + il) * 8 + e;
  union { __hip_bfloat16 h; ushort u; } c1, c2;
  c1.h = __float2bfloat16(w1[idx]);
  c2.h = __float2bfloat16(w2[idx]);
  wc1[pos] = c1.u;
  wc2[pos] = c2.u;
}

// ---- M = Wth^T.Wph (bf16) + bf16 Wg, WW
__global__ void k_prepM(const float* __restrict__ wth, const float* __restrict__ wph,
                        const float* __restrict__ wg, const float* __restrict__ wWm,
                        __hip_bfloat16* __restrict__ Mb,
                        __hip_bfloat16* __restrict__ wgb,
                        __hip_bfloat16* __restrict__ wWb) {
  const int idx = blockIdx.x * 256 + threadIdx.x;  // 4096
  const int a = idx >> 6, bb = idx & 63;
  float s = 0.f;
  for (int o = 0; o < kC; ++o) s += wth[o * kC + a] * wph[o * kC + bb];
  Mb[idx] = __float2bfloat16(s);
  wgb[idx] = __float2bfloat16(wg[idx]);
  wWb[idx] = __float2bfloat16(wWm[idx]);
}

// ---- x f32 [B][C][N] -> bf16 pixel-major [B][N][C]
__global__ __launch_bounds__(256) void k_tobf(const float* __restrict__ x,
                                              ushort* __restrict__ xb) {
  const int b = blockIdx.y;
  const int j0 = blockIdx.x * 64;
  const int t = threadIdx.x;
  __shared__ ushort tile[64][68];
  {
    const int c = t >> 2, jseg = (t & 3) * 16;
    const float* s = &x[((size_t)b * kC + c) * kN + j0 + jseg];
#pragma unroll
    for (int k = 0; k < 16; ++k) {
      union { __hip_bfloat16 h; ushort u; } cv;
      cv.h = __float2bfloat16(s[k]);
      tile[c][jseg + k] = cv.u;
    }
  }
  __syncthreads();
  {
    const int j = t >> 2, cseg = (t & 3) * 16;
    union { short8 v; ushort u[8]; } o0, o1;
#pragma unroll
    for (int k = 0; k < 16; ++k) {
      const ushort u = tile[cseg + k][j];
      if (k < 8) o0.u[k] = u; else o1.u[k - 8] = u;
    }
    short8* d = (short8*)&xb[((size_t)b * kN + j0 + j) * kC + cseg];
    d[0] = o0.v;
    d[1] = o1.v;
  }
}

// ---- MFMA 3x3 reflect conv (R10)
template <int MODE>
__global__ __launch_bounds__(256) void k_convm(
    const ushort* __restrict__ xb, const ushort* __restrict__ wc,
    const float* __restrict__ alphap, float* __restrict__ raw,
    ushort* __restrict__ pt) {
  const int tile = blockIdx.x;  // 400 = 80 rows x 5 col-tiles
  const int b = blockIdx.y;
  const int r0 = tile / 5, c0 = (tile % 5) * 16;
  const int lane = threadIdx.x & 63, w = threadIdx.x >> 6;
  const int il = lane & 15, hi = lane >> 4;

  __shared__ ushort zt[16][72];

  short8 wt[9][2];
#pragma unroll
  for (int t = 0; t < 9; ++t)
#pragma unroll
    for (int kc = 0; kc < 2; ++kc)
      wt[t][kc] = *(const short8*)&wc[(size_t)((t * 2 + kc) * 4 + w) * 512 + lane * 8];

  int cl[3], rb[3];
#pragma unroll
  for (int d = 0; d < 3; ++d) {
    const int cc = c0 + il + d - 1;
    cl[d] = cc < 0 ? 1 : (cc > kW - 1 ? kW - 2 : cc);
    const int rr = r0 + d - 1;
    rb[d] = rr < 0 ? 1 : (rr > kH - 1 ? kH - 2 : rr);
  }
  const ushort* xB = xb + (size_t)b * kN * kC;

  f32x4 acc = {0.f, 0.f, 0.f, 0.f};
#pragma unroll
  for (int dh = 0; dh < 3; ++dh) {
    const int nb = rb[dh] * kW;
#pragma unroll
    for (int dw = 0; dw < 3; ++dw) {
      const ushort* src = &xB[(size_t)(nb + cl[dw]) * kC + hi * 8];
      const short8 a0 = *(const short8*)src;
      const short8 a1 = *(const short8*)(src + 32);
      acc = __builtin_amdgcn_mfma_f32_16x16x32_bf16(a0, wt[dh * 3 + dw][0], acc, 0, 0, 0);
      acc = __builtin_amdgcn_mfma_f32_16x16x32_bf16(a1, wt[dh * 3 + dw][1], acc, 0, 0, 0);
    }
  }

  const int n0 = r0 * kW + c0;
  const float alpha = alphap[0];
  if (MODE == 0) {
    *(f32x4*)&raw[((size_t)b * kC + w * 16 + il) * kN + n0 + hi * 4] = acc;
#pragma unroll
    for (int r = 0; r < 4; ++r) {
      const float v = acc[r];
      union { __hip_bfloat16 h; ushort u; } cv;
      cv.h = __float2bfloat16(v >= 0.f ? v : alpha * v);
      zt[hi * 4 + r][w * 16 + il] = cv.u;
    }
    __syncthreads();
    const int t = threadIdx.x;
    const int px = t >> 4, cb = (t & 15) * 4;
    uint2 o2;
    o2.x = (uint)zt[px][cb] | ((uint)zt[px][cb + 1] << 16);
    o2.y = (uint)zt[px][cb + 2] | ((uint)zt[px][cb + 3] << 16);
    *(uint2*)&pt[((size_t)b * kN + n0 + px) * kC + cb] = o2;
  } else {
    f32x4 pr;
#pragma unroll
    for (int r = 0; r < 4; ++r) {
      const float v = acc[r];
      pr[r] = v >= 0.f ? v : alpha * v;
    }
    *(f32x4*)&raw[((size_t)b * kC + w * 16 + il) * kN + n0 + hi * 4] = pr;
  }
}

// ---- phi' = M.p, g = Wg.p (bf16 pixel-major)
__global__ __launch_bounds__(256) void k_pw(
    const __hip_bfloat16* __restrict__ pTb, const __hip_bfloat16* __restrict__ Mb,
    const __hip_bfloat16* __restrict__ wgb, __hip_bfloat16* __restrict__ phb,
    __hip_bfloat16* __restrict__ gb) {
  const int b = blockIdx.y;
  const int lane = threadIdx.x & 63, w = threadIdx.x >> 6;
  const int il = lane & 15, hi = lane >> 4;
  const int n = blockIdx.x * 16 + il;

  const short8 b0 = *(const short8*)&pTb[((size_t)b * kN + n) * kC + hi * 8];
  const short8 b1 = *(const short8*)&pTb[((size_t)b * kN + n) * kC + 32 + hi * 8];

  const short8 am0 = *(const short8*)&Mb[(size_t)(w * 16 + il) * kC + hi * 8];
  const short8 am1 = *(const short8*)&Mb[(size_t)(w * 16 + il) * kC + 32 + hi * 8];
  f32x4 o4 = {0.f, 0.f, 0.f, 0.f};
  o4 = __builtin_amdgcn_mfma_f32_16x16x32_bf16(am0, b0, o4, 0, 0, 0);
  o4 = __builtin_amdgcn_mfma_f32_16x16x32_bf16(am1, b1, o4, 0, 0, 0);
  uint2 p2;
  p2.x = pkbf(o4[0], o4[1]);
  p2.y = pkbf(o4[2], o4[3]);
  *(uint2*)&phb[((size_t)b * kN + n) * kC + w * 16 + hi * 4] = p2;

  const short8 ag0 = *(const short8*)&wgb[(size_t)(w * 16 + il) * kC + hi * 8];
  const short8 ag1 = *(const short8*)&wgb[(size_t)(w * 16 + il) * kC + 32 + hi * 8];
  f32x4 g4 = {0.f, 0.f, 0.f, 0.f};
  g4 = __builtin_amdgcn_mfma_f32_16x16x32_bf16(ag0, b0, g4, 0, 0, 0);
  g4 = __builtin_amdgcn_mfma_f32_16x16x32_bf16(ag1, b1, g4, 0, 0, 0);
  uint2 g2;
  g2.x = pkbf(g4[0], g4[1]);
  g2.y = pkbf(g4[2], g4[3]);
  *(uint2*)&gb[((size_t)b * kN + n) * kC + w * 16 + hi * 4] = g2;
}

// ---- column sums: 4 waves x 32 j share one staged theta tile, split kSJ.
__global__ __launch_bounds__(256, 2) void k_colstat(
    const __hip_bfloat16* __restrict__ th, const __hip_bfloat16* __restrict__ ph,
    float* __restrict__ partial) {
  const int b = blockIdx.z, ic = blockIdx.y;
  const int lane = threadIdx.x & 63, w = threadIdx.x >> 6;
  const int il = lane & 15, hi = lane >> 4;
  const int j0w = blockIdx.x * 128 + w * 32;

  __shared__ __align__(16) ushort tbufA[4096], tbufB[4096];

  const __hip_bfloat16* thB = th + (size_t)b * kN * kC;
  const size_t phr0 = ((size_t)b * kN + j0w + il) * kC;
  const size_t phr1 = ((size_t)b * kN + j0w + 16 + il) * kC;
  const short8 a00 = *(const short8*)&ph[phr0 + hi * 8];
  const short8 a01 = *(const short8*)&ph[phr0 + 32 + hi * 8];
  const short8 a10 = *(const short8*)&ph[phr1 + hi * 8];
  const short8 a11 = *(const short8*)&ph[phr1 + 32 + hi * 8];

  const int f0 = 2 * w;
  const char* st[2];
#pragma unroll
  for (int k = 0; k < 2; ++k) {
    const int f = f0 + k;
    st[k] = (const char*)&thB[(size_t)(ic * kChunk + (f >> 1) * 16 + il) * kC +
                              (f & 1) * 32 + hi * 8];
  }

#define CSTAGE(DST)                                                         \
  {                                                                         \
    _Pragma("unroll") for (int k = 0; k < 2; ++k) {                         \
      GL16(st[k], &DST[(f0 + k) * 512]);                                    \
      st[k] += (size_t)64 * kC * 2;                                         \
    }                                                                       \
  }

#define CCOMP(SRC)                                                         \
  {                                                                        \
    const ushort* bp_ = SRC;                                               \
    _Pragma("unroll") for (int s = 0; s < 4; ++s) {                        \
      const short8 bf0 = *(const short8*)&bp_[(2 * s) * 512 + lane * 8];   \
      const short8 bf1 = *(const short8*)&bp_[(2 * s + 1) * 512 + lane * 8];\
      f32x4 sj0 = {0.f, 0.f, 0.f, 0.f};                                    \
      f32x4 sj1 = {0.f, 0.f, 0.f, 0.f};                                    \
      sj0 = __builtin_amdgcn_mfma_f32_16x16x32_bf16(a00, bf0, sj0, 0, 0, 0);\
      sj0 = __builtin_amdgcn_mfma_f32_16x16x32_bf16(a01, bf1, sj0, 0, 0, 0);\
      sj1 = __builtin_amdgcn_mfma_f32_16x16x32_bf16(a10, bf0, sj1, 0, 0, 0);\
      sj1 = __builtin_amdgcn_mfma_f32_16x16x32_bf16(a11, bf1, sj1, 0, 0, 0);\
      _Pragma("unroll") for (int r = 0; r < 4; ++r) {                      \
        cs0[r] += exp2f(fmaf(sj0[r], kLOG2E, -kSHIFT));                    \
        cs1[r] += exp2f(fmaf(sj1[r], kLOG2E, -kSHIFT));                    \
      }                                                                    \
    }                                                                      \
  }

  float cs0[4] = {0.f, 0.f, 0.f, 0.f};
  float cs1[4] = {0.f, 0.f, 0.f, 0.f};
  CSTAGE(tbufA);
  __syncthreads();
#pragma unroll 1
  for (int t = 0; t < kNT / 2 - 1; ++t) {
    CSTAGE(tbufB);
    CCOMP(tbufA);
    __syncthreads();
    CSTAGE(tbufA);
    CCOMP(tbufB);
    __syncthreads();
  }
  CSTAGE(tbufB);
  CCOMP(tbufA);
  __syncthreads();
  CCOMP(tbufB);
#undef CSTAGE
#undef CCOMP

#pragma unroll
  for (int r = 0; r < 4; ++r) {
    cs0[r] += __shfl_xor(cs0[r], 1); cs1[r] += __shfl_xor(cs1[r], 1);
    cs0[r] += __shfl_xor(cs0[r], 2); cs1[r] += __shfl_xor(cs1[r], 2);
    cs0[r] += __shfl_xor(cs0[r], 4); cs1[r] += __shfl_xor(cs1[r], 4);
    cs0[r] += __shfl_xor(cs0[r], 8); cs1[r] += __shfl_xor(cs1[r], 8);
  }
  if (il == 0) {
    float* p = partial + (size_t)(b * kSJ + ic) * kN + j0w + hi * 4;
#pragma unroll
    for (int r = 0; r < 4; ++r) {
      p[r] = cs0[r];
      p[16 + r] = cs1[r];
    }
  }
}

// ---- gT[b][c][j] = bf16( g[b][j][c] * 1/colsum[b][j] )
__global__ __launch_bounds__(256) void k_gscale(
    const __hip_bfloat16* __restrict__ gb, const float* __restrict__ partial,
    __hip_bfloat16* __restrict__ gT) {
  const int b = blockIdx.y;
  const int j0 = blockIdx.x * 64;
  const int t = threadIdx.x;
  __shared__ ushort tile[64][66];
  __shared__ float rsv[64];
  if (t < 64) {
    const int j = j0 + t;
    float cs = 0.f;
#pragma unroll
    for (int s = 0; s < kSJ; ++s) cs += partial[(size_t)(b * kSJ + s) * kN + j];
    rsv[t] = 1.0f / cs;
  }
  {
    const int jl = t >> 2, cseg = (t & 3) * 16;
    const ushort* src = (const ushort*)&gb[((size_t)b * kN + j0 + jl) * kC + cseg];
    union { short8 v; ushort u[8]; } u0, u1;
    u0.v = *(const short8*)src;
    u1.v = *(const short8*)(src + 8);
#pragma unroll
    for (int k = 0; k < 8; ++k) {
      tile[jl][cseg + k] = u0.u[k];
      tile[jl][cseg + 8 + k] = u1.u[k];
    }
  }
  __syncthreads();
  const int c = t >> 2, jseg = (t & 3) * 16;
  union { short8 v; ushort u[8]; } o0, o1;
#pragma unroll
  for (int k = 0; k < 16; ++k) {
    const int j = jseg + k;
    const float gv = __uint_as_float((uint)tile[j][c] << 16);
    union { __hip_bfloat16 h; ushort us; } cv;
    cv.h = __float2bfloat16(gv * rsv[j]);
    if (k < 8) o0.u[k] = cv.us; else o1.u[k - 8] = cv.us;
  }
  short8* dst = (short8*)&gT[((size_t)b * kC + c) * kN + j0 + jseg];
  dst[0] = o0.v;
  dst[1] = o1.v;
}

// ---- pass B: 4 waves x 32 i share one staged phi+gT tile, split kSJ.
__global__ __launch_bounds__(256, 2) void k_nl(
    const __hip_bfloat16* __restrict__ th, const __hip_bfloat16* __restrict__ ph,
    const __hip_bfloat16* __restrict__ gT, ushort* __restrict__ py) {
  const int js = blockIdx.y, b = blockIdx.z;
  const int lane = threadIdx.x & 63, w = threadIdx.x >> 6;
  const int il = lane & 15, hi = lane >> 4;
  const int itile32 = blockIdx.x * 4 + w;
  const int i0w = itile32 * 32;
  const int jstart = js * kChunk;
  const int jbase = ((il >> 2) << 3) + (il & 3);  // sigma(row=il)

  __shared__ __align__(16) ushort bufA[8192], bufB[8192];

  const __hip_bfloat16* phB = ph + (size_t)b * kN * kC;
  const __hip_bfloat16* gTB = gT + (size_t)b * kC * kN;

  const size_t tr0 = ((size_t)b * kN + i0w + il) * kC;
  const size_t tr1 = ((size_t)b * kN + i0w + 16 + il) * kC;
  const short8 tA0k0 = *(const short8*)&th[tr0 + hi * 8];
  const short8 tA0k1 = *(const short8*)&th[tr0 + 32 + hi * 8];
  const short8 tA1k0 = *(const short8*)&th[tr1 + hi * 8];
  const short8 tA1k1 = *(const short8*)&th[tr1 + 32 + hi * 8];

  const int f0 = 2 * w;
  const char* sp[2];
  const char* sg[2];
#pragma unroll
  for (int k = 0; k < 2; ++k) {
    const int f = f0 + k;
    const int pr = jstart + jbase + ((f >> 1) & 1) * 4 + ((f >> 2) & 1) * 32;
    const int pc = (f & 1) * 32 + hi * 8;
    sp[k] = (const char*)&phB[(size_t)pr * kC + pc];
    const int gc = (f & 3) * 16 + il;
    const int gj = jstart + ((f >> 2) & 1) * 32 + hi * 8;
    sg[k] = (const char*)&gTB[(size_t)gc * kN + gj];
  }

#define NLSTAGE(DST)                                                        \
  {                                                                         \
    _Pragma("unroll") for (int k = 0; k < 2; ++k) {                         \
      GL16(sp[k], &DST[(f0 + k) * 512]);                                    \
      GL16(sg[k], &DST[4096 + (f0 + k) * 512]);                             \
      sp[k] += (size_t)64 * kC * 2;                                         \
      sg[k] += (size_t)64 * 2;                                              \
    }                                                                       \
  }

#define QKI(TB0, TB1, s0, s1, s2, s3)                                        \
    f32x4 s0 = {0.f, 0.f, 0.f, 0.f};                                         \
    f32x4 s1 = {0.f, 0.f, 0.f, 0.f};                                         \
    f32x4 s2 = {0.f, 0.f, 0.f, 0.f};                                         \
    f32x4 s3 = {0.f, 0.f, 0.f, 0.f};                                         \
    s0 = __builtin_amdgcn_mfma_f32_16x16x32_bf16(pa0, TB0, s0, 0, 0, 0);     \
    s0 = __builtin_amdgcn_mfma_f32_16x16x32_bf16(pa1, TB1, s0, 0, 0, 0);     \
    s1 = __builtin_amdgcn_mfma_f32_16x16x32_bf16(pa2, TB0, s1, 0, 0, 0);     \
    s1 = __builtin_amdgcn_mfma_f32_16x16x32_bf16(pa3, TB1, s1, 0, 0, 0);     \
    s2 = __builtin_amdgcn_mfma_f32_16x16x32_bf16(pa4, TB0, s2, 0, 0, 0);     \
    s2 = __builtin_amdgcn_mfma_f32_16x16x32_bf16(pa5, TB1, s2, 0, 0, 0);     \
    s3 = __builtin_amdgcn_mfma_f32_16x16x32_bf16(pa6, TB0, s3, 0, 0, 0);     \
    s3 = __builtin_amdgcn_mfma_f32_16x16x32_bf16(pa7, TB1, s3, 0, 0, 0);

#define PACK2(sa, sb, pb)                                                    \
    short8 pb;                                                               \
    {                                                                        \
      uint* pw_ = (uint*)&pb;                                                \
      pw_[0] = pkbf(exp2f(fmaf(sa[0], kLOG2E, -kSHIFT)),                     \
                    exp2f(fmaf(sa[1], kLOG2E, -kSHIFT)));                    \
      pw_[1] = pkbf(exp2f(fmaf(sa[2], kLOG2E, -kSHIFT)),                     \
                    exp2f(fmaf(sa[3], kLOG2E, -kSHIFT)));                    \
      pw_[2] = pkbf(exp2f(fmaf(sb[0], kLOG2E, -kSHIFT)),                     \
                    exp2f(fmaf(sb[1], kLOG2E, -kSHIFT)));                    \
      pw_[3] = pkbf(exp2f(fmaf(sb[2], kLOG2E, -kSHIFT)),                     \
                    exp2f(fmaf(sb[3], kLOG2E, -kSHIFT)));                    \
    }

#define NLCOMP(SRC)                                                          \
  {                                                                          \
    const ushort* bp_ = SRC;                                                 \
    const short8 pa0 = *(const short8*)&bp_[0 * 512 + lane * 8];             \
    const short8 pa1 = *(const short8*)&bp_[1 * 512 + lane * 8];             \
    const short8 pa2 = *(const short8*)&bp_[2 * 512 + lane * 8];             \
    const short8 pa3 = *(const short8*)&bp_[3 * 512 + lane * 8];             \
    const short8 pa4 = *(const short8*)&bp_[4 * 512 + lane * 8];             \
    const short8 pa5 = *(const short8*)&bp_[5 * 512 + lane * 8];             \
    const short8 pa6 = *(const short8*)&bp_[6 * 512 + lane * 8];             \
    const short8 pa7 = *(const short8*)&bp_[7 * 512 + lane * 8];             \
    const short8 ga0 = *(const short8*)&bp_[4096 + 0 * 512 + lane * 8];      \
    const short8 ga1 = *(const short8*)&bp_[4096 + 1 * 512 + lane * 8];      \
    const short8 ga2 = *(const short8*)&bp_[4096 + 2 * 512 + lane * 8];      \
    const short8 ga3 = *(const short8*)&bp_[4096 + 3 * 512 + lane * 8];      \
    const short8 ga4 = *(const short8*)&bp_[4096 + 4 * 512 + lane * 8];      \
    const short8 ga5 = *(const short8*)&bp_[4096 + 5 * 512 + lane * 8];      \
    const short8 ga6 = *(const short8*)&bp_[4096 + 6 * 512 + lane * 8];      \
    const short8 ga7 = *(const short8*)&bp_[4096 + 7 * 512 + lane * 8];      \
    {                                                                        \
      QKI(tA0k0, tA0k1, s00, s01, s02, s03)                                  \
      PACK2(s00, s01, pb00)                                                  \
      PACK2(s02, s03, pb01)                                                  \
      ay00 = __builtin_amdgcn_mfma_f32_16x16x32_bf16(ga0, pb00, ay00, 0, 0, 0);\
      ay01 = __builtin_amdgcn_mfma_f32_16x16x32_bf16(ga1, pb00, ay01, 0, 0, 0);\
      ay02 = __builtin_amdgcn_mfma_f32_16x16x32_bf16(ga2, pb00, ay02, 0, 0, 0);\
      ay03 = __builtin_amdgcn_mfma_f32_16x16x32_bf16(ga3, pb00, ay03, 0, 0, 0);\
      ay00 = __builtin_amdgcn_mfma_f32_16x16x32_bf16(ga4, pb01, ay00, 0, 0, 0);\
      ay01 = __builtin_amdgcn_mfma_f32_16x16x32_bf16(ga5, pb01, ay01, 0, 0, 0);\
      ay02 = __builtin_amdgcn_mfma_f32_16x16x32_bf16(ga6, pb01, ay02, 0, 0, 0);\
      ay03 = __builtin_amdgcn_mfma_f32_16x16x32_bf16(ga7, pb01, ay03, 0, 0, 0);\
    }                                                                        \
    {                                                                        \
      QKI(tA1k0, tA1k1, s10, s11, s12, s13)                                  \
      PACK2(s10, s11, pb10)                                                  \
      PACK2(s12, s13, pb11)                                                  \
      ay10 = __builtin_amdgcn_mfma_f32_16x16x32_bf16(ga0, pb10, ay10, 0, 0, 0);\
      ay11 = __builtin_amdgcn_mfma_f32_16x16x32_bf16(ga1, pb10, ay11, 0, 0, 0);\
      ay12 = __builtin_amdgcn_mfma_f32_16x16x32_bf16(ga2, pb10, ay12, 0, 0, 0);\
      ay13 = __builtin_amdgcn_mfma_f32_16x16x32_bf16(ga3, pb10, ay13, 0, 0, 0);\
      ay10 = __builtin_amdgcn_mfma_f32_16x16x32_bf16(ga4, pb11, ay10, 0, 0, 0);\
      ay11 = __builtin_amdgcn_mfma_f32_16x16x32_bf16(ga5, pb11, ay11, 0, 0, 0);\
      ay12 = __builtin_amdgcn_mfma_f32_16x16x32_bf16(ga6, pb11, ay12, 0, 0, 0);\
      ay13 = __builtin_amdgcn_mfma_f32_16x16x32_bf16(ga7, pb11, ay13, 0, 0, 0);\
    }                                                                        \
  }

  f32x4 ay00 = {0.f, 0.f, 0.f, 0.f}, ay01 = {0.f, 0.f, 0.f, 0.f};
  f32x4 ay02 = {0.f, 0.f, 0.f, 0.f}, ay03 = {0.f, 0.f, 0.f, 0.f};
  f32x4 ay10 = {0.f, 0.f, 0.f, 0.f}, ay11 = {0.f, 0.f, 0.f, 0.f};
  f32x4 ay12 = {0.f, 0.f, 0.f, 0.f}, ay13 = {0.f, 0.f, 0.f, 0.f};

  NLSTAGE(bufA);
  __syncthreads();
#pragma unroll 1
  for (int t = 0; t < kNT / 2 - 1; ++t) {
    NLSTAGE(bufB);
    NLCOMP(bufA);
    __syncthreads();
    NLSTAGE(bufA);
    NLCOMP(bufB);
    __syncthreads();
  }
  NLSTAGE(bufB);
  NLCOMP(bufA);
  __syncthreads();
  NLCOMP(bufB);
#undef NLSTAGE
#undef NLCOMP
#undef QKI
#undef PACK2

  uint* b32 = (uint*)(py + ((size_t)(js * kB + b) * (kN / 32) + itile32) * 2048);
  b32[0 * 64 + lane] = pkbf(ay00[0], ay00[1]);
  b32[1 * 64 + lane] = pkbf(ay00[2], ay00[3]);
  b32[2 * 64 + lane] = pkbf(ay01[0], ay01[1]);
  b32[3 * 64 + lane] = pkbf(ay01[2], ay01[3]);
  b32[4 * 64 + lane] = pkbf(ay02[0], ay02[1]);
  b32[5 * 64 + lane] = pkbf(ay02[2], ay02[3]);
  b32[6 * 64 + lane] = pkbf(ay03[0], ay03[1]);
  b32[7 * 64 + lane] = pkbf(ay03[2], ay03[3]);
  b32[8 * 64 + lane] = pkbf(ay10[0], ay10[1]);
  b32[9 * 64 + lane] = pkbf(ay10[2], ay10[3]);
  b32[10 * 64 + lane] = pkbf(ay11[0], ay11[1]);
  b32[11 * 64 + lane] = pkbf(ay11[2], ay11[3]);
  b32[12 * 64 + lane] = pkbf(ay12[0], ay12[1]);
  b32[13 * 64 + lane] = pkbf(ay12[2], ay12[3]);
  b32[14 * 64 + lane] = pkbf(ay13[0], ay13[1]);
  b32[15 * 64 + lane] = pkbf(ay13[2], ay13[3]);
}

// ---- reduce kSJ partials + fused W_y + residuals -> z bf16 pixel-major.
__global__ __launch_bounds__(128) void k_wy(
    const ushort* __restrict__ py, const __hip_bfloat16* __restrict__ wWb,
    const float* __restrict__ x1, const float* __restrict__ alphap,
    ushort* __restrict__ zb) {
  const int b = blockIdx.y;
  const int lane = threadIdx.x & 63, w = threadIdx.x >> 6;
  const int il = lane & 15, hi = lane >> 4;
  const int itile32 = blockIdx.x * 2 + w;
  const int i0w = itile32 * 32;

  __shared__ __align__(16) ushort yt2[2][32 * 72];
  __shared__ __align__(16) ushort zt2[2][32 * 72];
  ushort* yt = yt2[w];
  ushort* zt = zt2[w];

  float lo[16], hs[16];
#pragma unroll
  for (int k = 0; k < 16; ++k) { lo[k] = 0.f; hs[k] = 0.f; }
#pragma unroll 1
  for (int s = 0; s < kSJ; ++s) {
    const uint* ps =
        (const uint*)(py + ((size_t)(s * kB + b) * (kN / 32) + itile32) * 2048);
#pragma unroll
    for (int k = 0; k < 16; ++k) {
      const uint u = ps[k * 64 + lane];
      lo[k] += __uint_as_float(u << 16);
      hs[k] += __uint_as_float(u & 0xffff0000u);
    }
  }
#pragma unroll
  for (int k = 0; k < 16; ++k) {
    const int row = (k >> 3) * 16 + il;
    const int col = ((k >> 1) & 3) * 16 + hi * 4 + (k & 1) * 2;
    *(uint*)&yt[row * 72 + col] = pkbf(lo[k], hs[k]);
  }

  const float alpha = alphap[0];
#pragma unroll
  for (int a = 0; a < 2; ++a) {
    const short8 by0 = *(const short8*)&yt[(a * 16 + il) * 72 + hi * 8];
    const short8 by1 = *(const short8*)&yt[(a * 16 + il) * 72 + 32 + hi * 8];
#pragma unroll
    for (int q = 0; q < 4; ++q) {
      const short8 af0 = *(const short8*)&wWb[(size_t)(q * 16 + il) * kC + hi * 8];
      const short8 af1 = *(const short8*)&wWb[(size_t)(q * 16 + il) * kC + 32 + hi * 8];
      f32x4 o4 = {0.f, 0.f, 0.f, 0.f};
      o4 = __builtin_amdgcn_mfma_f32_16x16x32_bf16(af0, by0, o4, 0, 0, 0);
      o4 = __builtin_amdgcn_mfma_f32_16x16x32_bf16(af1, by1, o4, 0, 0, 0);
      float zv[4];
#pragma unroll
      for (int r = 0; r < 4; ++r) {
        const int o = q * 16 + hi * 4 + r;
        const size_t idx = ((size_t)b * kC + o) * kN + i0w + a * 16 + il;
        const float xv = x1[idx];
        const float pr = xv >= 0.f ? xv : alpha * xv;
        zv[r] = o4[r] + pr + xv;
      }
      *(uint*)&zt[(a * 16 + il) * 72 + q * 16 + hi * 4] = pkbf(zv[0], zv[1]);
      *(uint*)&zt[(a * 16 + il) * 72 + q * 16 + hi * 4 + 2] = pkbf(zv[2], zv[3]);
    }
  }

  const int px = lane >> 1, cseg = (lane & 1) * 32;
  short8* d = (short8*)&zb[((size_t)b * kN + i0w + px) * kC + cseg];
#pragma unroll
  for (int k = 0; k < 4; ++k)
    d[k] = *(const short8*)&zt[px * 72 + cseg + k * 8];
}

extern "C" void kernel_launch(void* const* d_in, const int* in_sizes, int n_in,
                              void* d_out, int out_size, void* d_ws, size_t ws_size,
                              hipStream_t stream) {
  const float* x      = (const float*)d_in[0];
  const float* w1     = (const float*)d_in[1];
  const float* w2     = (const float*)d_in[2];
  const float* wg     = (const float*)d_in[3];
  const float* wth    = (const float*)d_in[4];
  const float* wph    = (const float*)d_in[5];
  const float* wWm    = (const float*)d_in[6];
  const float* alphap = (const float*)d_in[7];
  float* out = (float*)d_out;

  const size_t SZ = (size_t)kB * kC * kN;  // 819200

  float* x1 = (float*)d_ws;
  __hip_bfloat16* pTb = (__hip_bfloat16*)(x1 + SZ);
  __hip_bfloat16* phb = pTb + SZ;
  __hip_bfloat16* gb  = phb + SZ;
  __hip_bfloat16* gT  = gb + SZ;
  float* partial = (float*)(gT + SZ);
  ushort* wc1 = (ushort*)(partial + (size_t)kB * kSJ * kN);
  ushort* wc2 = wc1 + 9 * kC * kC;
  __hip_bfloat16* Mb  = (__hip_bfloat16*)(wc2 + 9 * kC * kC);
  __hip_bfloat16* wgb = Mb + kC * kC;
  __hip_bfloat16* wWb = wgb + kC * kC;
  ushort* py = (ushort*)(wWb + kC * kC);
  ushort* xb = py;                // overlay: dead before k_nl writes py
  ushort* zb = (ushort*)gb;       // overlay: gb dead after gscale

  k_prep<<<144, 256, 0, stream>>>(w1, w2, wc1, wc2);
  k_prepM<<<16, 256, 0, stream>>>(wth, wph, wg, wWm, Mb, wgb, wWb);
  k_tobf<<<dim3(kN / 64, kB), 256, 0, stream>>>(x, xb);
  k_convm<0><<<dim3(400, kB), 256, 0, stream>>>(xb, wc1, alphap, x1, (ushort*)pTb);
  k_pw<<<dim3(kN / 16, kB), 256, 0, stream>>>(pTb, Mb, wgb, phb, gb);
  k_colstat<<<dim3(kN / 128, kSJ, kB), 256, 0, stream>>>(pTb, phb, partial);
  k_gscale<<<dim3(kN / 64, kB), 256, 0, stream>>>(gb, partial, gT);
  k_nl<<<dim3(kN / 128, kSJ, kB), 256, 0, stream>>>(pTb, phb, gT, py);
  k_wy<<<dim3(kN / 64, kB), 128, 0, stream>>>(py, wWb, x1, alphap, zb);
  k_convm<1><<<dim3(400, kB), 256, 0, stream>>>(zb, wc2, alphap, out, nullptr);
}

// Round 14
// 116.866 us; speedup vs baseline: 1.1908x; 1.0587x over previous
//
#include <hip/hip_runtime.h>
#include <hip/hip_bf16.h>
#include <cstddef>

// NLBasicBlock fused, round 14: R13 + 1-op truncating bf16 pack (v_perm_b32)
// for the P matrix in k_nl's hot loop (RNE __float2bfloat16 was ~4 VALU ops
// per value; VALUBusy 50% vs MfmaUtil 17%). RNE kept outside the hot loop.

constexpr int kB = 2, kC = 64, kH = 80, kW = 80, kN = kH * kW;
constexpr int kSJ = 10, kChunk = kN / kSJ, kNT = kChunk / 64;  // 640, 10
constexpr float kLOG2E = 1.4426950408889634f;
constexpr float kSHIFT = 28.853900817779268f;  // 20 * log2(e)

typedef __attribute__((ext_vector_type(8))) short short8;
typedef __attribute__((ext_vector_type(4))) float f32x4;

__device__ __forceinline__ uint pkbf(float a, float b) {
  union { __hip_bfloat162 h; uint u; } x;
  x.h.x = __float2bfloat16(a);
  x.h.y = __float2bfloat16(b);
  return x.u;
}

// truncating pack: low16(out)=hi16(a), high16(out)=hi16(b); 1 v_perm_b32
__device__ __forceinline__ uint pktr(float a, float b) {
  return __builtin_amdgcn_perm(__float_as_uint(b), __float_as_uint(a),
                               0x07060302u);
}

#define GL16(gsrc, ldst)                                                    \
  __builtin_amdgcn_global_load_lds(                                         \
      (__attribute__((address_space(1))) void*)(char*)(gsrc),               \
      (__attribute__((address_space(3))) void*)(ldst), 16, 0, 0)

// ---- conv weights -> bf16 MFMA B-fragment-linear; + M = Wth^T.Wph, Wg, WW
__global__ void k_prep(const float* __restrict__ w1, const float* __restrict__ w2,
                       const float* __restrict__ wth, const float* __restrict__ wph,
                       const float* __restrict__ wg, const float* __restrict__ wWm,
                       ushort* __restrict__ wc1, ushort* __restrict__ wc2,
                       __hip_bfloat16* __restrict__ Mb,
                       __hip_bfloat16* __restrict__ wgb,
                       __hip_bfloat16* __restrict__ wWb) {
  const int idx = blockIdx.x * 256 + threadIdx.x;  // 36864
  {
    const int o = idx / (kC * 9);
    const int r = idx % (kC * 9);
    const int ci = r / 9, tap = r % 9;
    const int og = o >> 4, il = o & 15;
    const int kc = ci >> 5, hi = (ci >> 3) & 3, e = ci & 7;
    const int pos = ((tap * 2 + kc) * 4 + og) * 512 + (hi * 16 + il) * 8 + e;
    union { __hip_bfloat16 h; ushort u; } c1, c2;
    c1.h = __float2bfloat16(w1[idx]);
    c2.h = __float2bfloat16(w2[idx]);
    wc1[pos] = c1.u;
    wc2[pos] = c2.u;
  }
  if (idx < kC * kC) {
    const int a = idx >> 6, bb = idx & 63;
    float s = 0.f;
    for (int o = 0; o < kC; ++o) s += wth[o * kC + a] * wph[o * kC + bb];
    Mb[idx] = __float2bfloat16(s);
    wgb[idx] = __float2bfloat16(wg[idx]);
    wWb[idx] = __float2bfloat16(wWm[idx]);
  }
}

// ---- x f32 [B][C][N] -> bf16 pixel-major [B][N][C]
__global__ __launch_bounds__(256) void k_tobf(const float* __restrict__ x,
                                              ushort* __restrict__ xb) {
  const int b = blockIdx.y;
  const int j0 = blockIdx.x * 64;
  const int t = threadIdx.x;
  __shared__ ushort tile[64][68];
  {
    const int c = t >> 2, jseg = (t & 3) * 16;
    const float* s = &x[((size_t)b * kC + c) * kN + j0 + jseg];
#pragma unroll
    for (int k = 0; k < 16; ++k) {
      union { __hip_bfloat16 h; ushort u; } cv;
      cv.h = __float2bfloat16(s[k]);
      tile[c][jseg + k] = cv.u;
    }
  }
  __syncthreads();
  {
    const int j = t >> 2, cseg = (t & 3) * 16;
    union { short8 v; ushort u[8]; } o0, o1;
#pragma unroll
    for (int k = 0; k < 16; ++k) {
      const ushort u = tile[cseg + k][j];
      if (k < 8) o0.u[k] = u; else o1.u[k - 8] = u;
    }
    short8* d = (short8*)&xb[((size_t)b * kN + j0 + j) * kC + cseg];
    d[0] = o0.v;
    d[1] = o1.v;
  }
}

// ---- MFMA 3x3 reflect conv (R10)
template <int MODE>
__global__ __launch_bounds__(256) void k_convm(
    const ushort* __restrict__ xb, const ushort* __restrict__ wc,
    const float* __restrict__ alphap, float* __restrict__ raw,
    ushort* __restrict__ pt) {
  const int tile = blockIdx.x;  // 400 = 80 rows x 5 col-tiles
  const int b = blockIdx.y;
  const int r0 = tile / 5, c0 = (tile % 5) * 16;
  const int lane = threadIdx.x & 63, w = threadIdx.x >> 6;
  const int il = lane & 15, hi = lane >> 4;

  __shared__ ushort zt[16][72];

  short8 wt[9][2];
#pragma unroll
  for (int t = 0; t < 9; ++t)
#pragma unroll
    for (int kc = 0; kc < 2; ++kc)
      wt[t][kc] = *(const short8*)&wc[(size_t)((t * 2 + kc) * 4 + w) * 512 + lane * 8];

  int cl[3], rb[3];
#pragma unroll
  for (int d = 0; d < 3; ++d) {
    const int cc = c0 + il + d - 1;
    cl[d] = cc < 0 ? 1 : (cc > kW - 1 ? kW - 2 : cc);
    const int rr = r0 + d - 1;
    rb[d] = rr < 0 ? 1 : (rr > kH - 1 ? kH - 2 : rr);
  }
  const ushort* xB = xb + (size_t)b * kN * kC;

  f32x4 acc = {0.f, 0.f, 0.f, 0.f};
#pragma unroll
  for (int dh = 0; dh < 3; ++dh) {
    const int nb = rb[dh] * kW;
#pragma unroll
    for (int dw = 0; dw < 3; ++dw) {
      const ushort* src = &xB[(size_t)(nb + cl[dw]) * kC + hi * 8];
      const short8 a0 = *(const short8*)src;
      const short8 a1 = *(const short8*)(src + 32);
      acc = __builtin_amdgcn_mfma_f32_16x16x32_bf16(a0, wt[dh * 3 + dw][0], acc, 0, 0, 0);
      acc = __builtin_amdgcn_mfma_f32_16x16x32_bf16(a1, wt[dh * 3 + dw][1], acc, 0, 0, 0);
    }
  }

  const int n0 = r0 * kW + c0;
  const float alpha = alphap[0];
  if (MODE == 0) {
    *(f32x4*)&raw[((size_t)b * kC + w * 16 + il) * kN + n0 + hi * 4] = acc;
#pragma unroll
    for (int r = 0; r < 4; ++r) {
      const float v = acc[r];
      union { __hip_bfloat16 h; ushort u; } cv;
      cv.h = __float2bfloat16(v >= 0.f ? v : alpha * v);
      zt[hi * 4 + r][w * 16 + il] = cv.u;
    }
    __syncthreads();
    const int t = threadIdx.x;
    const int px = t >> 4, cb = (t & 15) * 4;
    uint2 o2;
    o2.x = (uint)zt[px][cb] | ((uint)zt[px][cb + 1] << 16);
    o2.y = (uint)zt[px][cb + 2] | ((uint)zt[px][cb + 3] << 16);
    *(uint2*)&pt[((size_t)b * kN + n0 + px) * kC + cb] = o2;
  } else {
    f32x4 pr;
#pragma unroll
    for (int r = 0; r < 4; ++r) {
      const float v = acc[r];
      pr[r] = v >= 0.f ? v : alpha * v;
    }
    *(f32x4*)&raw[((size_t)b * kC + w * 16 + il) * kN + n0 + hi * 4] = pr;
  }
}

// ---- phi' = M.p, g = Wg.p (bf16 pixel-major)
__global__ __launch_bounds__(256) void k_pw(
    const __hip_bfloat16* __restrict__ pTb, const __hip_bfloat16* __restrict__ Mb,
    const __hip_bfloat16* __restrict__ wgb, __hip_bfloat16* __restrict__ phb,
    __hip_bfloat16* __restrict__ gb) {
  const int b = blockIdx.y;
  const int lane = threadIdx.x & 63, w = threadIdx.x >> 6;
  const int il = lane & 15, hi = lane >> 4;
  const int n = blockIdx.x * 16 + il;

  const short8 b0 = *(const short8*)&pTb[((size_t)b * kN + n) * kC + hi * 8];
  const short8 b1 = *(const short8*)&pTb[((size_t)b * kN + n) * kC + 32 + hi * 8];

  const short8 am0 = *(const short8*)&Mb[(size_t)(w * 16 + il) * kC + hi * 8];
  const short8 am1 = *(const short8*)&Mb[(size_t)(w * 16 + il) * kC + 32 + hi * 8];
  f32x4 o4 = {0.f, 0.f, 0.f, 0.f};
  o4 = __builtin_amdgcn_mfma_f32_16x16x32_bf16(am0, b0, o4, 0, 0, 0);
  o4 = __builtin_amdgcn_mfma_f32_16x16x32_bf16(am1, b1, o4, 0, 0, 0);
  uint2 p2;
  p2.x = pkbf(o4[0], o4[1]);
  p2.y = pkbf(o4[2], o4[3]);
  *(uint2*)&phb[((size_t)b * kN + n) * kC + w * 16 + hi * 4] = p2;

  const short8 ag0 = *(const short8*)&wgb[(size_t)(w * 16 + il) * kC + hi * 8];
  const short8 ag1 = *(const short8*)&wgb[(size_t)(w * 16 + il) * kC + 32 + hi * 8];
  f32x4 g4 = {0.f, 0.f, 0.f, 0.f};
  g4 = __builtin_amdgcn_mfma_f32_16x16x32_bf16(ag0, b0, g4, 0, 0, 0);
  g4 = __builtin_amdgcn_mfma_f32_16x16x32_bf16(ag1, b1, g4, 0, 0, 0);
  uint2 g2;
  g2.x = pkbf(g4[0], g4[1]);
  g2.y = pkbf(g4[2], g4[3]);
  *(uint2*)&gb[((size_t)b * kN + n) * kC + w * 16 + hi * 4] = g2;
}

// ---- column sums: 4 waves x 32 j share one staged theta tile, split kSJ.
__global__ __launch_bounds__(256, 2) void k_colstat(
    const __hip_bfloat16* __restrict__ th, const __hip_bfloat16* __restrict__ ph,
    float* __restrict__ partial) {
  const int b = blockIdx.z, ic = blockIdx.y;
  const int lane = threadIdx.x & 63, w = threadIdx.x >> 6;
  const int il = lane & 15, hi = lane >> 4;
  const int j0w = blockIdx.x * 128 + w * 32;

  __shared__ __align__(16) ushort tbufA[4096], tbufB[4096];

  const __hip_bfloat16* thB = th + (size_t)b * kN * kC;
  const size_t phr0 = ((size_t)b * kN + j0w + il) * kC;
  const size_t phr1 = ((size_t)b * kN + j0w + 16 + il) * kC;
  const short8 a00 = *(const short8*)&ph[phr0 + hi * 8];
  const short8 a01 = *(const short8*)&ph[phr0 + 32 + hi * 8];
  const short8 a10 = *(const short8*)&ph[phr1 + hi * 8];
  const short8 a11 = *(const short8*)&ph[phr1 + 16 + 16 + hi * 8];

  const int f0 = 2 * w;
  const char* st[2];
#pragma unroll
  for (int k = 0; k < 2; ++k) {
    const int f = f0 + k;
    st[k] = (const char*)&thB[(size_t)(ic * kChunk + (f >> 1) * 16 + il) * kC +
                              (f & 1) * 32 + hi * 8];
  }

#define CSTAGE(DST)                                                         \
  {                                                                         \
    _Pragma("unroll") for (int k = 0; k < 2; ++k) {                         \
      GL16(st[k], &DST[(f0 + k) * 512]);                                    \
      st[k] += (size_t)64 * kC * 2;                                         \
    }                                                                       \
  }

#define CCOMP(SRC)                                                         \
  {                                                                        \
    const ushort* bp_ = SRC;                                               \
    _Pragma("unroll") for (int s = 0; s < 4; ++s) {                        \
      const short8 bf0 = *(const short8*)&bp_[(2 * s) * 512 + lane * 8];   \
      const short8 bf1 = *(const short8*)&bp_[(2 * s + 1) * 512 + lane * 8];\
      f32x4 sj0 = {0.f, 0.f, 0.f, 0.f};                                    \
      f32x4 sj1 = {0.f, 0.f, 0.f, 0.f};                                    \
      sj0 = __builtin_amdgcn_mfma_f32_16x16x32_bf16(a00, bf0, sj0, 0, 0, 0);\
      sj0 = __builtin_amdgcn_mfma_f32_16x16x32_bf16(a01, bf1, sj0, 0, 0, 0);\
      sj1 = __builtin_amdgcn_mfma_f32_16x16x32_bf16(a10, bf0, sj1, 0, 0, 0);\
      sj1 = __builtin_amdgcn_mfma_f32_16x16x32_bf16(a11, bf1, sj1, 0, 0, 0);\
      _Pragma("unroll") for (int r = 0; r < 4; ++r) {                      \
        cs0[r] += exp2f(fmaf(sj0[r], kLOG2E, -kSHIFT));                    \
        cs1[r] += exp2f(fmaf(sj1[r], kLOG2E, -kSHIFT));                    \
      }                                                                    \
    }                                                                      \
  }

  float cs0[4] = {0.f, 0.f, 0.f, 0.f};
  float cs1[4] = {0.f, 0.f, 0.f, 0.f};
  CSTAGE(tbufA);
  __syncthreads();
#pragma unroll 1
  for (int t = 0; t < kNT / 2 - 1; ++t) {
    CSTAGE(tbufB);
    CCOMP(tbufA);
    __syncthreads();
    CSTAGE(tbufA);
    CCOMP(tbufB);
    __syncthreads();
  }
  CSTAGE(tbufB);
  CCOMP(tbufA);
  __syncthreads();
  CCOMP(tbufB);
#undef CSTAGE
#undef CCOMP

#pragma unroll
  for (int r = 0; r < 4; ++r) {
    cs0[r] += __shfl_xor(cs0[r], 1); cs1[r] += __shfl_xor(cs1[r], 1);
    cs0[r] += __shfl_xor(cs0[r], 2); cs1[r] += __shfl_xor(cs1[r], 2);
    cs0[r] += __shfl_xor(cs0[r], 4); cs1[r] += __shfl_xor(cs1[r], 4);
    cs0[r] += __shfl_xor(cs0[r], 8); cs1[r] += __shfl_xor(cs1[r], 8);
  }
  if (il == 0) {
    float* p = partial + (size_t)(b * kSJ + ic) * kN + j0w + hi * 4;
#pragma unroll
    for (int r = 0; r < 4; ++r) {
      p[r] = cs0[r];
      p[16 + r] = cs1[r];
    }
  }
}

// ---- gT[b][c][j] = bf16( g[b][j][c] * 1/colsum[b][j] )
__global__ __launch_bounds__(256) void k_gscale(
    const __hip_bfloat16* __restrict__ gb, const float* __restrict__ partial,
    __hip_bfloat16* __restrict__ gT) {
  const int b = blockIdx.y;
  const int j0 = blockIdx.x * 64;
  const int t = threadIdx.x;
  __shared__ ushort tile[64][66];
  __shared__ float rsv[64];
  if (t < 64) {
    const int j = j0 + t;
    float cs = 0.f;
#pragma unroll
    for (int s = 0; s < kSJ; ++s) cs += partial[(size_t)(b * kSJ + s) * kN + j];
    rsv[t] = 1.0f / cs;
  }
  {
    const int jl = t >> 2, cseg = (t & 3) * 16;
    const ushort* src = (const ushort*)&gb[((size_t)b * kN + j0 + jl) * kC + cseg];
    union { short8 v; ushort u[8]; } u0, u1;
    u0.v = *(const short8*)src;
    u1.v = *(const short8*)(src + 8);
#pragma unroll
    for (int k = 0; k < 8; ++k) {
      tile[jl][cseg + k] = u0.u[k];
      tile[jl][cseg + 8 + k] = u1.u[k];
    }
  }
  __syncthreads();
  const int c = t >> 2, jseg = (t & 3) * 16;
  union { short8 v; ushort u[8]; } o0, o1;
#pragma unroll
  for (int k = 0; k < 16; ++k) {
    const int j = jseg + k;
    const float gv = __uint_as_float((uint)tile[j][c] << 16);
    union { __hip_bfloat16 h; ushort us; } cv;
    cv.h = __float2bfloat16(gv * rsv[j]);
    if (k < 8) o0.u[k] = cv.us; else o1.u[k - 8] = cv.us;
  }
  short8* dst = (short8*)&gT[((size_t)b * kC + c) * kN + j0 + jseg];
  dst[0] = o0.v;
  dst[1] = o1.v;
}

// ---- pass B: 4 waves x 32 i share one staged phi+gT tile, split kSJ.
__global__ __launch_bounds__(256, 2) void k_nl(
    const __hip_bfloat16* __restrict__ th, const __hip_bfloat16* __restrict__ ph,
    const __hip_bfloat16* __restrict__ gT, ushort* __restrict__ py) {
  const int js = blockIdx.y, b = blockIdx.z;
  const int lane = threadIdx.x & 63, w = threadIdx.x >> 6;
  const int il = lane & 15, hi = lane >> 4;
  const int itile32 = blockIdx.x * 4 + w;
  const int i0w = itile32 * 32;
  const int jstart = js * kChunk;
  const int jbase = ((il >> 2) << 3) + (il & 3);  // sigma(row=il)

  __shared__ __align__(16) ushort bufA[8192], bufB[8192];

  const __hip_bfloat16* phB = ph + (size_t)b * kN * kC;
  const __hip_bfloat16* gTB = gT + (size_t)b * kC * kN;

  const size_t tr0 = ((size_t)b * kN + i0w + il) * kC;
  const size_t tr1 = ((size_t)b * kN + i0w + 16 + il) * kC;
  const short8 tA0k0 = *(const short8*)&th[tr0 + hi * 8];
  const short8 tA0k1 = *(const short8*)&th[tr0 + 32 + hi * 8];
  const short8 tA1k0 = *(const short8*)&th[tr1 + hi * 8];
  const short8 tA1k1 = *(const short8*)&th[tr1 + 32 + hi * 8];

  const int f0 = 2 * w;
  const char* sp[2];
  const char* sg[2];
#pragma unroll
  for (int k = 0; k < 2; ++k) {
    const int f = f0 + k;
    const int pr = jstart + jbase + ((f >> 1) & 1) * 4 + ((f >> 2) & 1) * 32;
    const int pc = (f & 1) * 32 + hi * 8;
    sp[k] = (const char*)&phB[(size_t)pr * kC + pc];
    const int gc = (f & 3) * 16 + il;
    const int gj = jstart + ((f >> 2) & 1) * 32 + hi * 8;
    sg[k] = (const char*)&gTB[(size_t)gc * kN + gj];
  }

#define NLSTAGE(DST)                                                        \
  {                                                                         \
    _Pragma("unroll") for (int k = 0; k < 2; ++k) {                         \
      GL16(sp[k], &DST[(f0 + k) * 512]);                                    \
      GL16(sg[k], &DST[4096 + (f0 + k) * 512]);                             \
      sp[k] += (size_t)64 * kC * 2;                                         \
      sg[k] += (size_t)64 * 2;                                              \
    }                                                                       \
  }

#define QKI(TB0, TB1, s0, s1, s2, s3)                                        \
    f32x4 s0 = {0.f, 0.f, 0.f, 0.f};                                         \
    f32x4 s1 = {0.f, 0.f, 0.f, 0.f};                                         \
    f32x4 s2 = {0.f, 0.f, 0.f, 0.f};                                         \
    f32x4 s3 = {0.f, 0.f, 0.f, 0.f};                                         \
    s0 = __builtin_amdgcn_mfma_f32_16x16x32_bf16(pa0, TB0, s0, 0, 0, 0);     \
    s0 = __builtin_amdgcn_mfma_f32_16x16x32_bf16(pa1, TB1, s0, 0, 0, 0);     \
    s1 = __builtin_amdgcn_mfma_f32_16x16x32_bf16(pa2, TB0, s1, 0, 0, 0);     \
    s1 = __builtin_amdgcn_mfma_f32_16x16x32_bf16(pa3, TB1, s1, 0, 0, 0);     \
    s2 = __builtin_amdgcn_mfma_f32_16x16x32_bf16(pa4, TB0, s2, 0, 0, 0);     \
    s2 = __builtin_amdgcn_mfma_f32_16x16x32_bf16(pa5, TB1, s2, 0, 0, 0);     \
    s3 = __builtin_amdgcn_mfma_f32_16x16x32_bf16(pa6, TB0, s3, 0, 0, 0);     \
    s3 = __builtin_amdgcn_mfma_f32_16x16x32_bf16(pa7, TB1, s3, 0, 0, 0);

// truncating bf16 pack (hot loop): 1 v_perm per pair
#define PACK2(sa, sb, pb)                                                    \
    short8 pb;                                                               \
    {                                                                        \
      uint* pw_ = (uint*)&pb;                                                \
      pw_[0] = pktr(exp2f(fmaf(sa[0], kLOG2E, -kSHIFT)),                     \
                    exp2f(fmaf(sa[1], kLOG2E, -kSHIFT)));                    \
      pw_[1] = pktr(exp2f(fmaf(sa[2], kLOG2E, -kSHIFT)),                     \
                    exp2f(fmaf(sa[3], kLOG2E, -kSHIFT)));                    \
      pw_[2] = pktr(exp2f(fmaf(sb[0], kLOG2E, -kSHIFT)),                     \
                    exp2f(fmaf(sb[1], kLOG2E, -kSHIFT)));                    \
      pw_[3] = pktr(exp2f(fmaf(sb[2], kLOG2E, -kSHIFT)),                     \
                    exp2f(fmaf(sb[3], kLOG2E, -kSHIFT)));                    \
    }

#define NLCOMP(SRC)                                                          \
  {                                                                          \
    const ushort* bp_ = SRC;                                                 \
    const short8 pa0 = *(const short8*)&bp_[0 * 512 + lane * 8];             \
    const short8 pa1 = *(const short8*)&bp_[1 * 512 + lane * 8];             \
    const short8 pa2 = *(const short8*)&bp_[2 * 512 + lane * 8];             \
    const short8 pa3 = *(const short8*)&bp_[3 * 512 + lane * 8];             \
    const short8 pa4 = *(const short8*)&bp_[4 * 512 + lane * 8];             \
    const short8 pa5 = *(const short8*)&bp_[5 * 512 + lane * 8];             \
    const short8 pa6 = *(const short8*)&bp_[6 * 512 + lane * 8];             \
    const short8 pa7 = *(const short8*)&bp_[7 * 512 + lane * 8];             \
    const short8 ga0 = *(const short8*)&bp_[4096 + 0 * 512 + lane * 8];      \
    const short8 ga1 = *(const short8*)&bp_[4096 + 1 * 512 + lane * 8];      \
    const short8 ga2 = *(const short8*)&bp_[4096 + 2 * 512 + lane * 8];      \
    const short8 ga3 = *(const short8*)&bp_[4096 + 3 * 512 + lane * 8];      \
    const short8 ga4 = *(const short8*)&bp_[4096 + 4 * 512 + lane * 8];      \
    const short8 ga5 = *(const short8*)&bp_[4096 + 5 * 512 + lane * 8];      \
    const short8 ga6 = *(const short8*)&bp_[4096 + 6 * 512 + lane * 8];      \
    const short8 ga7 = *(const short8*)&bp_[4096 + 7 * 512 + lane * 8];      \
    {                                                                        \
      QKI(tA0k0, tA0k1, s00, s01, s02, s03)                                  \
      PACK2(s00, s01, pb00)                                                  \
      PACK2(s02, s03, pb01)                                                  \
      ay00 = __builtin_amdgcn_mfma_f32_16x16x32_bf16(ga0, pb00, ay00, 0, 0, 0);\
      ay01 = __builtin_amdgcn_mfma_f32_16x16x32_bf16(ga1, pb00, ay01, 0, 0, 0);\
      ay02 = __builtin_amdgcn_mfma_f32_16x16x32_bf16(ga2, pb00, ay02, 0, 0, 0);\
      ay03 = __builtin_amdgcn_mfma_f32_16x16x32_bf16(ga3, pb00, ay03, 0, 0, 0);\
      ay00 = __builtin_amdgcn_mfma_f32_16x16x32_bf16(ga4, pb01, ay00, 0, 0, 0);\
      ay01 = __builtin_amdgcn_mfma_f32_16x16x32_bf16(ga5, pb01, ay01, 0, 0, 0);\
      ay02 = __builtin_amdgcn_mfma_f32_16x16x32_bf16(ga6, pb01, ay02, 0, 0, 0);\
      ay03 = __builtin_amdgcn_mfma_f32_16x16x32_bf16(ga7, pb01, ay03, 0, 0, 0);\
    }                                                                        \
    {                                                                        \
      QKI(tA1k0, tA1k1, s10, s11, s12, s13)                                  \
      PACK2(s10, s11, pb10)                                                  \
      PACK2(s12, s13, pb11)                                                  \
      ay10 = __builtin_amdgcn_mfma_f32_16x16x32_bf16(ga0, pb10, ay10, 0, 0, 0);\
      ay11 = __builtin_amdgcn_mfma_f32_16x16x32_bf16(ga1, pb10, ay11, 0, 0, 0);\
      ay12 = __builtin_amdgcn_mfma_f32_16x16x32_bf16(ga2, pb10, ay12, 0, 0, 0);\
      ay13 = __builtin_amdgcn_mfma_f32_16x16x32_bf16(ga3, pb10, ay13, 0, 0, 0);\
      ay10 = __builtin_amdgcn_mfma_f32_16x16x32_bf16(ga4, pb11, ay10, 0, 0, 0);\
      ay11 = __builtin_amdgcn_mfma_f32_16x16x32_bf16(ga5, pb11, ay11, 0, 0, 0);\
      ay12 = __builtin_amdgcn_mfma_f32_16x16x32_bf16(ga6, pb11, ay12, 0, 0, 0);\
      ay13 = __builtin_amdgcn_mfma_f32_16x16x32_bf16(ga7, pb11, ay13, 0, 0, 0);\
    }                                                                        \
  }

  f32x4 ay00 = {0.f, 0.f, 0.f, 0.f}, ay01 = {0.f, 0.f, 0.f, 0.f};
  f32x4 ay02 = {0.f, 0.f, 0.f, 0.f}, ay03 = {0.f, 0.f, 0.f, 0.f};
  f32x4 ay10 = {0.f, 0.f, 0.f, 0.f}, ay11 = {0.f, 0.f, 0.f, 0.f};
  f32x4 ay12 = {0.f, 0.f, 0.f, 0.f}, ay13 = {0.f, 0.f, 0.f, 0.f};

  NLSTAGE(bufA);
  __syncthreads();
#pragma unroll 1
  for (int t = 0; t < kNT / 2 - 1; ++t) {
    NLSTAGE(bufB);
    NLCOMP(bufA);
    __syncthreads();
    NLSTAGE(bufA);
    NLCOMP(bufB);
    __syncthreads();
  }
  NLSTAGE(bufB);
  NLCOMP(bufA);
  __syncthreads();
  NLCOMP(bufB);
#undef NLSTAGE
#undef NLCOMP
#undef QKI
#undef PACK2

  uint* b32 = (uint*)(py + ((size_t)(js * kB + b) * (kN / 32) + itile32) * 2048);
  b32[0 * 64 + lane] = pkbf(ay00[0], ay00[1]);
  b32[1 * 64 + lane] = pkbf(ay00[2], ay00[3]);
  b32[2 * 64 + lane] = pkbf(ay01[0], ay01[1]);
  b32[3 * 64 + lane] = pkbf(ay01[2], ay01[3]);
  b32[4 * 64 + lane] = pkbf(ay02[0], ay02[1]);
  b32[5 * 64 + lane] = pkbf(ay02[2], ay02[3]);
  b32[6 * 64 + lane] = pkbf(ay03[0], ay03[1]);
  b32[7 * 64 + lane] = pkbf(ay03[2], ay03[3]);
  b32[8 * 64 + lane] = pkbf(ay10[0], ay10[1]);
  b32[9 * 64 + lane] = pkbf(ay10[2], ay10[3]);
  b32[10 * 64 + lane] = pkbf(ay11[0], ay11[1]);
  b32[11 * 64 + lane] = pkbf(ay11[2], ay11[3]);
  b32[12 * 64 + lane] = pkbf(ay12[0], ay12[1]);
  b32[13 * 64 + lane] = pkbf(ay12[2], ay12[3]);
  b32[14 * 64 + lane] = pkbf(ay13[0], ay13[1]);
  b32[15 * 64 + lane] = pkbf(ay13[2], ay13[3]);
}

// ---- reduce kSJ partials + fused W_y + residuals -> z bf16 pixel-major.
__global__ __launch_bounds__(128) void k_wy(
    const ushort* __restrict__ py, const __hip_bfloat16* __restrict__ wWb,
    const float* __restrict__ x1, const float* __restrict__ alphap,
    ushort* __restrict__ zb) {
  const int b = blockIdx.y;
  const int lane = threadIdx.x & 63, w = threadIdx.x >> 6;
  const int il = lane & 15, hi = lane >> 4;
  const int itile32 = blockIdx.x * 2 + w;
  const int i0w = itile32 * 32;

  __shared__ __align__(16) ushort yt2[2][32 * 72];
  __shared__ __align__(16) ushort zt2[2][32 * 72];
  ushort* yt = yt2[w];
  ushort* zt = zt2[w];

  float lo[16], hs[16];
#pragma unroll
  for (int k = 0; k < 16; ++k) { lo[k] = 0.f; hs[k] = 0.f; }
#pragma unroll 1
  for (int s = 0; s < kSJ; ++s) {
    const uint* ps =
        (const uint*)(py + ((size_t)(s * kB + b) * (kN / 32) + itile32) * 2048);
#pragma unroll
    for (int k = 0; k < 16; ++k) {
      const uint u = ps[k * 64 + lane];
      lo[k] += __uint_as_float(u << 16);
      hs[k] += __uint_as_float(u & 0xffff0000u);
    }
  }
#pragma unroll
  for (int k = 0; k < 16; ++k) {
    const int row = (k >> 3) * 16 + il;
    const int col = ((k >> 1) & 3) * 16 + hi * 4 + (k & 1) * 2;
    *(uint*)&yt[row * 72 + col] = pkbf(lo[k], hs[k]);
  }

  const float alpha = alphap[0];
#pragma unroll
  for (int a = 0; a < 2; ++a) {
    const short8 by0 = *(const short8*)&yt[(a * 16 + il) * 72 + hi * 8];
    const short8 by1 = *(const short8*)&yt[(a * 16 + il) * 72 + 32 + hi * 8];
#pragma unroll
    for (int q = 0; q < 4; ++q) {
      const short8 af0 = *(const short8*)&wWb[(size_t)(q * 16 + il) * kC + hi * 8];
      const short8 af1 = *(const short8*)&wWb[(size_t)(q * 16 + il) * kC + 32 + hi * 8];
      f32x4 o4 = {0.f, 0.f, 0.f, 0.f};
      o4 = __builtin_amdgcn_mfma_f32_16x16x32_bf16(af0, by0, o4, 0, 0, 0);
      o4 = __builtin_amdgcn_mfma_f32_16x16x32_bf16(af1, by1, o4, 0, 0, 0);
      float zv[4];
#pragma unroll
      for (int r = 0; r < 4; ++r) {
        const int o = q * 16 + hi * 4 + r;
        const size_t idx = ((size_t)b * kC + o) * kN + i0w + a * 16 + il;
        const float xv = x1[idx];
        const float pr = xv >= 0.f ? xv : alpha * xv;
        zv[r] = o4[r] + pr + xv;
      }
      *(uint*)&zt[(a * 16 + il) * 72 + q * 16 + hi * 4] = pkbf(zv[0], zv[1]);
      *(uint*)&zt[(a * 16 + il) * 72 + q * 16 + hi * 4 + 2] = pkbf(zv[2], zv[3]);
    }
  }

  const int px = lane >> 1, cseg = (lane & 1) * 32;
  short8* d = (short8*)&zb[((size_t)b * kN + i0w + px) * kC + cseg];
#pragma unroll
  for (int k = 0; k < 4; ++k)
    d[k] = *(const short8*)&zt[px * 72 + cseg + k * 8];
}

extern "C" void kernel_launch(void* const* d_in, const int* in_sizes, int n_in,
                              void* d_out, int out_size, void* d_ws, size_t ws_size,
                              hipStream_t stream) {
  const float* x      = (const float*)d_in[0];
  const float* w1     = (const float*)d_in[1];
  const float* w2     = (const float*)d_in[2];
  const float* wg     = (const float*)d_in[3];
  const float* wth    = (const float*)d_in[4];
  const float* wph    = (const float*)d_in[5];
  const float* wWm    = (const float*)d_in[6];
  const float* alphap = (const float*)d_in[7];
  float* out = (float*)d_out;

  const size_t SZ = (size_t)kB * kC * kN;  // 819200

  float* x1 = (float*)d_ws;
  __hip_bfloat16* pTb = (__hip_bfloat16*)(x1 + SZ);
  __hip_bfloat16* phb = pTb + SZ;
  __hip_bfloat16* gb  = phb + SZ;
  __hip_bfloat16* gT  = gb + SZ;
  float* partial = (float*)(gT + SZ);
  ushort* wc1 = (ushort*)(partial + (size_t)kB * kSJ * kN);
  ushort* wc2 = wc1 + 9 * kC * kC;
  __hip_bfloat16* Mb  = (__hip_bfloat16*)(wc2 + 9 * kC * kC);
  __hip_bfloat16* wgb = Mb + kC * kC;
  __hip_bfloat16* wWb = wgb + kC * kC;
  ushort* py = (ushort*)(wWb + kC * kC);
  ushort* xb = py;                // overlay: dead before k_nl writes py
  ushort* zb = (ushort*)gb;       // overlay: gb dead after gscale

  k_prep<<<144, 256, 0, stream>>>(w1, w2, wth, wph, wg, wWm, wc1, wc2,
                                  Mb, wgb, wWb);
  k_tobf<<<dim3(kN / 64, kB), 256, 0, stream>>>(x, xb);
  k_convm<0><<<dim3(400, kB), 256, 0, stream>>>(xb, wc1, alphap, x1, (ushort*)pTb);
  k_pw<<<dim3(kN / 16, kB), 256, 0, stream>>>(pTb, Mb, wgb, phb, gb);
  k_colstat<<<dim3(kN / 128, kSJ, kB), 256, 0, stream>>>(pTb, phb, partial);
  k_gscale<<<dim3(kN / 64, kB), 256, 0, stream>>>(gb, partial, gT);
  k_nl<<<dim3(kN / 128, kSJ, kB), 256, 0, stream>>>(pTb, phb, gT, py);
  k_wy<<<dim3(kN / 64, kB), 128, 0, stream>>>(py, wWb, x1, alphap, zb);
  k_convm<1><<<dim3(400, kB), 256, 0, stream>>>(zb, wc2, alphap, out, nullptr);
}

// Round 15
// 113.704 us; speedup vs baseline: 1.2239x; 1.0278x over previous
//
#include <hip/hip_runtime.h>
#include <hip/hip_bf16.h>
#include <cstddef>

// NLBasicBlock fused, round 15: R14 + super-tile staging (2x64 rows per
// buffer flip) in k_nl / k_colstat -> barrier count halved, compute per
// vmcnt(0) drain doubled (~900cy >> L2 latency). NT=10 tiles = 5 supers,
// odd count handled by prologue + 2 double-iters + tail COMP.

constexpr int kB = 2, kC = 64, kH = 80, kW = 80, kN = kH * kW;
constexpr int kSJ = 10, kChunk = kN / kSJ, kNT = kChunk / 64;  // 640, 10
constexpr float kLOG2E = 1.4426950408889634f;
constexpr float kSHIFT = 28.853900817779268f;  // 20 * log2(e)

typedef __attribute__((ext_vector_type(8))) short short8;
typedef __attribute__((ext_vector_type(4))) float f32x4;

__device__ __forceinline__ uint pkbf(float a, float b) {
  union { __hip_bfloat162 h; uint u; } x;
  x.h.x = __float2bfloat16(a);
  x.h.y = __float2bfloat16(b);
  return x.u;
}

// truncating pack: low16(out)=hi16(a), high16(out)=hi16(b); 1 v_perm_b32
__device__ __forceinline__ uint pktr(float a, float b) {
  return __builtin_amdgcn_perm(__float_as_uint(b), __float_as_uint(a),
                               0x07060302u);
}

#define GL16(gsrc, ldst)                                                    \
  __builtin_amdgcn_global_load_lds(                                         \
      (__attribute__((address_space(1))) void*)(char*)(gsrc),               \
      (__attribute__((address_space(3))) void*)(ldst), 16, 0, 0)

// ---- conv weights -> bf16 MFMA B-fragment-linear; + M = Wth^T.Wph, Wg, WW
__global__ void k_prep(const float* __restrict__ w1, const float* __restrict__ w2,
                       const float* __restrict__ wth, const float* __restrict__ wph,
                       const float* __restrict__ wg, const float* __restrict__ wWm,
                       ushort* __restrict__ wc1, ushort* __restrict__ wc2,
                       __hip_bfloat16* __restrict__ Mb,
                       __hip_bfloat16* __restrict__ wgb,
                       __hip_bfloat16* __restrict__ wWb) {
  const int idx = blockIdx.x * 256 + threadIdx.x;  // 36864
  {
    const int o = idx / (kC * 9);
    const int r = idx % (kC * 9);
    const int ci = r / 9, tap = r % 9;
    const int og = o >> 4, il = o & 15;
    const int kc = ci >> 5, hi = (ci >> 3) & 3, e = ci & 7;
    const int pos = ((tap * 2 + kc) * 4 + og) * 512 + (hi * 16 + il) * 8 + e;
    union { __hip_bfloat16 h; ushort u; } c1, c2;
    c1.h = __float2bfloat16(w1[idx]);
    c2.h = __float2bfloat16(w2[idx]);
    wc1[pos] = c1.u;
    wc2[pos] = c2.u;
  }
  if (idx < kC * kC) {
    const int a = idx >> 6, bb = idx & 63;
    float s = 0.f;
    for (int o = 0; o < kC; ++o) s += wth[o * kC + a] * wph[o * kC + bb];
    Mb[idx] = __float2bfloat16(s);
    wgb[idx] = __float2bfloat16(wg[idx]);
    wWb[idx] = __float2bfloat16(wWm[idx]);
  }
}

// ---- x f32 [B][C][N] -> bf16 pixel-major [B][N][C]
__global__ __launch_bounds__(256) void k_tobf(const float* __restrict__ x,
                                              ushort* __restrict__ xb) {
  const int b = blockIdx.y;
  const int j0 = blockIdx.x * 64;
  const int t = threadIdx.x;
  __shared__ ushort tile[64][68];
  {
    const int c = t >> 2, jseg = (t & 3) * 16;
    const float* s = &x[((size_t)b * kC + c) * kN + j0 + jseg];
#pragma unroll
    for (int k = 0; k < 16; ++k) {
      union { __hip_bfloat16 h; ushort u; } cv;
      cv.h = __float2bfloat16(s[k]);
      tile[c][jseg + k] = cv.u;
    }
  }
  __syncthreads();
  {
    const int j = t >> 2, cseg = (t & 3) * 16;
    union { short8 v; ushort u[8]; } o0, o1;
#pragma unroll
    for (int k = 0; k < 16; ++k) {
      const ushort u = tile[cseg + k][j];
      if (k < 8) o0.u[k] = u; else o1.u[k - 8] = u;
    }
    short8* d = (short8*)&xb[((size_t)b * kN + j0 + j) * kC + cseg];
    d[0] = o0.v;
    d[1] = o1.v;
  }
}

// ---- MFMA 3x3 reflect conv (R10)
template <int MODE>
__global__ __launch_bounds__(256) void k_convm(
    const ushort* __restrict__ xb, const ushort* __restrict__ wc,
    const float* __restrict__ alphap, float* __restrict__ raw,
    ushort* __restrict__ pt) {
  const int tile = blockIdx.x;  // 400 = 80 rows x 5 col-tiles
  const int b = blockIdx.y;
  const int r0 = tile / 5, c0 = (tile % 5) * 16;
  const int lane = threadIdx.x & 63, w = threadIdx.x >> 6;
  const int il = lane & 15, hi = lane >> 4;

  __shared__ ushort zt[16][72];

  short8 wt[9][2];
#pragma unroll
  for (int t = 0; t < 9; ++t)
#pragma unroll
    for (int kc = 0; kc < 2; ++kc)
      wt[t][kc] = *(const short8*)&wc[(size_t)((t * 2 + kc) * 4 + w) * 512 + lane * 8];

  int cl[3], rb[3];
#pragma unroll
  for (int d = 0; d < 3; ++d) {
    const int cc = c0 + il + d - 1;
    cl[d] = cc < 0 ? 1 : (cc > kW - 1 ? kW - 2 : cc);
    const int rr = r0 + d - 1;
    rb[d] = rr < 0 ? 1 : (rr > kH - 1 ? kH - 2 : rr);
  }
  const ushort* xB = xb + (size_t)b * kN * kC;

  f32x4 acc = {0.f, 0.f, 0.f, 0.f};
#pragma unroll
  for (int dh = 0; dh < 3; ++dh) {
    const int nb = rb[dh] * kW;
#pragma unroll
    for (int dw = 0; dw < 3; ++dw) {
      const ushort* src = &xB[(size_t)(nb + cl[dw]) * kC + hi * 8];
      const short8 a0 = *(const short8*)src;
      const short8 a1 = *(const short8*)(src + 32);
      acc = __builtin_amdgcn_mfma_f32_16x16x32_bf16(a0, wt[dh * 3 + dw][0], acc, 0, 0, 0);
      acc = __builtin_amdgcn_mfma_f32_16x16x32_bf16(a1, wt[dh * 3 + dw][1], acc, 0, 0, 0);
    }
  }

  const int n0 = r0 * kW + c0;
  const float alpha = alphap[0];
  if (MODE == 0) {
    *(f32x4*)&raw[((size_t)b * kC + w * 16 + il) * kN + n0 + hi * 4] = acc;
#pragma unroll
    for (int r = 0; r < 4; ++r) {
      const float v = acc[r];
      union { __hip_bfloat16 h; ushort u; } cv;
      cv.h = __float2bfloat16(v >= 0.f ? v : alpha * v);
      zt[hi * 4 + r][w * 16 + il] = cv.u;
    }
    __syncthreads();
    const int t = threadIdx.x;
    const int px = t >> 4, cb = (t & 15) * 4;
    uint2 o2;
    o2.x = (uint)zt[px][cb] | ((uint)zt[px][cb + 1] << 16);
    o2.y = (uint)zt[px][cb + 2] | ((uint)zt[px][cb + 3] << 16);
    *(uint2*)&pt[((size_t)b * kN + n0 + px) * kC + cb] = o2;
  } else {
    f32x4 pr;
#pragma unroll
    for (int r = 0; r < 4; ++r) {
      const float v = acc[r];
      pr[r] = v >= 0.f ? v : alpha * v;
    }
    *(f32x4*)&raw[((size_t)b * kC + w * 16 + il) * kN + n0 + hi * 4] = pr;
  }
}

// ---- phi' = M.p, g = Wg.p (bf16 pixel-major)
__global__ __launch_bounds__(256) void k_pw(
    const __hip_bfloat16* __restrict__ pTb, const __hip_bfloat16* __restrict__ Mb,
    const __hip_bfloat16* __restrict__ wgb, __hip_bfloat16* __restrict__ phb,
    __hip_bfloat16* __restrict__ gb) {
  const int b = blockIdx.y;
  const int lane = threadIdx.x & 63, w = threadIdx.x >> 6;
  const int il = lane & 15, hi = lane >> 4;
  const int n = blockIdx.x * 16 + il;

  const short8 b0 = *(const short8*)&pTb[((size_t)b * kN + n) * kC + hi * 8];
  const short8 b1 = *(const short8*)&pTb[((size_t)b * kN + n) * kC + 32 + hi * 8];

  const short8 am0 = *(const short8*)&Mb[(size_t)(w * 16 + il) * kC + hi * 8];
  const short8 am1 = *(const short8*)&Mb[(size_t)(w * 16 + il) * kC + 32 + hi * 8];
  f32x4 o4 = {0.f, 0.f, 0.f, 0.f};
  o4 = __builtin_amdgcn_mfma_f32_16x16x32_bf16(am0, b0, o4, 0, 0, 0);
  o4 = __builtin_amdgcn_mfma_f32_16x16x32_bf16(am1, b1, o4, 0, 0, 0);
  uint2 p2;
  p2.x = pkbf(o4[0], o4[1]);
  p2.y = pkbf(o4[2], o4[3]);
  *(uint2*)&phb[((size_t)b * kN + n) * kC + w * 16 + hi * 4] = p2;

  const short8 ag0 = *(const short8*)&wgb[(size_t)(w * 16 + il) * kC + hi * 8];
  const short8 ag1 = *(const short8*)&wgb[(size_t)(w * 16 + il) * kC + 32 + hi * 8];
  f32x4 g4 = {0.f, 0.f, 0.f, 0.f};
  g4 = __builtin_amdgcn_mfma_f32_16x16x32_bf16(ag0, b0, g4, 0, 0, 0);
  g4 = __builtin_amdgcn_mfma_f32_16x16x32_bf16(ag1, b1, g4, 0, 0, 0);
  uint2 g2;
  g2.x = pkbf(g4[0], g4[1]);
  g2.y = pkbf(g4[2], g4[3]);
  *(uint2*)&gb[((size_t)b * kN + n) * kC + w * 16 + hi * 4] = g2;
}

// ---- column sums: 4 waves x 32 j share staged theta; super-tile = 128 i.
__global__ __launch_bounds__(256, 2) void k_colstat(
    const __hip_bfloat16* __restrict__ th, const __hip_bfloat16* __restrict__ ph,
    float* __restrict__ partial) {
  const int b = blockIdx.z, ic = blockIdx.y;
  const int lane = threadIdx.x & 63, w = threadIdx.x >> 6;
  const int il = lane & 15, hi = lane >> 4;
  const int j0w = blockIdx.x * 128 + w * 32;

  __shared__ __align__(16) ushort tbufA[8192], tbufB[8192];  // 2 tiles each

  const __hip_bfloat16* thB = th + (size_t)b * kN * kC;
  const size_t phr0 = ((size_t)b * kN + j0w + il) * kC;
  const size_t phr1 = ((size_t)b * kN + j0w + 16 + il) * kC;
  const short8 a00 = *(const short8*)&ph[phr0 + hi * 8];
  const short8 a01 = *(const short8*)&ph[phr0 + 32 + hi * 8];
  const short8 a10 = *(const short8*)&ph[phr1 + hi * 8];
  const short8 a11 = *(const short8*)&ph[phr1 + 32 + hi * 8];

  const int f0 = 2 * w;
  const char* st[2];
#pragma unroll
  for (int k = 0; k < 2; ++k) {
    const int f = f0 + k;
    st[k] = (const char*)&thB[(size_t)(ic * kChunk + (f >> 1) * 16 + il) * kC +
                              (f & 1) * 32 + hi * 8];
  }

#define CSTAGE1(DST)                                                        \
  {                                                                         \
    _Pragma("unroll") for (int k = 0; k < 2; ++k) {                         \
      GL16(st[k], &(DST)[(f0 + k) * 512]);                                  \
      st[k] += (size_t)64 * kC * 2;                                         \
    }                                                                       \
  }
#define CSTAGE2(DST) { CSTAGE1(DST) CSTAGE1((DST) + 4096) }

#define CCOMP1(SRC)                                                        \
  {                                                                        \
    const ushort* bp_ = SRC;                                               \
    _Pragma("unroll") for (int s = 0; s < 4; ++s) {                        \
      const short8 bf0 = *(const short8*)&bp_[(2 * s) * 512 + lane * 8];   \
      const short8 bf1 = *(const short8*)&bp_[(2 * s + 1) * 512 + lane * 8];\
      f32x4 sj0 = {0.f, 0.f, 0.f, 0.f};                                    \
      f32x4 sj1 = {0.f, 0.f, 0.f, 0.f};                                    \
      sj0 = __builtin_amdgcn_mfma_f32_16x16x32_bf16(a00, bf0, sj0, 0, 0, 0);\
      sj0 = __builtin_amdgcn_mfma_f32_16x16x32_bf16(a01, bf1, sj0, 0, 0, 0);\
      sj1 = __builtin_amdgcn_mfma_f32_16x16x32_bf16(a10, bf0, sj1, 0, 0, 0);\
      sj1 = __builtin_amdgcn_mfma_f32_16x16x32_bf16(a11, bf1, sj1, 0, 0, 0);\
      _Pragma("unroll") for (int r = 0; r < 4; ++r) {                      \
        cs0[r] += exp2f(fmaf(sj0[r], kLOG2E, -kSHIFT));                    \
        cs1[r] += exp2f(fmaf(sj1[r], kLOG2E, -kSHIFT));                    \
      }                                                                    \
    }                                                                      \
  }
#define CCOMP2(SRC) { CCOMP1(SRC) CCOMP1((SRC) + 4096) }

  float cs0[4] = {0.f, 0.f, 0.f, 0.f};
  float cs1[4] = {0.f, 0.f, 0.f, 0.f};
  // 10 tiles = 5 super-tiles: prologue + 2 double-iters + tail
  CSTAGE2(tbufA);
  __syncthreads();
#pragma unroll 1
  for (int t = 0; t < 2; ++t) {
    CSTAGE2(tbufB);
    CCOMP2(tbufA);
    __syncthreads();
    CSTAGE2(tbufA);
    CCOMP2(tbufB);
    __syncthreads();
  }
  CCOMP2(tbufA);
#undef CSTAGE1
#undef CSTAGE2
#undef CCOMP1
#undef CCOMP2

#pragma unroll
  for (int r = 0; r < 4; ++r) {
    cs0[r] += __shfl_xor(cs0[r], 1); cs1[r] += __shfl_xor(cs1[r], 1);
    cs0[r] += __shfl_xor(cs0[r], 2); cs1[r] += __shfl_xor(cs1[r], 2);
    cs0[r] += __shfl_xor(cs0[r], 4); cs1[r] += __shfl_xor(cs1[r], 4);
    cs0[r] += __shfl_xor(cs0[r], 8); cs1[r] += __shfl_xor(cs1[r], 8);
  }
  if (il == 0) {
    float* p = partial + (size_t)(b * kSJ + ic) * kN + j0w + hi * 4;
#pragma unroll
    for (int r = 0; r < 4; ++r) {
      p[r] = cs0[r];
      p[16 + r] = cs1[r];
    }
  }
}

// ---- gT[b][c][j] = bf16( g[b][j][c] * 1/colsum[b][j] )
__global__ __launch_bounds__(256) void k_gscale(
    const __hip_bfloat16* __restrict__ gb, const float* __restrict__ partial,
    __hip_bfloat16* __restrict__ gT) {
  const int b = blockIdx.y;
  const int j0 = blockIdx.x * 64;
  const int t = threadIdx.x;
  __shared__ ushort tile[64][66];
  __shared__ float rsv[64];
  if (t < 64) {
    const int j = j0 + t;
    float cs = 0.f;
#pragma unroll
    for (int s = 0; s < kSJ; ++s) cs += partial[(size_t)(b * kSJ + s) * kN + j];
    rsv[t] = 1.0f / cs;
  }
  {
    const int jl = t >> 2, cseg = (t & 3) * 16;
    const ushort* src = (const ushort*)&gb[((size_t)b * kN + j0 + jl) * kC + cseg];
    union { short8 v; ushort u[8]; } u0, u1;
    u0.v = *(const short8*)src;
    u1.v = *(const short8*)(src + 8);
#pragma unroll
    for (int k = 0; k < 8; ++k) {
      tile[jl][cseg + k] = u0.u[k];
      tile[jl][cseg + 8 + k] = u1.u[k];
    }
  }
  __syncthreads();
  const int c = t >> 2, jseg = (t & 3) * 16;
  union { short8 v; ushort u[8]; } o0, o1;
#pragma unroll
  for (int k = 0; k < 16; ++k) {
    const int j = jseg + k;
    const float gv = __uint_as_float((uint)tile[j][c] << 16);
    union { __hip_bfloat16 h; ushort us; } cv;
    cv.h = __float2bfloat16(gv * rsv[j]);
    if (k < 8) o0.u[k] = cv.us; else o1.u[k - 8] = cv.us;
  }
  short8* dst = (short8*)&gT[((size_t)b * kC + c) * kN + j0 + jseg];
  dst[0] = o0.v;
  dst[1] = o1.v;
}

// ---- pass B: 4 waves x 32 i share staged phi+gT; super-tile = 128 j.
__global__ __launch_bounds__(256, 2) void k_nl(
    const __hip_bfloat16* __restrict__ th, const __hip_bfloat16* __restrict__ ph,
    const __hip_bfloat16* __restrict__ gT, ushort* __restrict__ py) {
  const int js = blockIdx.y, b = blockIdx.z;
  const int lane = threadIdx.x & 63, w = threadIdx.x >> 6;
  const int il = lane & 15, hi = lane >> 4;
  const int itile32 = blockIdx.x * 4 + w;
  const int i0w = itile32 * 32;
  const int jstart = js * kChunk;
  const int jbase = ((il >> 2) << 3) + (il & 3);  // sigma(row=il)

  __shared__ __align__(16) ushort bufA[16384], bufB[16384];  // 2 tiles each

  const __hip_bfloat16* phB = ph + (size_t)b * kN * kC;
  const __hip_bfloat16* gTB = gT + (size_t)b * kC * kN;

  const size_t tr0 = ((size_t)b * kN + i0w + il) * kC;
  const size_t tr1 = ((size_t)b * kN + i0w + 16 + il) * kC;
  const short8 tA0k0 = *(const short8*)&th[tr0 + hi * 8];
  const short8 tA0k1 = *(const short8*)&th[tr0 + 32 + hi * 8];
  const short8 tA1k0 = *(const short8*)&th[tr1 + hi * 8];
  const short8 tA1k1 = *(const short8*)&th[tr1 + 32 + hi * 8];

  const int f0 = 2 * w;
  const char* sp[2];
  const char* sg[2];
#pragma unroll
  for (int k = 0; k < 2; ++k) {
    const int f = f0 + k;
    const int pr = jstart + jbase + ((f >> 1) & 1) * 4 + ((f >> 2) & 1) * 32;
    const int pc = (f & 1) * 32 + hi * 8;
    sp[k] = (const char*)&phB[(size_t)pr * kC + pc];
    const int gc = (f & 3) * 16 + il;
    const int gj = jstart + ((f >> 2) & 1) * 32 + hi * 8;
    sg[k] = (const char*)&gTB[(size_t)gc * kN + gj];
  }

#define NLSTAGE1(DST)                                                       \
  {                                                                         \
    _Pragma("unroll") for (int k = 0; k < 2; ++k) {                         \
      GL16(sp[k], &(DST)[(f0 + k) * 512]);                                  \
      GL16(sg[k], &(DST)[4096 + (f0 + k) * 512]);                           \
      sp[k] += (size_t)64 * kC * 2;                                         \
      sg[k] += (size_t)64 * 2;                                              \
    }                                                                       \
  }
#define NLSTAGE2(DST) { NLSTAGE1(DST) NLSTAGE1((DST) + 8192) }

#define QKI(TB0, TB1, s0, s1, s2, s3)                                        \
    f32x4 s0 = {0.f, 0.f, 0.f, 0.f};                                         \
    f32x4 s1 = {0.f, 0.f, 0.f, 0.f};                                         \
    f32x4 s2 = {0.f, 0.f, 0.f, 0.f};                                         \
    f32x4 s3 = {0.f, 0.f, 0.f, 0.f};                                         \
    s0 = __builtin_amdgcn_mfma_f32_16x16x32_bf16(pa0, TB0, s0, 0, 0, 0);     \
    s0 = __builtin_amdgcn_mfma_f32_16x16x32_bf16(pa1, TB1, s0, 0, 0, 0);     \
    s1 = __builtin_amdgcn_mfma_f32_16x16x32_bf16(pa2, TB0, s1, 0, 0, 0);     \
    s1 = __builtin_amdgcn_mfma_f32_16x16x32_bf16(pa3, TB1, s1, 0, 0, 0);     \
    s2 = __builtin_amdgcn_mfma_f32_16x16x32_bf16(pa4, TB0, s2, 0, 0, 0);     \
    s2 = __builtin_amdgcn_mfma_f32_16x16x32_bf16(pa5, TB1, s2, 0, 0, 0);     \
    s3 = __builtin_amdgcn_mfma_f32_16x16x32_bf16(pa6, TB0, s3, 0, 0, 0);     \
    s3 = __builtin_amdgcn_mfma_f32_16x16x32_bf16(pa7, TB1, s3, 0, 0, 0);

// truncating bf16 pack (hot loop): 1 v_perm per pair
#define PACK2(sa, sb, pb)                                                    \
    short8 pb;                                                               \
    {                                                                        \
      uint* pw_ = (uint*)&pb;                                                \
      pw_[0] = pktr(exp2f(fmaf(sa[0], kLOG2E, -kSHIFT)),                     \
                    exp2f(fmaf(sa[1], kLOG2E, -kSHIFT)));                    \
      pw_[1] = pktr(exp2f(fmaf(sa[2], kLOG2E, -kSHIFT)),                     \
                    exp2f(fmaf(sa[3], kLOG2E, -kSHIFT)));                    \
      pw_[2] = pktr(exp2f(fmaf(sb[0], kLOG2E, -kSHIFT)),                     \
                    exp2f(fmaf(sb[1], kLOG2E, -kSHIFT)));                    \
      pw_[3] = pktr(exp2f(fmaf(sb[2], kLOG2E, -kSHIFT)),                     \
                    exp2f(fmaf(sb[3], kLOG2E, -kSHIFT)));                    \
    }

#define NLCOMP1(SRC)                                                         \
  {                                                                          \
    const ushort* bp_ = SRC;                                                 \
    const short8 pa0 = *(const short8*)&bp_[0 * 512 + lane * 8];             \
    const short8 pa1 = *(const short8*)&bp_[1 * 512 + lane * 8];             \
    const short8 pa2 = *(const short8*)&bp_[2 * 512 + lane * 8];             \
    const short8 pa3 = *(const short8*)&bp_[3 * 512 + lane * 8];             \
    const short8 pa4 = *(const short8*)&bp_[4 * 512 + lane * 8];             \
    const short8 pa5 = *(const short8*)&bp_[5 * 512 + lane * 8];             \
    const short8 pa6 = *(const short8*)&bp_[6 * 512 + lane * 8];             \
    const short8 pa7 = *(const short8*)&bp_[7 * 512 + lane * 8];             \
    const short8 ga0 = *(const short8*)&bp_[4096 + 0 * 512 + lane * 8];      \
    const short8 ga1 = *(const short8*)&bp_[4096 + 1 * 512 + lane * 8];      \
    const short8 ga2 = *(const short8*)&bp_[4096 + 2 * 512 + lane * 8];      \
    const short8 ga3 = *(const short8*)&bp_[4096 + 3 * 512 + lane * 8];      \
    const short8 ga4 = *(const short8*)&bp_[4096 + 4 * 512 + lane * 8];      \
    const short8 ga5 = *(const short8*)&bp_[4096 + 5 * 512 + lane * 8];      \
    const short8 ga6 = *(const short8*)&bp_[4096 + 6 * 512 + lane * 8];      \
    const short8 ga7 = *(const short8*)&bp_[4096 + 7 * 512 + lane * 8];      \
    {                                                                        \
      QKI(tA0k0, tA0k1, s00, s01, s02, s03)                                  \
      PACK2(s00, s01, pb00)                                                  \
      PACK2(s02, s03, pb01)                                                  \
      ay00 = __builtin_amdgcn_mfma_f32_16x16x32_bf16(ga0, pb00, ay00, 0, 0, 0);\
      ay01 = __builtin_amdgcn_mfma_f32_16x16x32_bf16(ga1, pb00, ay01, 0, 0, 0);\
      ay02 = __builtin_amdgcn_mfma_f32_16x16x32_bf16(ga2, pb00, ay02, 0, 0, 0);\
      ay03 = __builtin_amdgcn_mfma_f32_16x16x32_bf16(ga3, pb00, ay03, 0, 0, 0);\
      ay00 = __builtin_amdgcn_mfma_f32_16x16x32_bf16(ga4, pb01, ay00, 0, 0, 0);\
      ay01 = __builtin_amdgcn_mfma_f32_16x16x32_bf16(ga5, pb01, ay01, 0, 0, 0);\
      ay02 = __builtin_amdgcn_mfma_f32_16x16x32_bf16(ga6, pb01, ay02, 0, 0, 0);\
      ay03 = __builtin_amdgcn_mfma_f32_16x16x32_bf16(ga7, pb01, ay03, 0, 0, 0);\
    }                                                                        \
    {                                                                        \
      QKI(tA1k0, tA1k1, s10, s11, s12, s13)                                  \
      PACK2(s10, s11, pb10)                                                  \
      PACK2(s12, s13, pb11)                                                  \
      ay10 = __builtin_amdgcn_mfma_f32_16x16x32_bf16(ga0, pb10, ay10, 0, 0, 0);\
      ay11 = __builtin_amdgcn_mfma_f32_16x16x32_bf16(ga1, pb10, ay11, 0, 0, 0);\
      ay12 = __builtin_amdgcn_mfma_f32_16x16x32_bf16(ga2, pb10, ay12, 0, 0, 0);\
      ay13 = __builtin_amdgcn_mfma_f32_16x16x32_bf16(ga3, pb10, ay13, 0, 0, 0);\
      ay10 = __builtin_amdgcn_mfma_f32_16x16x32_bf16(ga4, pb11, ay10, 0, 0, 0);\
      ay11 = __builtin_amdgcn_mfma_f32_16x16x32_bf16(ga5, pb11, ay11, 0, 0, 0);\
      ay12 = __builtin_amdgcn_mfma_f32_16x16x32_bf16(ga6, pb11, ay12, 0, 0, 0);\
      ay13 = __builtin_amdgcn_mfma_f32_16x16x32_bf16(ga7, pb11, ay13, 0, 0, 0);\
    }                                                                        \
  }
#define NLCOMP2(SRC) { NLCOMP1(SRC) NLCOMP1((SRC) + 8192) }

  f32x4 ay00 = {0.f, 0.f, 0.f, 0.f}, ay01 = {0.f, 0.f, 0.f, 0.f};
  f32x4 ay02 = {0.f, 0.f, 0.f, 0.f}, ay03 = {0.f, 0.f, 0.f, 0.f};
  f32x4 ay10 = {0.f, 0.f, 0.f, 0.f}, ay11 = {0.f, 0.f, 0.f, 0.f};
  f32x4 ay12 = {0.f, 0.f, 0.f, 0.f}, ay13 = {0.f, 0.f, 0.f, 0.f};

  // 10 tiles = 5 super-tiles: prologue + 2 double-iters + tail
  NLSTAGE2(bufA);
  __syncthreads();
#pragma unroll 1
  for (int t = 0; t < 2; ++t) {
    NLSTAGE2(bufB);
    NLCOMP2(bufA);
    __syncthreads();
    NLSTAGE2(bufA);
    NLCOMP2(bufB);
    __syncthreads();
  }
  NLCOMP2(bufA);
#undef NLSTAGE1
#undef NLSTAGE2
#undef NLCOMP1
#undef NLCOMP2
#undef QKI
#undef PACK2

  uint* b32 = (uint*)(py + ((size_t)(js * kB + b) * (kN / 32) + itile32) * 2048);
  b32[0 * 64 + lane] = pkbf(ay00[0], ay00[1]);
  b32[1 * 64 + lane] = pkbf(ay00[2], ay00[3]);
  b32[2 * 64 + lane] = pkbf(ay01[0], ay01[1]);
  b32[3 * 64 + lane] = pkbf(ay01[2], ay01[3]);
  b32[4 * 64 + lane] = pkbf(ay02[0], ay02[1]);
  b32[5 * 64 + lane] = pkbf(ay02[2], ay02[3]);
  b32[6 * 64 + lane] = pkbf(ay03[0], ay03[1]);
  b32[7 * 64 + lane] = pkbf(ay03[2], ay03[3]);
  b32[8 * 64 + lane] = pkbf(ay10[0], ay10[1]);
  b32[9 * 64 + lane] = pkbf(ay10[2], ay10[3]);
  b32[10 * 64 + lane] = pkbf(ay11[0], ay11[1]);
  b32[11 * 64 + lane] = pkbf(ay11[2], ay11[3]);
  b32[12 * 64 + lane] = pkbf(ay12[0], ay12[1]);
  b32[13 * 64 + lane] = pkbf(ay12[2], ay12[3]);
  b32[14 * 64 + lane] = pkbf(ay13[0], ay13[1]);
  b32[15 * 64 + lane] = pkbf(ay13[2], ay13[3]);
}

// ---- reduce kSJ partials + fused W_y + residuals -> z bf16 pixel-major.
__global__ __launch_bounds__(128) void k_wy(
    const ushort* __restrict__ py, const __hip_bfloat16* __restrict__ wWb,
    const float* __restrict__ x1, const float* __restrict__ alphap,
    ushort* __restrict__ zb) {
  const int b = blockIdx.y;
  const int lane = threadIdx.x & 63, w = threadIdx.x >> 6;
  const int il = lane & 15, hi = lane >> 4;
  const int itile32 = blockIdx.x * 2 + w;
  const int i0w = itile32 * 32;

  __shared__ __align__(16) ushort yt2[2][32 * 72];
  __shared__ __align__(16) ushort zt2[2][32 * 72];
  ushort* yt = yt2[w];
  ushort* zt = zt2[w];

  float lo[16], hs[16];
#pragma unroll
  for (int k = 0; k < 16; ++k) { lo[k] = 0.f; hs[k] = 0.f; }
#pragma unroll 1
  for (int s = 0; s < kSJ; ++s) {
    const uint* ps =
        (const uint*)(py + ((size_t)(s * kB + b) * (kN / 32) + itile32) * 2048);
#pragma unroll
    for (int k = 0; k < 16; ++k) {
      const uint u = ps[k * 64 + lane];
      lo[k] += __uint_as_float(u << 16);
      hs[k] += __uint_as_float(u & 0xffff0000u);
    }
  }
#pragma unroll
  for (int k = 0; k < 16; ++k) {
    const int row = (k >> 3) * 16 + il;
    const int col = ((k >> 1) & 3) * 16 + hi * 4 + (k & 1) * 2;
    *(uint*)&yt[row * 72 + col] = pkbf(lo[k], hs[k]);
  }

  const float alpha = alphap[0];
#pragma unroll
  for (int a = 0; a < 2; ++a) {
    const short8 by0 = *(const short8*)&yt[(a * 16 + il) * 72 + hi * 8];
    const short8 by1 = *(const short8*)&yt[(a * 16 + il) * 72 + 32 + hi * 8];
#pragma unroll
    for (int q = 0; q < 4; ++q) {
      const short8 af0 = *(const short8*)&wWb[(size_t)(q * 16 + il) * kC + hi * 8];
      const short8 af1 = *(const short8*)&wWb[(size_t)(q * 16 + il) * kC + 32 + hi * 8];
      f32x4 o4 = {0.f, 0.f, 0.f, 0.f};
      o4 = __builtin_amdgcn_mfma_f32_16x16x32_bf16(af0, by0, o4, 0, 0, 0);
      o4 = __builtin_amdgcn_mfma_f32_16x16x32_bf16(af1, by1, o4, 0, 0, 0);
      float zv[4];
#pragma unroll
      for (int r = 0; r < 4; ++r) {
        const int o = q * 16 + hi * 4 + r;
        const size_t idx = ((size_t)b * kC + o) * kN + i0w + a * 16 + il;
        const float xv = x1[idx];
        const float pr = xv >= 0.f ? xv : alpha * xv;
        zv[r] = o4[r] + pr + xv;
      }
      *(uint*)&zt[(a * 16 + il) * 72 + q * 16 + hi * 4] = pkbf(zv[0], zv[1]);
      *(uint*)&zt[(a * 16 + il) * 72 + q * 16 + hi * 4 + 2] = pkbf(zv[2], zv[3]);
    }
  }

  const int px = lane >> 1, cseg = (lane & 1) * 32;
  short8* d = (short8*)&zb[((size_t)b * kN + i0w + px) * kC + cseg];
#pragma unroll
  for (int k = 0; k < 4; ++k)
    d[k] = *(const short8*)&zt[px * 72 + cseg + k * 8];
}

extern "C" void kernel_launch(void* const* d_in, const int* in_sizes, int n_in,
                              void* d_out, int out_size, void* d_ws, size_t ws_size,
                              hipStream_t stream) {
  const float* x      = (const float*)d_in[0];
  const float* w1     = (const float*)d_in[1];
  const float* w2     = (const float*)d_in[2];
  const float* wg     = (const float*)d_in[3];
  const float* wth    = (const float*)d_in[4];
  const float* wph    = (const float*)d_in[5];
  const float* wWm    = (const float*)d_in[6];
  const float* alphap = (const float*)d_in[7];
  float* out = (float*)d_out;

  const size_t SZ = (size_t)kB * kC * kN;  // 819200

  float* x1 = (float*)d_ws;
  __hip_bfloat16* pTb = (__hip_bfloat16*)(x1 + SZ);
  __hip_bfloat16* phb = pTb + SZ;
  __hip_bfloat16* gb  = phb + SZ;
  __hip_bfloat16* gT  = gb + SZ;
  float* partial = (float*)(gT + SZ);
  ushort* wc1 = (ushort*)(partial + (size_t)kB * kSJ * kN);
  ushort* wc2 = wc1 + 9 * kC * kC;
  __hip_bfloat16* Mb  = (__hip_bfloat16*)(wc2 + 9 * kC * kC);
  __hip_bfloat16* wgb = Mb + kC * kC;
  __hip_bfloat16* wWb = wgb + kC * kC;
  ushort* py = (ushort*)(wWb + kC * kC);
  ushort* xb = py;                // overlay: dead before k_nl writes py
  ushort* zb = (ushort*)gb;       // overlay: gb dead after gscale

  k_prep<<<144, 256, 0, stream>>>(w1, w2, wth, wph, wg, wWm, wc1, wc2,
                                  Mb, wgb, wWb);
  k_tobf<<<dim3(kN / 64, kB), 256, 0, stream>>>(x, xb);
  k_convm<0><<<dim3(400, kB), 256, 0, stream>>>(xb, wc1, alphap, x1, (ushort*)pTb);
  k_pw<<<dim3(kN / 16, kB), 256, 0, stream>>>(pTb, Mb, wgb, phb, gb);
  k_colstat<<<dim3(kN / 128, kSJ, kB), 256, 0, stream>>>(pTb, phb, partial);
  k_gscale<<<dim3(kN / 64, kB), 256, 0, stream>>>(gb, partial, gT);
  k_nl<<<dim3(kN / 128, kSJ, kB), 256, 0, stream>>>(pTb, phb, gT, py);
  k_wy<<<dim3(kN / 64, kB), 128, 0, stream>>>(py, wWb, x1, alphap, zb);
  k_convm<1><<<dim3(400, kB), 256, 0, stream>>>(zb, wc2, alphap, out, nullptr);
}

// Round 16
// 109.128 us; speedup vs baseline: 1.2752x; 1.0419x over previous
//
#include <hip/hip_runtime.h>
#include <hip/hip_bf16.h>
#include <cstddef>

// NLBasicBlock fused, round 16:
// - log2e folded into M (phi' pre-scaled); softmax shift dropped (shift-
//   invariant; unshifted exps fit fp32/bf16 range) -> P = exp2f(s) direct,
//   no fmaf in either hot loop.
// - k_pw fused into conv1 epilogue (its p-tile is already in LDS there);
//   one launch + 6.6 MB of pTb traffic deleted.

constexpr int kB = 2, kC = 64, kH = 80, kW = 80, kN = kH * kW;
constexpr int kSJ = 10, kChunk = kN / kSJ, kNT = kChunk / 64;  // 640, 10
constexpr float kLOG2E = 1.4426950408889634f;

typedef __attribute__((ext_vector_type(8))) short short8;
typedef __attribute__((ext_vector_type(4))) float f32x4;

__device__ __forceinline__ uint pkbf(float a, float b) {
  union { __hip_bfloat162 h; uint u; } x;
  x.h.x = __float2bfloat16(a);
  x.h.y = __float2bfloat16(b);
  return x.u;
}

// truncating pack: low16(out)=hi16(a), high16(out)=hi16(b); 1 v_perm_b32
__device__ __forceinline__ uint pktr(float a, float b) {
  return __builtin_amdgcn_perm(__float_as_uint(b), __float_as_uint(a),
                               0x07060302u);
}

#define GL16(gsrc, ldst)                                                    \
  __builtin_amdgcn_global_load_lds(                                         \
      (__attribute__((address_space(1))) void*)(char*)(gsrc),               \
      (__attribute__((address_space(3))) void*)(ldst), 16, 0, 0)

// ---- conv weights -> bf16 MFMA B-fragment-linear; + M = log2e*Wth^T.Wph
__global__ void k_prep(const float* __restrict__ w1, const float* __restrict__ w2,
                       const float* __restrict__ wth, const float* __restrict__ wph,
                       const float* __restrict__ wg, const float* __restrict__ wWm,
                       ushort* __restrict__ wc1, ushort* __restrict__ wc2,
                       __hip_bfloat16* __restrict__ Mb,
                       __hip_bfloat16* __restrict__ wgb,
                       __hip_bfloat16* __restrict__ wWb) {
  const int idx = blockIdx.x * 256 + threadIdx.x;  // 36864
  {
    const int o = idx / (kC * 9);
    const int r = idx % (kC * 9);
    const int ci = r / 9, tap = r % 9;
    const int og = o >> 4, il = o & 15;
    const int kc = ci >> 5, hi = (ci >> 3) & 3, e = ci & 7;
    const int pos = ((tap * 2 + kc) * 4 + og) * 512 + (hi * 16 + il) * 8 + e;
    union { __hip_bfloat16 h; ushort u; } c1, c2;
    c1.h = __float2bfloat16(w1[idx]);
    c2.h = __float2bfloat16(w2[idx]);
    wc1[pos] = c1.u;
    wc2[pos] = c2.u;
  }
  if (idx < kC * kC) {
    const int a = idx >> 6, bb = idx & 63;
    float s = 0.f;
    for (int o = 0; o < kC; ++o) s += wth[o * kC + a] * wph[o * kC + bb];
    Mb[idx] = __float2bfloat16(s * kLOG2E);
    wgb[idx] = __float2bfloat16(wg[idx]);
    wWb[idx] = __float2bfloat16(wWm[idx]);
  }
}

// ---- x f32 [B][C][N] -> bf16 pixel-major [B][N][C]
__global__ __launch_bounds__(256) void k_tobf(const float* __restrict__ x,
                                              ushort* __restrict__ xb) {
  const int b = blockIdx.y;
  const int j0 = blockIdx.x * 64;
  const int t = threadIdx.x;
  __shared__ ushort tile[64][68];
  {
    const int c = t >> 2, jseg = (t & 3) * 16;
    const float* s = &x[((size_t)b * kC + c) * kN + j0 + jseg];
#pragma unroll
    for (int k = 0; k < 16; ++k) {
      union { __hip_bfloat16 h; ushort u; } cv;
      cv.h = __float2bfloat16(s[k]);
      tile[c][jseg + k] = cv.u;
    }
  }
  __syncthreads();
  {
    const int j = t >> 2, cseg = (t & 3) * 16;
    union { short8 v; ushort u[8]; } o0, o1;
#pragma unroll
    for (int k = 0; k < 16; ++k) {
      const ushort u = tile[cseg + k][j];
      if (k < 8) o0.u[k] = u; else o1.u[k - 8] = u;
    }
    short8* d = (short8*)&xb[((size_t)b * kN + j0 + j) * kC + cseg];
    d[0] = o0.v;
    d[1] = o1.v;
  }
}

// ---- MFMA 3x3 reflect conv. MODE 0: raw f32 + prelu bf16 pixel-major
// + fused phi' = M.p and g = Wg.p (k_pw absorbed). MODE 1: prelu f32 only.
template <int MODE>
__global__ __launch_bounds__(256) void k_convm(
    const ushort* __restrict__ xb, const ushort* __restrict__ wc,
    const float* __restrict__ alphap, float* __restrict__ raw,
    ushort* __restrict__ pt, const __hip_bfloat16* __restrict__ Mb,
    const __hip_bfloat16* __restrict__ wgb, __hip_bfloat16* __restrict__ phb,
    __hip_bfloat16* __restrict__ gb) {
  const int tile = blockIdx.x;  // 400 = 80 rows x 5 col-tiles
  const int b = blockIdx.y;
  const int r0 = tile / 5, c0 = (tile % 5) * 16;
  const int lane = threadIdx.x & 63, w = threadIdx.x >> 6;
  const int il = lane & 15, hi = lane >> 4;

  __shared__ ushort zt[16][72];

  short8 wt[9][2];
#pragma unroll
  for (int t = 0; t < 9; ++t)
#pragma unroll
    for (int kc = 0; kc < 2; ++kc)
      wt[t][kc] = *(const short8*)&wc[(size_t)((t * 2 + kc) * 4 + w) * 512 + lane * 8];

  int cl[3], rb[3];
#pragma unroll
  for (int d = 0; d < 3; ++d) {
    const int cc = c0 + il + d - 1;
    cl[d] = cc < 0 ? 1 : (cc > kW - 1 ? kW - 2 : cc);
    const int rr = r0 + d - 1;
    rb[d] = rr < 0 ? 1 : (rr > kH - 1 ? kH - 2 : rr);
  }
  const ushort* xB = xb + (size_t)b * kN * kC;

  f32x4 acc = {0.f, 0.f, 0.f, 0.f};
#pragma unroll
  for (int dh = 0; dh < 3; ++dh) {
    const int nb = rb[dh] * kW;
#pragma unroll
    for (int dw = 0; dw < 3; ++dw) {
      const ushort* src = &xB[(size_t)(nb + cl[dw]) * kC + hi * 8];
      const short8 a0 = *(const short8*)src;
      const short8 a1 = *(const short8*)(src + 32);
      acc = __builtin_amdgcn_mfma_f32_16x16x32_bf16(a0, wt[dh * 3 + dw][0], acc, 0, 0, 0);
      acc = __builtin_amdgcn_mfma_f32_16x16x32_bf16(a1, wt[dh * 3 + dw][1], acc, 0, 0, 0);
    }
  }

  const int n0 = r0 * kW + c0;
  const float alpha = alphap[0];
  if (MODE == 0) {
    *(f32x4*)&raw[((size_t)b * kC + w * 16 + il) * kN + n0 + hi * 4] = acc;
#pragma unroll
    for (int r = 0; r < 4; ++r) {
      const float v = acc[r];
      union { __hip_bfloat16 h; ushort u; } cv;
      cv.h = __float2bfloat16(v >= 0.f ? v : alpha * v);
      zt[hi * 4 + r][w * 16 + il] = cv.u;
    }
    __syncthreads();
    {
      const int t = threadIdx.x;
      const int px = t >> 4, cb = (t & 15) * 4;
      uint2 o2;
      o2.x = (uint)zt[px][cb] | ((uint)zt[px][cb + 1] << 16);
      o2.y = (uint)zt[px][cb + 2] | ((uint)zt[px][cb + 3] << 16);
      *(uint2*)&pt[((size_t)b * kN + n0 + px) * kC + cb] = o2;
    }
    // fused k_pw: B = p cols (pixel il), rows = channels from zt
    {
      const int n = n0 + il;
      const short8 b0 = *(const short8*)&zt[il][hi * 8];
      const short8 b1 = *(const short8*)&zt[il][32 + hi * 8];
      const short8 am0 = *(const short8*)&Mb[(size_t)(w * 16 + il) * kC + hi * 8];
      const short8 am1 = *(const short8*)&Mb[(size_t)(w * 16 + il) * kC + 32 + hi * 8];
      f32x4 o4 = {0.f, 0.f, 0.f, 0.f};
      o4 = __builtin_amdgcn_mfma_f32_16x16x32_bf16(am0, b0, o4, 0, 0, 0);
      o4 = __builtin_amdgcn_mfma_f32_16x16x32_bf16(am1, b1, o4, 0, 0, 0);
      uint2 p2;
      p2.x = pkbf(o4[0], o4[1]);
      p2.y = pkbf(o4[2], o4[3]);
      *(uint2*)&phb[((size_t)b * kN + n) * kC + w * 16 + hi * 4] = p2;
      const short8 ag0 = *(const short8*)&wgb[(size_t)(w * 16 + il) * kC + hi * 8];
      const short8 ag1 = *(const short8*)&wgb[(size_t)(w * 16 + il) * kC + 32 + hi * 8];
      f32x4 g4 = {0.f, 0.f, 0.f, 0.f};
      g4 = __builtin_amdgcn_mfma_f32_16x16x32_bf16(ag0, b0, g4, 0, 0, 0);
      g4 = __builtin_amdgcn_mfma_f32_16x16x32_bf16(ag1, b1, g4, 0, 0, 0);
      uint2 g2;
      g2.x = pkbf(g4[0], g4[1]);
      g2.y = pkbf(g4[2], g4[3]);
      *(uint2*)&gb[((size_t)b * kN + n) * kC + w * 16 + hi * 4] = g2;
    }
  } else {
    f32x4 pr;
#pragma unroll
    for (int r = 0; r < 4; ++r) {
      const float v = acc[r];
      pr[r] = v >= 0.f ? v : alpha * v;
    }
    *(f32x4*)&raw[((size_t)b * kC + w * 16 + il) * kN + n0 + hi * 4] = pr;
  }
}

// ---- column sums: 4 waves x 32 j share staged theta; super-tile = 128 i.
__global__ __launch_bounds__(256, 2) void k_colstat(
    const __hip_bfloat16* __restrict__ th, const __hip_bfloat16* __restrict__ ph,
    float* __restrict__ partial) {
  const int b = blockIdx.z, ic = blockIdx.y;
  const int lane = threadIdx.x & 63, w = threadIdx.x >> 6;
  const int il = lane & 15, hi = lane >> 4;
  const int j0w = blockIdx.x * 128 + w * 32;

  __shared__ __align__(16) ushort tbufA[8192], tbufB[8192];  // 2 tiles each

  const __hip_bfloat16* thB = th + (size_t)b * kN * kC;
  const size_t phr0 = ((size_t)b * kN + j0w + il) * kC;
  const size_t phr1 = ((size_t)b * kN + j0w + 16 + il) * kC;
  const short8 a00 = *(const short8*)&ph[phr0 + hi * 8];
  const short8 a01 = *(const short8*)&ph[phr0 + 32 + hi * 8];
  const short8 a10 = *(const short8*)&ph[phr1 + hi * 8];
  const short8 a11 = *(const short8*)&ph[phr1 + 32 + hi * 8];

  const int f0 = 2 * w;
  const char* st[2];
#pragma unroll
  for (int k = 0; k < 2; ++k) {
    const int f = f0 + k;
    st[k] = (const char*)&thB[(size_t)(ic * kChunk + (f >> 1) * 16 + il) * kC +
                              (f & 1) * 32 + hi * 8];
  }

#define CSTAGE1(DST)                                                        \
  {                                                                         \
    _Pragma("unroll") for (int k = 0; k < 2; ++k) {                         \
      GL16(st[k], &(DST)[(f0 + k) * 512]);                                  \
      st[k] += (size_t)64 * kC * 2;                                         \
    }                                                                       \
  }
#define CSTAGE2(DST) { CSTAGE1(DST) CSTAGE1((DST) + 4096) }

#define CCOMP1(SRC)                                                        \
  {                                                                        \
    const ushort* bp_ = SRC;                                               \
    _Pragma("unroll") for (int s = 0; s < 4; ++s) {                        \
      const short8 bf0 = *(const short8*)&bp_[(2 * s) * 512 + lane * 8];   \
      const short8 bf1 = *(const short8*)&bp_[(2 * s + 1) * 512 + lane * 8];\
      f32x4 sj0 = {0.f, 0.f, 0.f, 0.f};                                    \
      f32x4 sj1 = {0.f, 0.f, 0.f, 0.f};                                    \
      sj0 = __builtin_amdgcn_mfma_f32_16x16x32_bf16(a00, bf0, sj0, 0, 0, 0);\
      sj0 = __builtin_amdgcn_mfma_f32_16x16x32_bf16(a01, bf1, sj0, 0, 0, 0);\
      sj1 = __builtin_amdgcn_mfma_f32_16x16x32_bf16(a10, bf0, sj1, 0, 0, 0);\
      sj1 = __builtin_amdgcn_mfma_f32_16x16x32_bf16(a11, bf1, sj1, 0, 0, 0);\
      _Pragma("unroll") for (int r = 0; r < 4; ++r) {                      \
        cs0[r] += exp2f(sj0[r]);                                           \
        cs1[r] += exp2f(sj1[r]);                                           \
      }                                                                    \
    }                                                                      \
  }
#define CCOMP2(SRC) { CCOMP1(SRC) CCOMP1((SRC) + 4096) }

  float cs0[4] = {0.f, 0.f, 0.f, 0.f};
  float cs1[4] = {0.f, 0.f, 0.f, 0.f};
  // 10 tiles = 5 super-tiles: prologue + 2 double-iters + tail
  CSTAGE2(tbufA);
  __syncthreads();
#pragma unroll 1
  for (int t = 0; t < 2; ++t) {
    CSTAGE2(tbufB);
    CCOMP2(tbufA);
    __syncthreads();
    CSTAGE2(tbufA);
    CCOMP2(tbufB);
    __syncthreads();
  }
  CCOMP2(tbufA);
#undef CSTAGE1
#undef CSTAGE2
#undef CCOMP1
#undef CCOMP2

#pragma unroll
  for (int r = 0; r < 4; ++r) {
    cs0[r] += __shfl_xor(cs0[r], 1); cs1[r] += __shfl_xor(cs1[r], 1);
    cs0[r] += __shfl_xor(cs0[r], 2); cs1[r] += __shfl_xor(cs1[r], 2);
    cs0[r] += __shfl_xor(cs0[r], 4); cs1[r] += __shfl_xor(cs1[r], 4);
    cs0[r] += __shfl_xor(cs0[r], 8); cs1[r] += __shfl_xor(cs1[r], 8);
  }
  if (il == 0) {
    float* p = partial + (size_t)(b * kSJ + ic) * kN + j0w + hi * 4;
#pragma unroll
    for (int r = 0; r < 4; ++r) {
      p[r] = cs0[r];
      p[16 + r] = cs1[r];
    }
  }
}

// ---- gT[b][c][j] = bf16( g[b][j][c] * 1/colsum[b][j] )
__global__ __launch_bounds__(256) void k_gscale(
    const __hip_bfloat16* __restrict__ gb, const float* __restrict__ partial,
    __hip_bfloat16* __restrict__ gT) {
  const int b = blockIdx.y;
  const int j0 = blockIdx.x * 64;
  const int t = threadIdx.x;
  __shared__ ushort tile[64][66];
  __shared__ float rsv[64];
  if (t < 64) {
    const int j = j0 + t;
    float cs = 0.f;
#pragma unroll
    for (int s = 0; s < kSJ; ++s) cs += partial[(size_t)(b * kSJ + s) * kN + j];
    rsv[t] = 1.0f / cs;
  }
  {
    const int jl = t >> 2, cseg = (t & 3) * 16;
    const ushort* src = (const ushort*)&gb[((size_t)b * kN + j0 + jl) * kC + cseg];
    union { short8 v; ushort u[8]; } u0, u1;
    u0.v = *(const short8*)src;
    u1.v = *(const short8*)(src + 8);
#pragma unroll
    for (int k = 0; k < 8; ++k) {
      tile[jl][cseg + k] = u0.u[k];
      tile[jl][cseg + 8 + k] = u1.u[k];
    }
  }
  __syncthreads();
  const int c = t >> 2, jseg = (t & 3) * 16;
  union { short8 v; ushort u[8]; } o0, o1;
#pragma unroll
  for (int k = 0; k < 16; ++k) {
    const int j = jseg + k;
    const float gv = __uint_as_float((uint)tile[j][c] << 16);
    union { __hip_bfloat16 h; ushort us; } cv;
    cv.h = __float2bfloat16(gv * rsv[j]);
    if (k < 8) o0.u[k] = cv.us; else o1.u[k - 8] = cv.us;
  }
  short8* dst = (short8*)&gT[((size_t)b * kC + c) * kN + j0 + jseg];
  dst[0] = o0.v;
  dst[1] = o1.v;
}

// ---- pass B: 4 waves x 32 i share staged phi+gT; super-tile = 128 j.
__global__ __launch_bounds__(256, 2) void k_nl(
    const __hip_bfloat16* __restrict__ th, const __hip_bfloat16* __restrict__ ph,
    const __hip_bfloat16* __restrict__ gT, ushort* __restrict__ py) {
  const int js = blockIdx.y, b = blockIdx.z;
  const int lane = threadIdx.x & 63, w = threadIdx.x >> 6;
  const int il = lane & 15, hi = lane >> 4;
  const int itile32 = blockIdx.x * 4 + w;
  const int i0w = itile32 * 32;
  const int jstart = js * kChunk;
  const int jbase = ((il >> 2) << 3) + (il & 3);  // sigma(row=il)

  __shared__ __align__(16) ushort bufA[16384], bufB[16384];  // 2 tiles each

  const __hip_bfloat16* phB = ph + (size_t)b * kN * kC;
  const __hip_bfloat16* gTB = gT + (size_t)b * kC * kN;

  const size_t tr0 = ((size_t)b * kN + i0w + il) * kC;
  const size_t tr1 = ((size_t)b * kN + i0w + 16 + il) * kC;
  const short8 tA0k0 = *(const short8*)&th[tr0 + hi * 8];
  const short8 tA0k1 = *(const short8*)&th[tr0 + 32 + hi * 8];
  const short8 tA1k0 = *(const short8*)&th[tr1 + hi * 8];
  const short8 tA1k1 = *(const short8*)&th[tr1 + 32 + hi * 8];

  const int f0 = 2 * w;
  const char* sp[2];
  const char* sg[2];
#pragma unroll
  for (int k = 0; k < 2; ++k) {
    const int f = f0 + k;
    const int pr = jstart + jbase + ((f >> 1) & 1) * 4 + ((f >> 2) & 1) * 32;
    const int pc = (f & 1) * 32 + hi * 8;
    sp[k] = (const char*)&phB[(size_t)pr * kC + pc];
    const int gc = (f & 3) * 16 + il;
    const int gj = jstart + ((f >> 2) & 1) * 32 + hi * 8;
    sg[k] = (const char*)&gTB[(size_t)gc * kN + gj];
  }

#define NLSTAGE1(DST)                                                       \
  {                                                                         \
    _Pragma("unroll") for (int k = 0; k < 2; ++k) {                         \
      GL16(sp[k], &(DST)[(f0 + k) * 512]);                                  \
      GL16(sg[k], &(DST)[4096 + (f0 + k) * 512]);                           \
      sp[k] += (size_t)64 * kC * 2;                                         \
      sg[k] += (size_t)64 * 2;                                              \
    }                                                                       \
  }
#define NLSTAGE2(DST) { NLSTAGE1(DST) NLSTAGE1((DST) + 8192) }

#define QKI(TB0, TB1, s0, s1, s2, s3)                                        \
    f32x4 s0 = {0.f, 0.f, 0.f, 0.f};                                         \
    f32x4 s1 = {0.f, 0.f, 0.f, 0.f};                                         \
    f32x4 s2 = {0.f, 0.f, 0.f, 0.f};                                         \
    f32x4 s3 = {0.f, 0.f, 0.f, 0.f};                                         \
    s0 = __builtin_amdgcn_mfma_f32_16x16x32_bf16(pa0, TB0, s0, 0, 0, 0);     \
    s0 = __builtin_amdgcn_mfma_f32_16x16x32_bf16(pa1, TB1, s0, 0, 0, 0);     \
    s1 = __builtin_amdgcn_mfma_f32_16x16x32_bf16(pa2, TB0, s1, 0, 0, 0);     \
    s1 = __builtin_amdgcn_mfma_f32_16x16x32_bf16(pa3, TB1, s1, 0, 0, 0);     \
    s2 = __builtin_amdgcn_mfma_f32_16x16x32_bf16(pa4, TB0, s2, 0, 0, 0);     \
    s2 = __builtin_amdgcn_mfma_f32_16x16x32_bf16(pa5, TB1, s2, 0, 0, 0);     \
    s3 = __builtin_amdgcn_mfma_f32_16x16x32_bf16(pa6, TB0, s3, 0, 0, 0);     \
    s3 = __builtin_amdgcn_mfma_f32_16x16x32_bf16(pa7, TB1, s3, 0, 0, 0);

// exp2 direct (log2e pre-folded into M), truncating pack: 1 perm per pair
#define PACK2(sa, sb, pb)                                                    \
    short8 pb;                                                               \
    {                                                                        \
      uint* pw_ = (uint*)&pb;                                                \
      pw_[0] = pktr(exp2f(sa[0]), exp2f(sa[1]));                             \
      pw_[1] = pktr(exp2f(sa[2]), exp2f(sa[3]));                             \
      pw_[2] = pktr(exp2f(sb[0]), exp2f(sb[1]));                             \
      pw_[3] = pktr(exp2f(sb[2]), exp2f(sb[3]));                             \
    }

#define NLCOMP1(SRC)                                                         \
  {                                                                          \
    const ushort* bp_ = SRC;                                                 \
    const short8 pa0 = *(const short8*)&bp_[0 * 512 + lane * 8];             \
    const short8 pa1 = *(const short8*)&bp_[1 * 512 + lane * 8];             \
    const short8 pa2 = *(const short8*)&bp_[2 * 512 + lane * 8];             \
    const short8 pa3 = *(const short8*)&bp_[3 * 512 + lane * 8];             \
    const short8 pa4 = *(const short8*)&bp_[4 * 512 + lane * 8];             \
    const short8 pa5 = *(const short8*)&bp_[5 * 512 + lane * 8];             \
    const short8 pa6 = *(const short8*)&bp_[6 * 512 + lane * 8];             \
    const short8 pa7 = *(const short8*)&bp_[7 * 512 + lane * 8];             \
    const short8 ga0 = *(const short8*)&bp_[4096 + 0 * 512 + lane * 8];      \
    const short8 ga1 = *(const short8*)&bp_[4096 + 1 * 512 + lane * 8];      \
    const short8 ga2 = *(const short8*)&bp_[4096 + 2 * 512 + lane * 8];      \
    const short8 ga3 = *(const short8*)&bp_[4096 + 3 * 512 + lane * 8];      \
    const short8 ga4 = *(const short8*)&bp_[4096 + 4 * 512 + lane * 8];      \
    const short8 ga5 = *(const short8*)&bp_[4096 + 5 * 512 + lane * 8];      \
    const short8 ga6 = *(const short8*)&bp_[4096 + 6 * 512 + lane * 8];      \
    const short8 ga7 = *(const short8*)&bp_[4096 + 7 * 512 + lane * 8];      \
    {                                                                        \
      QKI(tA0k0, tA0k1, s00, s01, s02, s03)                                  \
      PACK2(s00, s01, pb00)                                                  \
      PACK2(s02, s03, pb01)                                                  \
      ay00 = __builtin_amdgcn_mfma_f32_16x16x32_bf16(ga0, pb00, ay00, 0, 0, 0);\
      ay01 = __builtin_amdgcn_mfma_f32_16x16x32_bf16(ga1, pb00, ay01, 0, 0, 0);\
      ay02 = __builtin_amdgcn_mfma_f32_16x16x32_bf16(ga2, pb00, ay02, 0, 0, 0);\
      ay03 = __builtin_amdgcn_mfma_f32_16x16x32_bf16(ga3, pb00, ay03, 0, 0, 0);\
      ay00 = __builtin_amdgcn_mfma_f32_16x16x32_bf16(ga4, pb01, ay00, 0, 0, 0);\
      ay01 = __builtin_amdgcn_mfma_f32_16x16x32_bf16(ga5, pb01, ay01, 0, 0, 0);\
      ay02 = __builtin_amdgcn_mfma_f32_16x16x32_bf16(ga6, pb01, ay02, 0, 0, 0);\
      ay03 = __builtin_amdgcn_mfma_f32_16x16x32_bf16(ga7, pb01, ay03, 0, 0, 0);\
    }                                                                        \
    {                                                                        \
      QKI(tA1k0, tA1k1, s10, s11, s12, s13)                                  \
      PACK2(s10, s11, pb10)                                                  \
      PACK2(s12, s13, pb11)                                                  \
      ay10 = __builtin_amdgcn_mfma_f32_16x16x32_bf16(ga0, pb10, ay10, 0, 0, 0);\
      ay11 = __builtin_amdgcn_mfma_f32_16x16x32_bf16(ga1, pb10, ay11, 0, 0, 0);\
      ay12 = __builtin_amdgcn_mfma_f32_16x16x32_bf16(ga2, pb10, ay12, 0, 0, 0);\
      ay13 = __builtin_amdgcn_mfma_f32_16x16x32_bf16(ga3, pb10, ay13, 0, 0, 0);\
      ay10 = __builtin_amdgcn_mfma_f32_16x16x32_bf16(ga4, pb11, ay10, 0, 0, 0);\
      ay11 = __builtin_amdgcn_mfma_f32_16x16x32_bf16(ga5, pb11, ay11, 0, 0, 0);\
      ay12 = __builtin_amdgcn_mfma_f32_16x16x32_bf16(ga6, pb11, ay12, 0, 0, 0);\
      ay13 = __builtin_amdgcn_mfma_f32_16x16x32_bf16(ga7, pb11, ay13, 0, 0, 0);\
    }                                                                        \
  }
#define NLCOMP2(SRC) { NLCOMP1(SRC) NLCOMP1((SRC) + 8192) }

  f32x4 ay00 = {0.f, 0.f, 0.f, 0.f}, ay01 = {0.f, 0.f, 0.f, 0.f};
  f32x4 ay02 = {0.f, 0.f, 0.f, 0.f}, ay03 = {0.f, 0.f, 0.f, 0.f};
  f32x4 ay10 = {0.f, 0.f, 0.f, 0.f}, ay11 = {0.f, 0.f, 0.f, 0.f};
  f32x4 ay12 = {0.f, 0.f, 0.f, 0.f}, ay13 = {0.f, 0.f, 0.f, 0.f};

  // 10 tiles = 5 super-tiles: prologue + 2 double-iters + tail
  NLSTAGE2(bufA);
  __syncthreads();
#pragma unroll 1
  for (int t = 0; t < 2; ++t) {
    NLSTAGE2(bufB);
    NLCOMP2(bufA);
    __syncthreads();
    NLSTAGE2(bufA);
    NLCOMP2(bufB);
    __syncthreads();
  }
  NLCOMP2(bufA);
#undef NLSTAGE1
#undef NLSTAGE2
#undef NLCOMP1
#undef NLCOMP2
#undef QKI
#undef PACK2

  uint* b32 = (uint*)(py + ((size_t)(js * kB + b) * (kN / 32) + itile32) * 2048);
  b32[0 * 64 + lane] = pkbf(ay00[0], ay00[1]);
  b32[1 * 64 + lane] = pkbf(ay00[2], ay00[3]);
  b32[2 * 64 + lane] = pkbf(ay01[0], ay01[1]);
  b32[3 * 64 + lane] = pkbf(ay01[2], ay01[3]);
  b32[4 * 64 + lane] = pkbf(ay02[0], ay02[1]);
  b32[5 * 64 + lane] = pkbf(ay02[2], ay02[3]);
  b32[6 * 64 + lane] = pkbf(ay03[0], ay03[1]);
  b32[7 * 64 + lane] = pkbf(ay03[2], ay03[3]);
  b32[8 * 64 + lane] = pkbf(ay10[0], ay10[1]);
  b32[9 * 64 + lane] = pkbf(ay10[2], ay10[3]);
  b32[10 * 64 + lane] = pkbf(ay11[0], ay11[1]);
  b32[11 * 64 + lane] = pkbf(ay11[2], ay11[3]);
  b32[12 * 64 + lane] = pkbf(ay12[0], ay12[1]);
  b32[13 * 64 + lane] = pkbf(ay12[2], ay12[3]);
  b32[14 * 64 + lane] = pkbf(ay13[0], ay13[1]);
  b32[15 * 64 + lane] = pkbf(ay13[2], ay13[3]);
}

// ---- reduce kSJ partials + fused W_y + residuals -> z bf16 pixel-major.
__global__ __launch_bounds__(128) void k_wy(
    const ushort* __restrict__ py, const __hip_bfloat16* __restrict__ wWb,
    const float* __restrict__ x1, const float* __restrict__ alphap,
    ushort* __restrict__ zb) {
  const int b = blockIdx.y;
  const int lane = threadIdx.x & 63, w = threadIdx.x >> 6;
  const int il = lane & 15, hi = lane >> 4;
  const int itile32 = blockIdx.x * 2 + w;
  const int i0w = itile32 * 32;

  __shared__ __align__(16) ushort yt2[2][32 * 72];
  __shared__ __align__(16) ushort zt2[2][32 * 72];
  ushort* yt = yt2[w];
  ushort* zt = zt2[w];

  float lo[16], hs[16];
#pragma unroll
  for (int k = 0; k < 16; ++k) { lo[k] = 0.f; hs[k] = 0.f; }
#pragma unroll 1
  for (int s = 0; s < kSJ; ++s) {
    const uint* ps =
        (const uint*)(py + ((size_t)(s * kB + b) * (kN / 32) + itile32) * 2048);
#pragma unroll
    for (int k = 0; k < 16; ++k) {
      const uint u = ps[k * 64 + lane];
      lo[k] += __uint_as_float(u << 16);
      hs[k] += __uint_as_float(u & 0xffff0000u);
    }
  }
#pragma unroll
  for (int k = 0; k < 16; ++k) {
    const int row = (k >> 3) * 16 + il;
    const int col = ((k >> 1) & 3) * 16 + hi * 4 + (k & 1) * 2;
    *(uint*)&yt[row * 72 + col] = pkbf(lo[k], hs[k]);
  }

  const float alpha = alphap[0];
#pragma unroll
  for (int a = 0; a < 2; ++a) {
    const short8 by0 = *(const short8*)&yt[(a * 16 + il) * 72 + hi * 8];
    const short8 by1 = *(const short8*)&yt[(a * 16 + il) * 72 + 32 + hi * 8];
#pragma unroll
    for (int q = 0; q < 4; ++q) {
      const short8 af0 = *(const short8*)&wWb[(size_t)(q * 16 + il) * kC + hi * 8];
      const short8 af1 = *(const short8*)&wWb[(size_t)(q * 16 + il) * kC + 32 + hi * 8];
      f32x4 o4 = {0.f, 0.f, 0.f, 0.f};
      o4 = __builtin_amdgcn_mfma_f32_16x16x32_bf16(af0, by0, o4, 0, 0, 0);
      o4 = __builtin_amdgcn_mfma_f32_16x16x32_bf16(af1, by1, o4, 0, 0, 0);
      float zv[4];
#pragma unroll
      for (int r = 0; r < 4; ++r) {
        const int o = q * 16 + hi * 4 + r;
        const size_t idx = ((size_t)b * kC + o) * kN + i0w + a * 16 + il;
        const float xv = x1[idx];
        const float pr = xv >= 0.f ? xv : alpha * xv;
        zv[r] = o4[r] + pr + xv;
      }
      *(uint*)&zt[(a * 16 + il) * 72 + q * 16 + hi * 4] = pkbf(zv[0], zv[1]);
      *(uint*)&zt[(a * 16 + il) * 72 + q * 16 + hi * 4 + 2] = pkbf(zv[2], zv[3]);
    }
  }

  const int px = lane >> 1, cseg = (lane & 1) * 32;
  short8* d = (short8*)&zb[((size_t)b * kN + i0w + px) * kC + cseg];
#pragma unroll
  for (int k = 0; k < 4; ++k)
    d[k] = *(const short8*)&zt[px * 72 + cseg + k * 8];
}

extern "C" void kernel_launch(void* const* d_in, const int* in_sizes, int n_in,
                              void* d_out, int out_size, void* d_ws, size_t ws_size,
                              hipStream_t stream) {
  const float* x      = (const float*)d_in[0];
  const float* w1     = (const float*)d_in[1];
  const float* w2     = (const float*)d_in[2];
  const float* wg     = (const float*)d_in[3];
  const float* wth    = (const float*)d_in[4];
  const float* wph    = (const float*)d_in[5];
  const float* wWm    = (const float*)d_in[6];
  const float* alphap = (const float*)d_in[7];
  float* out = (float*)d_out;

  const size_t SZ = (size_t)kB * kC * kN;  // 819200

  float* x1 = (float*)d_ws;
  __hip_bfloat16* pTb = (__hip_bfloat16*)(x1 + SZ);
  __hip_bfloat16* phb = pTb + SZ;
  __hip_bfloat16* gb  = phb + SZ;
  __hip_bfloat16* gT  = gb + SZ;
  float* partial = (float*)(gT + SZ);
  ushort* wc1 = (ushort*)(partial + (size_t)kB * kSJ * kN);
  ushort* wc2 = wc1 + 9 * kC * kC;
  __hip_bfloat16* Mb  = (__hip_bfloat16*)(wc2 + 9 * kC * kC);
  __hip_bfloat16* wgb = Mb + kC * kC;
  __hip_bfloat16* wWb = wgb + kC * kC;
  ushort* py = (ushort*)(wWb + kC * kC);
  ushort* xb = py;                // overlay: dead before k_nl writes py
  ushort* zb = (ushort*)gb;       // overlay: gb dead after gscale

  k_prep<<<144, 256, 0, stream>>>(w1, w2, wth, wph, wg, wWm, wc1, wc2,
                                  Mb, wgb, wWb);
  k_tobf<<<dim3(kN / 64, kB), 256, 0, stream>>>(x, xb);
  k_convm<0><<<dim3(400, kB), 256, 0, stream>>>(xb, wc1, alphap, x1,
                                                (ushort*)pTb, Mb, wgb, phb, gb);
  k_colstat<<<dim3(kN / 128, kSJ, kB), 256, 0, stream>>>(pTb, phb, partial);
  k_gscale<<<dim3(kN / 64, kB), 256, 0, stream>>>(gb, partial, gT);
  k_nl<<<dim3(kN / 128, kSJ, kB), 256, 0, stream>>>(pTb, phb, gT, py);
  k_wy<<<dim3(kN / 64, kB), 128, 0, stream>>>(py, wWb, x1, alphap, zb);
  k_convm<1><<<dim3(400, kB), 256, 0, stream>>>(zb, wc2, alphap, out, nullptr,
                                                nullptr, nullptr, nullptr,
                                                nullptr);
}

// Round 17
// 106.136 us; speedup vs baseline: 1.3112x; 1.0282x over previous
//
#include <hip/hip_runtime.h>
#include <hip/hip_bf16.h>
#include <cstddef>

// NLBasicBlock fused, round 17: i-tile 64/wave in k_nl, j-tile 64/wave in
// k_colstat (2x MFMA per staged byte vs R16; 16 f32x4 acc + 8 theta frags
// fit under the (256,2) VGPR cap); k_tobf merged into k_prep.

constexpr int kB = 2, kC = 64, kH = 80, kW = 80, kN = kH * kW;
constexpr int kSJ = 10, kChunk = kN / kSJ, kNT = kChunk / 64;  // 640, 10
constexpr float kLOG2E = 1.4426950408889634f;

typedef __attribute__((ext_vector_type(8))) short short8;
typedef __attribute__((ext_vector_type(4))) float f32x4;

__device__ __forceinline__ uint pkbf(float a, float b) {
  union { __hip_bfloat162 h; uint u; } x;
  x.h.x = __float2bfloat16(a);
  x.h.y = __float2bfloat16(b);
  return x.u;
}

// truncating pack: low16(out)=hi16(a), high16(out)=hi16(b); 1 v_perm_b32
__device__ __forceinline__ uint pktr(float a, float b) {
  return __builtin_amdgcn_perm(__float_as_uint(b), __float_as_uint(a),
                               0x07060302u);
}

#define GL16(gsrc, ldst)                                                    \
  __builtin_amdgcn_global_load_lds(                                         \
      (__attribute__((address_space(1))) void*)(char*)(gsrc),               \
      (__attribute__((address_space(3))) void*)(ldst), 16, 0, 0)

// ---- prep (conv weights -> fragment-linear bf16, M = log2e*Wth^T.Wph,
// Wg/WW bf16) fused with x f32 -> bf16 pixel-major transpose.
__global__ __launch_bounds__(256) void k_prep(
    const float* __restrict__ w1, const float* __restrict__ w2,
    const float* __restrict__ wth, const float* __restrict__ wph,
    const float* __restrict__ wg, const float* __restrict__ wWm,
    const float* __restrict__ x, ushort* __restrict__ wc1,
    ushort* __restrict__ wc2, __hip_bfloat16* __restrict__ Mb,
    __hip_bfloat16* __restrict__ wgb, __hip_bfloat16* __restrict__ wWb,
    ushort* __restrict__ xb) {
  const int bx = blockIdx.x;
  if (bx < 144) {
    const int idx = bx * 256 + threadIdx.x;  // 36864
    {
      const int o = idx / (kC * 9);
      const int r = idx % (kC * 9);
      const int ci = r / 9, tap = r % 9;
      const int og = o >> 4, il = o & 15;
      const int kc = ci >> 5, hi = (ci >> 3) & 3, e = ci & 7;
      const int pos = ((tap * 2 + kc) * 4 + og) * 512 + (hi * 16 + il) * 8 + e;
      union { __hip_bfloat16 h; ushort u; } c1, c2;
      c1.h = __float2bfloat16(w1[idx]);
      c2.h = __float2bfloat16(w2[idx]);
      wc1[pos] = c1.u;
      wc2[pos] = c2.u;
    }
    if (idx < kC * kC) {
      const int a = idx >> 6, bb = idx & 63;
      float s = 0.f;
      for (int o = 0; o < kC; ++o) s += wth[o * kC + a] * wph[o * kC + bb];
      Mb[idx] = __float2bfloat16(s * kLOG2E);
      wgb[idx] = __float2bfloat16(wg[idx]);
      wWb[idx] = __float2bfloat16(wWm[idx]);
    }
    return;
  }
  // tobf part: 200 blocks
  const int tb = bx - 144;
  const int b = tb / 100;
  const int j0 = (tb % 100) * 64;
  const int t = threadIdx.x;
  __shared__ ushort tile[64][68];
  {
    const int c = t >> 2, jseg = (t & 3) * 16;
    const float* s = &x[((size_t)b * kC + c) * kN + j0 + jseg];
#pragma unroll
    for (int k = 0; k < 16; ++k) {
      union { __hip_bfloat16 h; ushort u; } cv;
      cv.h = __float2bfloat16(s[k]);
      tile[c][jseg + k] = cv.u;
    }
  }
  __syncthreads();
  {
    const int j = t >> 2, cseg = (t & 3) * 16;
    union { short8 v; ushort u[8]; } o0, o1;
#pragma unroll
    for (int k = 0; k < 16; ++k) {
      const ushort u = tile[cseg + k][j];
      if (k < 8) o0.u[k] = u; else o1.u[k - 8] = u;
    }
    short8* d = (short8*)&xb[((size_t)b * kN + j0 + j) * kC + cseg];
    d[0] = o0.v;
    d[1] = o1.v;
  }
}

// ---- MFMA 3x3 reflect conv. MODE 0: raw f32 + prelu bf16 pixel-major
// + fused phi' = M.p and g = Wg.p. MODE 1: prelu f32 only.
template <int MODE>
__global__ __launch_bounds__(256) void k_convm(
    const ushort* __restrict__ xb, const ushort* __restrict__ wc,
    const float* __restrict__ alphap, float* __restrict__ raw,
    ushort* __restrict__ pt, const __hip_bfloat16* __restrict__ Mb,
    const __hip_bfloat16* __restrict__ wgb, __hip_bfloat16* __restrict__ phb,
    __hip_bfloat16* __restrict__ gb) {
  const int tile = blockIdx.x;  // 400 = 80 rows x 5 col-tiles
  const int b = blockIdx.y;
  const int r0 = tile / 5, c0 = (tile % 5) * 16;
  const int lane = threadIdx.x & 63, w = threadIdx.x >> 6;
  const int il = lane & 15, hi = lane >> 4;

  __shared__ ushort zt[16][72];

  short8 wt[9][2];
#pragma unroll
  for (int t = 0; t < 9; ++t)
#pragma unroll
    for (int kc = 0; kc < 2; ++kc)
      wt[t][kc] = *(const short8*)&wc[(size_t)((t * 2 + kc) * 4 + w) * 512 + lane * 8];

  int cl[3], rb[3];
#pragma unroll
  for (int d = 0; d < 3; ++d) {
    const int cc = c0 + il + d - 1;
    cl[d] = cc < 0 ? 1 : (cc > kW - 1 ? kW - 2 : cc);
    const int rr = r0 + d - 1;
    rb[d] = rr < 0 ? 1 : (rr > kH - 1 ? kH - 2 : rr);
  }
  const ushort* xB = xb + (size_t)b * kN * kC;

  f32x4 acc = {0.f, 0.f, 0.f, 0.f};
#pragma unroll
  for (int dh = 0; dh < 3; ++dh) {
    const int nb = rb[dh] * kW;
#pragma unroll
    for (int dw = 0; dw < 3; ++dw) {
      const ushort* src = &xB[(size_t)(nb + cl[dw]) * kC + hi * 8];
      const short8 a0 = *(const short8*)src;
      const short8 a1 = *(const short8*)(src + 32);
      acc = __builtin_amdgcn_mfma_f32_16x16x32_bf16(a0, wt[dh * 3 + dw][0], acc, 0, 0, 0);
      acc = __builtin_amdgcn_mfma_f32_16x16x32_bf16(a1, wt[dh * 3 + dw][1], acc, 0, 0, 0);
    }
  }

  const int n0 = r0 * kW + c0;
  const float alpha = alphap[0];
  if (MODE == 0) {
    *(f32x4*)&raw[((size_t)b * kC + w * 16 + il) * kN + n0 + hi * 4] = acc;
#pragma unroll
    for (int r = 0; r < 4; ++r) {
      const float v = acc[r];
      union { __hip_bfloat16 h; ushort u; } cv;
      cv.h = __float2bfloat16(v >= 0.f ? v : alpha * v);
      zt[hi * 4 + r][w * 16 + il] = cv.u;
    }
    __syncthreads();
    {
      const int t = threadIdx.x;
      const int px = t >> 4, cb = (t & 15) * 4;
      uint2 o2;
      o2.x = (uint)zt[px][cb] | ((uint)zt[px][cb + 1] << 16);
      o2.y = (uint)zt[px][cb + 2] | ((uint)zt[px][cb + 3] << 16);
      *(uint2*)&pt[((size_t)b * kN + n0 + px) * kC + cb] = o2;
    }
    {
      const int n = n0 + il;
      const short8 b0 = *(const short8*)&zt[il][hi * 8];
      const short8 b1 = *(const short8*)&zt[il][32 + hi * 8];
      const short8 am0 = *(const short8*)&Mb[(size_t)(w * 16 + il) * kC + hi * 8];
      const short8 am1 = *(const short8*)&Mb[(size_t)(w * 16 + il) * kC + 32 + hi * 8];
      f32x4 o4 = {0.f, 0.f, 0.f, 0.f};
      o4 = __builtin_amdgcn_mfma_f32_16x16x32_bf16(am0, b0, o4, 0, 0, 0);
      o4 = __builtin_amdgcn_mfma_f32_16x16x32_bf16(am1, b1, o4, 0, 0, 0);
      uint2 p2;
      p2.x = pkbf(o4[0], o4[1]);
      p2.y = pkbf(o4[2], o4[3]);
      *(uint2*)&phb[((size_t)b * kN + n) * kC + w * 16 + hi * 4] = p2;
      const short8 ag0 = *(const short8*)&wgb[(size_t)(w * 16 + il) * kC + hi * 8];
      const short8 ag1 = *(const short8*)&wgb[(size_t)(w * 16 + il) * kC + 32 + hi * 8];
      f32x4 g4 = {0.f, 0.f, 0.f, 0.f};
      g4 = __builtin_amdgcn_mfma_f32_16x16x32_bf16(ag0, b0, g4, 0, 0, 0);
      g4 = __builtin_amdgcn_mfma_f32_16x16x32_bf16(ag1, b1, g4, 0, 0, 0);
      uint2 g2;
      g2.x = pkbf(g4[0], g4[1]);
      g2.y = pkbf(g4[2], g4[3]);
      *(uint2*)&gb[((size_t)b * kN + n) * kC + w * 16 + hi * 4] = g2;
    }
  } else {
    f32x4 pr;
#pragma unroll
    for (int r = 0; r < 4; ++r) {
      const float v = acc[r];
      pr[r] = v >= 0.f ? v : alpha * v;
    }
    *(f32x4*)&raw[((size_t)b * kC + w * 16 + il) * kN + n0 + hi * 4] = pr;
  }
}

// ---- column sums: 4 waves x 64 j share staged theta; super-tile = 128 i.
__global__ __launch_bounds__(256, 2) void k_colstat(
    const __hip_bfloat16* __restrict__ th, const __hip_bfloat16* __restrict__ ph,
    float* __restrict__ partial) {
  const int b = blockIdx.z, ic = blockIdx.y;
  const int lane = threadIdx.x & 63, w = threadIdx.x >> 6;
  const int il = lane & 15, hi = lane >> 4;
  const int j0w = blockIdx.x * 256 + w * 64;

  __shared__ __align__(16) ushort tbufA[8192], tbufB[8192];  // 2 tiles each

  const __hip_bfloat16* thB = th + (size_t)b * kN * kC;
  short8 aA[4][2];
#pragma unroll
  for (int c = 0; c < 4; ++c) {
    const size_t pr = ((size_t)b * kN + j0w + c * 16 + il) * kC;
    aA[c][0] = *(const short8*)&ph[pr + hi * 8];
    aA[c][1] = *(const short8*)&ph[pr + 32 + hi * 8];
  }

  const int f0 = 2 * w;
  const char* st[2];
#pragma unroll
  for (int k = 0; k < 2; ++k) {
    const int f = f0 + k;
    st[k] = (const char*)&thB[(size_t)(ic * kChunk + (f >> 1) * 16 + il) * kC +
                              (f & 1) * 32 + hi * 8];
  }

#define CSTAGE1(DST)                                                        \
  {                                                                         \
    _Pragma("unroll") for (int k = 0; k < 2; ++k) {                         \
      GL16(st[k], &(DST)[(f0 + k) * 512]);                                  \
      st[k] += (size_t)64 * kC * 2;                                         \
    }                                                                       \
  }
#define CSTAGE2(DST) { CSTAGE1(DST) CSTAGE1((DST) + 4096) }

#define CCOMP1(SRC)                                                        \
  {                                                                        \
    const ushort* bp_ = SRC;                                               \
    _Pragma("unroll") for (int s = 0; s < 4; ++s) {                        \
      const short8 bf0 = *(const short8*)&bp_[(2 * s) * 512 + lane * 8];   \
      const short8 bf1 = *(const short8*)&bp_[(2 * s + 1) * 512 + lane * 8];\
      _Pragma("unroll") for (int c = 0; c < 4; ++c) {                      \
        f32x4 sj = {0.f, 0.f, 0.f, 0.f};                                   \
        sj = __builtin_amdgcn_mfma_f32_16x16x32_bf16(aA[c][0], bf0, sj, 0, 0, 0);\
        sj = __builtin_amdgcn_mfma_f32_16x16x32_bf16(aA[c][1], bf1, sj, 0, 0, 0);\
        _Pragma("unroll") for (int r = 0; r < 4; ++r)                      \
            cs[c][r] += exp2f(sj[r]);                                      \
      }                                                                    \
    }                                                                      \
  }
#define CCOMP2(SRC) { CCOMP1(SRC) CCOMP1((SRC) + 4096) }

  float cs[4][4];
#pragma unroll
  for (int c = 0; c < 4; ++c)
#pragma unroll
    for (int r = 0; r < 4; ++r) cs[c][r] = 0.f;

  CSTAGE2(tbufA);
  __syncthreads();
#pragma unroll 1
  for (int t = 0; t < 2; ++t) {
    CSTAGE2(tbufB);
    CCOMP2(tbufA);
    __syncthreads();
    CSTAGE2(tbufA);
    CCOMP2(tbufB);
    __syncthreads();
  }
  CCOMP2(tbufA);
#undef CSTAGE1
#undef CSTAGE2
#undef CCOMP1
#undef CCOMP2

#pragma unroll
  for (int c = 0; c < 4; ++c)
#pragma unroll
    for (int r = 0; r < 4; ++r) {
      cs[c][r] += __shfl_xor(cs[c][r], 1);
      cs[c][r] += __shfl_xor(cs[c][r], 2);
      cs[c][r] += __shfl_xor(cs[c][r], 4);
      cs[c][r] += __shfl_xor(cs[c][r], 8);
    }
  if (il == 0) {
    float* p = partial + (size_t)(b * kSJ + ic) * kN + j0w + hi * 4;
#pragma unroll
    for (int c = 0; c < 4; ++c)
#pragma unroll
      for (int r = 0; r < 4; ++r) p[c * 16 + r] = cs[c][r];
  }
}

// ---- gT[b][c][j] = bf16( g[b][j][c] * 1/colsum[b][j] )
__global__ __launch_bounds__(256) void k_gscale(
    const __hip_bfloat16* __restrict__ gb, const float* __restrict__ partial,
    __hip_bfloat16* __restrict__ gT) {
  const int b = blockIdx.y;
  const int j0 = blockIdx.x * 64;
  const int t = threadIdx.x;
  __shared__ ushort tile[64][66];
  __shared__ float rsv[64];
  if (t < 64) {
    const int j = j0 + t;
    float cs = 0.f;
#pragma unroll
    for (int s = 0; s < kSJ; ++s) cs += partial[(size_t)(b * kSJ + s) * kN + j];
    rsv[t] = 1.0f / cs;
  }
  {
    const int jl = t >> 2, cseg = (t & 3) * 16;
    const ushort* src = (const ushort*)&gb[((size_t)b * kN + j0 + jl) * kC + cseg];
    union { short8 v; ushort u[8]; } u0, u1;
    u0.v = *(const short8*)src;
    u1.v = *(const short8*)(src + 8);
#pragma unroll
    for (int k = 0; k < 8; ++k) {
      tile[jl][cseg + k] = u0.u[k];
      tile[jl][cseg + 8 + k] = u1.u[k];
    }
  }
  __syncthreads();
  const int c = t >> 2, jseg = (t & 3) * 16;
  union { short8 v; ushort u[8]; } o0, o1;
#pragma unroll
  for (int k = 0; k < 16; ++k) {
    const int j = jseg + k;
    const float gv = __uint_as_float((uint)tile[j][c] << 16);
    union { __hip_bfloat16 h; ushort us; } cv;
    cv.h = __float2bfloat16(gv * rsv[j]);
    if (k < 8) o0.u[k] = cv.us; else o1.u[k - 8] = cv.us;
  }
  short8* dst = (short8*)&gT[((size_t)b * kC + c) * kN + j0 + jseg];
  dst[0] = o0.v;
  dst[1] = o1.v;
}

// ---- pass B: 4 waves x 64 i share staged phi+gT; super-tile = 128 j.
__global__ __launch_bounds__(256, 2) void k_nl(
    const __hip_bfloat16* __restrict__ th, const __hip_bfloat16* __restrict__ ph,
    const __hip_bfloat16* __restrict__ gT, ushort* __restrict__ py) {
  const int js = blockIdx.y, b = blockIdx.z;
  const int lane = threadIdx.x & 63, w = threadIdx.x >> 6;
  const int il = lane & 15, hi = lane >> 4;
  const int itile64 = blockIdx.x * 4 + w;
  const int i0w = itile64 * 64;
  const int jstart = js * kChunk;
  const int jbase = ((il >> 2) << 3) + (il & 3);  // sigma(row=il)

  __shared__ __align__(16) ushort bufA[16384], bufB[16384];  // 2 tiles each

  const __hip_bfloat16* phB = ph + (size_t)b * kN * kC;
  const __hip_bfloat16* gTB = gT + (size_t)b * kC * kN;

  short8 tA[4][2];
#pragma unroll
  for (int c = 0; c < 4; ++c) {
    const size_t tr = ((size_t)b * kN + i0w + c * 16 + il) * kC;
    tA[c][0] = *(const short8*)&th[tr + hi * 8];
    tA[c][1] = *(const short8*)&th[tr + 32 + hi * 8];
  }

  const int f0 = 2 * w;
  const char* sp[2];
  const char* sg[2];
#pragma unroll
  for (int k = 0; k < 2; ++k) {
    const int f = f0 + k;
    const int pr = jstart + jbase + ((f >> 1) & 1) * 4 + ((f >> 2) & 1) * 32;
    const int pc = (f & 1) * 32 + hi * 8;
    sp[k] = (const char*)&phB[(size_t)pr * kC + pc];
    const int gc = (f & 3) * 16 + il;
    const int gj = jstart + ((f >> 2) & 1) * 32 + hi * 8;
    sg[k] = (const char*)&gTB[(size_t)gc * kN + gj];
  }

#define NLSTAGE1(DST)                                                       \
  {                                                                         \
    _Pragma("unroll") for (int k = 0; k < 2; ++k) {                         \
      GL16(sp[k], &(DST)[(f0 + k) * 512]);                                  \
      GL16(sg[k], &(DST)[4096 + (f0 + k) * 512]);                           \
      sp[k] += (size_t)64 * kC * 2;                                         \
      sg[k] += (size_t)64 * 2;                                              \
    }                                                                       \
  }
#define NLSTAGE2(DST) { NLSTAGE1(DST) NLSTAGE1((DST) + 8192) }

// exp2 direct (log2e pre-folded into M), truncating pack: 1 perm per pair
#define NLCOMP1(SRC)                                                         \
  {                                                                          \
    const ushort* bp_ = SRC;                                                 \
    short8 pa[8], ga[8];                                                     \
    _Pragma("unroll") for (int f = 0; f < 8; ++f) {                          \
      pa[f] = *(const short8*)&bp_[f * 512 + lane * 8];                      \
      ga[f] = *(const short8*)&bp_[4096 + f * 512 + lane * 8];               \
    }                                                                        \
    _Pragma("unroll") for (int c = 0; c < 4; ++c) {                          \
      f32x4 s[4];                                                            \
      _Pragma("unroll") for (int q = 0; q < 4; ++q) {                        \
        f32x4 z = {0.f, 0.f, 0.f, 0.f};                                     \
        z = __builtin_amdgcn_mfma_f32_16x16x32_bf16(pa[2 * q], tA[c][0], z, 0, 0, 0); \
        z = __builtin_amdgcn_mfma_f32_16x16x32_bf16(pa[2 * q + 1], tA[c][1], z, 0, 0, 0); \
        s[q] = z;                                                            \
      }                                                                      \
      short8 pb0, pb1;                                                       \
      {                                                                      \
        uint* pw_ = (uint*)&pb0;                                             \
        pw_[0] = pktr(exp2f(s[0][0]), exp2f(s[0][1]));                       \
        pw_[1] = pktr(exp2f(s[0][2]), exp2f(s[0][3]));                       \
        pw_[2] = pktr(exp2f(s[1][0]), exp2f(s[1][1]));                       \
        pw_[3] = pktr(exp2f(s[1][2]), exp2f(s[1][3]));                       \
      }                                                                      \
      {                                                                      \
        uint* pw_ = (uint*)&pb1;                                             \
        pw_[0] = pktr(exp2f(s[2][0]), exp2f(s[2][1]));                       \
        pw_[1] = pktr(exp2f(s[2][2]), exp2f(s[2][3]));                       \
        pw_[2] = pktr(exp2f(s[3][0]), exp2f(s[3][1]));                       \
        pw_[3] = pktr(exp2f(s[3][2]), exp2f(s[3][3]));                       \
      }                                                                      \
      _Pragma("unroll") for (int q = 0; q < 4; ++q)                          \
          ay[c][q] = __builtin_amdgcn_mfma_f32_16x16x32_bf16(ga[q], pb0, ay[c][q], 0, 0, 0); \
      _Pragma("unroll") for (int q = 0; q < 4; ++q)                          \
          ay[c][q] = __builtin_amdgcn_mfma_f32_16x16x32_bf16(ga[4 + q], pb1, ay[c][q], 0, 0, 0); \
    }                                                                        \
  }
#define NLCOMP2(SRC) { NLCOMP1(SRC) NLCOMP1((SRC) + 8192) }

  f32x4 ay[4][4];
#pragma unroll
  for (int c = 0; c < 4; ++c)
#pragma unroll
    for (int q = 0; q < 4; ++q) ay[c][q] = {0.f, 0.f, 0.f, 0.f};

  // 10 tiles = 5 super-tiles: prologue + 2 double-iters + tail
  NLSTAGE2(bufA);
  __syncthreads();
#pragma unroll 1
  for (int t = 0; t < 2; ++t) {
    NLSTAGE2(bufB);
    NLCOMP2(bufA);
    __syncthreads();
    NLSTAGE2(bufA);
    NLCOMP2(bufB);
    __syncthreads();
  }
  NLCOMP2(bufA);
#undef NLSTAGE1
#undef NLSTAGE2
#undef NLCOMP1
#undef NLCOMP2

  uint* b32 = (uint*)(py + ((size_t)(js * kB + b) * (kN / 64) + itile64) * 4096);
#pragma unroll
  for (int c = 0; c < 4; ++c)
#pragma unroll
    for (int q = 0; q < 4; ++q) {
      b32[(c * 8 + q * 2 + 0) * 64 + lane] = pkbf(ay[c][q][0], ay[c][q][1]);
      b32[(c * 8 + q * 2 + 1) * 64 + lane] = pkbf(ay[c][q][2], ay[c][q][3]);
    }
}

// ---- reduce kSJ partials + fused W_y + residuals -> z bf16 pixel-major.
__global__ __launch_bounds__(128) void k_wy(
    const ushort* __restrict__ py, const __hip_bfloat16* __restrict__ wWb,
    const float* __restrict__ x1, const float* __restrict__ alphap,
    ushort* __restrict__ zb) {
  const int b = blockIdx.y;
  const int lane = threadIdx.x & 63, w = threadIdx.x >> 6;
  const int il = lane & 15, hi = lane >> 4;
  const int itile32 = blockIdx.x * 2 + w;
  const int i0w = itile32 * 32;
  const int itile64 = itile32 >> 1, half = itile32 & 1;

  __shared__ __align__(16) ushort yt2[2][32 * 72];
  __shared__ __align__(16) ushort zt2[2][32 * 72];
  ushort* yt = yt2[w];
  ushort* zt = zt2[w];

  float lo[16], hs[16];
#pragma unroll
  for (int k = 0; k < 16; ++k) { lo[k] = 0.f; hs[k] = 0.f; }
#pragma unroll 1
  for (int s = 0; s < kSJ; ++s) {
    const uint* ps =
        (const uint*)(py +
                      ((size_t)(s * kB + b) * (kN / 64) + itile64) * 4096) +
        half * 1024;
#pragma unroll
    for (int k = 0; k < 16; ++k) {
      const uint u = ps[k * 64 + lane];
      lo[k] += __uint_as_float(u << 16);
      hs[k] += __uint_as_float(u & 0xffff0000u);
    }
  }
#pragma unroll
  for (int k = 0; k < 16; ++k) {
    const int row = (k >> 3) * 16 + il;
    const int col = ((k >> 1) & 3) * 16 + hi * 4 + (k & 1) * 2;
    *(uint*)&yt[row * 72 + col] = pkbf(lo[k], hs[k]);
  }

  const float alpha = alphap[0];
#pragma unroll
  for (int a = 0; a < 2; ++a) {
    const short8 by0 = *(const short8*)&yt[(a * 16 + il) * 72 + hi * 8];
    const short8 by1 = *(const short8*)&yt[(a * 16 + il) * 72 + 32 + hi * 8];
#pragma unroll
    for (int q = 0; q < 4; ++q) {
      const short8 af0 = *(const short8*)&wWb[(size_t)(q * 16 + il) * kC + hi * 8];
      const short8 af1 = *(const short8*)&wWb[(size_t)(q * 16 + il) * kC + 32 + hi * 8];
      f32x4 o4 = {0.f, 0.f, 0.f, 0.f};
      o4 = __builtin_amdgcn_mfma_f32_16x16x32_bf16(af0, by0, o4, 0, 0, 0);
      o4 = __builtin_amdgcn_mfma_f32_16x16x32_bf16(af1, by1, o4, 0, 0, 0);
      float zv[4];
#pragma unroll
      for (int r = 0; r < 4; ++r) {
        const int o = q * 16 + hi * 4 + r;
        const size_t idx = ((size_t)b * kC + o) * kN + i0w + a * 16 + il;
        const float xv = x1[idx];
        const float pr = xv >= 0.f ? xv : alpha * xv;
        zv[r] = o4[r] + pr + xv;
      }
      *(uint*)&zt[(a * 16 + il) * 72 + q * 16 + hi * 4] = pkbf(zv[0], zv[1]);
      *(uint*)&zt[(a * 16 + il) * 72 + q * 16 + hi * 4 + 2] = pkbf(zv[2], zv[3]);
    }
  }

  const int px = lane >> 1, cseg = (lane & 1) * 32;
  short8* d = (short8*)&zb[((size_t)b * kN + i0w + px) * kC + cseg];
#pragma unroll
  for (int k = 0; k < 4; ++k)
    d[k] = *(const short8*)&zt[px * 72 + cseg + k * 8];
}

extern "C" void kernel_launch(void* const* d_in, const int* in_sizes, int n_in,
                              void* d_out, int out_size, void* d_ws, size_t ws_size,
                              hipStream_t stream) {
  const float* x      = (const float*)d_in[0];
  const float* w1     = (const float*)d_in[1];
  const float* w2     = (const float*)d_in[2];
  const float* wg     = (const float*)d_in[3];
  const float* wth    = (const float*)d_in[4];
  const float* wph    = (const float*)d_in[5];
  const float* wWm    = (const float*)d_in[6];
  const float* alphap = (const float*)d_in[7];
  float* out = (float*)d_out;

  const size_t SZ = (size_t)kB * kC * kN;  // 819200

  float* x1 = (float*)d_ws;
  __hip_bfloat16* pTb = (__hip_bfloat16*)(x1 + SZ);
  __hip_bfloat16* phb = pTb + SZ;
  __hip_bfloat16* gb  = phb + SZ;
  __hip_bfloat16* gT  = gb + SZ;
  float* partial = (float*)(gT + SZ);
  ushort* wc1 = (ushort*)(partial + (size_t)kB * kSJ * kN);
  ushort* wc2 = wc1 + 9 * kC * kC;
  __hip_bfloat16* Mb  = (__hip_bfloat16*)(wc2 + 9 * kC * kC);
  __hip_bfloat16* wgb = Mb + kC * kC;
  __hip_bfloat16* wWb = wgb + kC * kC;
  ushort* py = (ushort*)(wWb + kC * kC);
  ushort* xb = py;                // overlay: dead before k_nl writes py
  ushort* zb = (ushort*)gb;       // overlay: gb dead after gscale

  k_prep<<<344, 256, 0, stream>>>(w1, w2, wth, wph, wg, wWm, x,
                                  wc1, wc2, Mb, wgb, wWb, xb);
  k_convm<0><<<dim3(400, kB), 256, 0, stream>>>(xb, wc1, alphap, x1,
                                                (ushort*)pTb, Mb, wgb, phb, gb);
  k_colstat<<<dim3(kN / 256, kSJ, kB), 256, 0, stream>>>(pTb, phb, partial);
  k_gscale<<<dim3(kN / 64, kB), 256, 0, stream>>>(gb, partial, gT);
  k_nl<<<dim3(kN / 256, kSJ, kB), 256, 0, stream>>>(pTb, phb, gT, py);
  k_wy<<<dim3(kN / 64, kB), 128, 0, stream>>>(py, wWb, x1, alphap, zb);
  k_convm<1><<<dim3(400, kB), 256, 0, stream>>>(zb, wc2, alphap, out, nullptr,
                                                nullptr, nullptr, nullptr,
                                                nullptr);
}